// Round 2
// baseline (1829.319 us; speedup 1.0000x reference)
//
#include <hip/hip_runtime.h>
#include <hip/hip_bf16.h>

#define BB 4
#define CC 64
#define NN 4096
#define HH 64
#define AH 256
#define KNN 16
#define EPSV 1e-5f

// ---------------------------------------------------------------------------
// Kernel 1: fold BN params, transpose P2 (C,H)->(H,C) and A2 (C,AH)->(AH,C)
// ---------------------------------------------------------------------------
__global__ void prep_params(const float* __restrict__ P2, const float* __restrict__ A2,
                            const float* __restrict__ g1, const float* __restrict__ b1,
                            const float* __restrict__ m1, const float* __restrict__ v1,
                            const float* __restrict__ g2, const float* __restrict__ b2,
                            const float* __restrict__ m2, const float* __restrict__ v2,
                            float* __restrict__ P2T, float* __restrict__ A2T,
                            float* __restrict__ bn1s, float* __restrict__ bn1c,
                            float* __restrict__ bn2s, float* __restrict__ bn2c) {
    int t = threadIdx.x;
    if (t < HH) {
        float s = g1[t] * rsqrtf(v1[t] + EPSV);
        bn1s[t] = s;
        bn1c[t] = b1[t] - m1[t] * s;
    }
    if (t < AH) {
        float s = g2[t] * rsqrtf(v2[t] + EPSV);
        bn2s[t] = s;
        bn2c[t] = b2[t] - m2[t] * s;
    }
    for (int i = t; i < HH * CC; i += 256) {
        int h = i >> 6, c = i & 63;
        P2T[i] = P2[c * HH + h];
    }
    for (int i = t; i < AH * CC; i += 256) {
        int h = i >> 6, o = i & 63;
        A2T[i] = A2[o * AH + h];
    }
}

// ---------------------------------------------------------------------------
// Kernel 2: y1 = Ws*y+bs, key = Wk*y1+bk, query = Wq*x+bq  (point-major out)
// ---------------------------------------------------------------------------
__global__ void prep_features(const float* __restrict__ x, const float* __restrict__ y,
                              const float* __restrict__ Ws, const float* __restrict__ bs,
                              const float* __restrict__ Wk, const float* __restrict__ bk,
                              const float* __restrict__ Wq, const float* __restrict__ bq,
                              float* __restrict__ y1_t, float* __restrict__ key_t,
                              float* __restrict__ qry_t) {
    int gid = blockIdx.x * blockDim.x + threadIdx.x;  // 0..B*N-1
    int b = gid >> 12;
    int n = gid & (NN - 1);

    float yv[CC];
#pragma unroll
    for (int c = 0; c < CC; ++c) yv[c] = y[((size_t)(b * CC + c)) * NN + n];

    float y1v[CC];
#pragma unroll 4
    for (int o = 0; o < CC; ++o) {
        const float* wr = Ws + o * CC;
        float s0 = 0.f, s1 = 0.f, s2 = 0.f, s3 = 0.f;
#pragma unroll
        for (int d = 0; d < 16; ++d) {
            s0 += wr[4 * d + 0] * yv[4 * d + 0];
            s1 += wr[4 * d + 1] * yv[4 * d + 1];
            s2 += wr[4 * d + 2] * yv[4 * d + 2];
            s3 += wr[4 * d + 3] * yv[4 * d + 3];
        }
        y1v[o] = (s0 + s1) + (s2 + s3) + bs[o];
    }

    float* y1o = y1_t + (size_t)gid * CC;
#pragma unroll
    for (int o = 0; o < CC; ++o) y1o[o] = y1v[o];

    float* ko = key_t + (size_t)gid * CC;
#pragma unroll 4
    for (int o = 0; o < CC; ++o) {
        const float* wr = Wk + o * CC;
        float s0 = 0.f, s1 = 0.f, s2 = 0.f, s3 = 0.f;
#pragma unroll
        for (int d = 0; d < 16; ++d) {
            s0 += wr[4 * d + 0] * y1v[4 * d + 0];
            s1 += wr[4 * d + 1] * y1v[4 * d + 1];
            s2 += wr[4 * d + 2] * y1v[4 * d + 2];
            s3 += wr[4 * d + 3] * y1v[4 * d + 3];
        }
        ko[o] = (s0 + s1) + (s2 + s3) + bk[o];
    }

    float x0 = x[(size_t)(b * 3 + 0) * NN + n];
    float x1 = x[(size_t)(b * 3 + 1) * NN + n];
    float x2 = x[(size_t)(b * 3 + 2) * NN + n];
    float* qo = qry_t + (size_t)gid * CC;
#pragma unroll
    for (int o = 0; o < CC; ++o)
        qo[o] = Wq[o * 3 + 0] * x0 + Wq[o * 3 + 1] * x1 + Wq[o * 3 + 2] * x2 + bq[o];
}

// ---------------------------------------------------------------------------
// Kernel 3: exact KNN. 16 queries/block, 16 scanner-threads per query (within
// one wave). 64-bit keys (dist_bits<<32 | j) reproduce top_k tie-breaking.
// Merge: per-thread bitonic sort + 16-round shfl tournament.
// ---------------------------------------------------------------------------
__global__ __launch_bounds__(256) void knn_kernel(const float* __restrict__ x,
                                                  int* __restrict__ idx_out) {
    __shared__ __align__(16) float4 pts[NN];  // 64 KB: xyz per point
    int b = blockIdx.x >> 8;            // 256 blocks per batch
    int n0 = (blockIdx.x & 255) << 4;   // 16 queries per block
    const float* xb = x + (size_t)b * 3 * NN;
    for (int i = threadIdx.x; i < NN; i += 256)
        pts[i] = make_float4(xb[i], xb[NN + i], xb[2 * NN + i], 0.f);
    __syncthreads();

    int ql = threadIdx.x >> 4;   // query within block
    int s  = threadIdx.x & 15;   // scanner id
    int n = n0 + ql;
    float4 q = pts[n];

    unsigned long long key[16];
#pragma unroll
    for (int i = 0; i < 16; ++i) key[i] = 0xFFFFFFFFFFFFFFFFULL;
    unsigned long long kmax = 0xFFFFFFFFFFFFFFFFULL;
    int maxslot = 0;

    // scanner s handles j = m*16 + s  (2-way-free LDS banking)
    for (int m = 0; m < 256; ++m) {
        int j = (m << 4) + s;
        float4 c = pts[j];
        float ax = q.x - c.x, ay = q.y - c.y, az = q.z - c.z;
        float d = ax * ax + ay * ay + az * az;
        unsigned long long kk = ((unsigned long long)__float_as_uint(d) << 32) | (unsigned)j;
        if (kk < kmax) {
#pragma unroll
            for (int t2 = 0; t2 < 16; ++t2)
                if (t2 == maxslot) key[t2] = kk;
            kmax = key[0]; maxslot = 0;
#pragma unroll
            for (int t2 = 1; t2 < 16; ++t2)
                if (key[t2] > kmax) { kmax = key[t2]; maxslot = t2; }
        }
    }

    // bitonic sort the 16 local keys ascending (static indices only)
#pragma unroll
    for (int kk2 = 2; kk2 <= 16; kk2 <<= 1) {
#pragma unroll
        for (int j2 = kk2 >> 1; j2 > 0; j2 >>= 1) {
#pragma unroll
            for (int i = 0; i < 16; ++i) {
                int l = i ^ j2;
                if (l > i) {
                    bool up = ((i & kk2) == 0);
                    unsigned long long A = key[i], Bv = key[l];
                    bool sw = up ? (A > Bv) : (A < Bv);
                    unsigned long long lo = sw ? Bv : A;
                    unsigned long long hi = sw ? A : Bv;
                    key[i] = lo; key[l] = hi;
                }
            }
        }
    }

    // 16-round tournament: global min of the 16 lanes' heads; winner shifts.
    int mywin = 0;
#pragma unroll
    for (int r = 0; r < 16; ++r) {
        unsigned long long h = key[0];
        unsigned long long o1;
        o1 = __shfl_xor(h, 1); h = (o1 < h) ? o1 : h;
        o1 = __shfl_xor(h, 2); h = (o1 < h) ? o1 : h;
        o1 = __shfl_xor(h, 4); h = (o1 < h) ? o1 : h;
        o1 = __shfl_xor(h, 8); h = (o1 < h) ? o1 : h;
        bool win = (key[0] == h);
#pragma unroll
        for (int i2 = 0; i2 < 15; ++i2) key[i2] = win ? key[i2 + 1] : key[i2];
        key[15] = win ? 0xFFFFFFFFFFFFFFFFULL : key[15];
        mywin = (r == s) ? (int)(unsigned)(h & 0xFFFFFFFFu) : mywin;
    }
    idx_out[((size_t)b * NN + n) * KNN + s] = mywin;
}

// ---------------------------------------------------------------------------
// Kernel 4: fused attention. 2 threads per (point, neighbor) pair; each owns
// 32 channels. 8 points x 16 k x 2 halves = 256 threads/block.
// Dot merges across halves via shfl_xor(16); softmax/agg via shfl over k.
// ---------------------------------------------------------------------------
__global__ __launch_bounds__(256, 3) void attn_kernel(
    const float* __restrict__ x, const float* __restrict__ y,
    const float* __restrict__ y1_t, const float* __restrict__ key_t,
    const float* __restrict__ qry_t, const int* __restrict__ idx,
    const float* __restrict__ P1, const float* __restrict__ pb1,
    const float* __restrict__ bn1s, const float* __restrict__ bn1c,
    const float* __restrict__ P2T, const float* __restrict__ pb2,
    const float* __restrict__ A1, const float* __restrict__ ab1,
    const float* __restrict__ bn2s, const float* __restrict__ bn2c,
    const float* __restrict__ A2T, const float* __restrict__ ab2,
    const float* __restrict__ Wend, const float* __restrict__ bend,
    float* __restrict__ out) {
    int b  = blockIdx.x >> 9;           // 512 blocks per batch
    int n0 = (blockIdx.x & 511) << 3;   // 8 points per block
    int t = threadIdx.x;
    int p  = t >> 5;         // point within block
    int h  = (t >> 4) & 1;   // channel half
    int kk = t & 15;         // neighbor
    int n = n0 + p;
    size_t bn = (size_t)b * NN + n;
    int j = idx[bn * KNN + kk];
    size_t bj = (size_t)b * NN + j;
    int co = h << 5;         // channel offset (0 or 32)

    float dx = x[(size_t)(b * 3 + 0) * NN + n] - x[(size_t)(b * 3 + 0) * NN + j];
    float dy = x[(size_t)(b * 3 + 1) * NN + n] - x[(size_t)(b * 3 + 1) * NN + j];
    float dz = x[(size_t)(b * 3 + 2) * NN + n] - x[(size_t)(b * 3 + 2) * NN + j];

    // u(own half) = query - gathered key
    float u[32];
    {
        const float4* q4 = (const float4*)(qry_t + bn * CC + co);
        const float4* k4 = (const float4*)(key_t + bj * CC + co);
#pragma unroll
        for (int c = 0; c < 8; ++c) {
            float4 qv = q4[c], kv = k4[c];
            u[4 * c + 0] = qv.x - kv.x;
            u[4 * c + 1] = qv.y - kv.y;
            u[4 * c + 2] = qv.z - kv.z;
            u[4 * c + 3] = qv.w - kv.w;
        }
    }

    // pe(own half) = P2 * relu(bn1(P1*pos_rel+pb1)) + pb2
    float pe[32];
    {
        const float4* pb24 = (const float4*)(pb2 + co);
#pragma unroll
        for (int c = 0; c < 8; ++c) {
            float4 v = pb24[c];
            pe[4 * c + 0] = v.x; pe[4 * c + 1] = v.y;
            pe[4 * c + 2] = v.z; pe[4 * c + 3] = v.w;
        }
    }
#pragma unroll 1
    for (int hh = 0; hh < HH; ++hh) {
        float tp = P1[hh * 3 + 0] * dx + P1[hh * 3 + 1] * dy + P1[hh * 3 + 2] * dz + pb1[hh];
        float a = fmaxf(tp * bn1s[hh] + bn1c[hh], 0.f);
        const float4* w4 = (const float4*)(P2T + hh * CC + co);
#pragma unroll
        for (int c = 0; c < 8; ++c) {
            float4 w = w4[c];
            pe[4 * c + 0] += w.x * a; pe[4 * c + 1] += w.y * a;
            pe[4 * c + 2] += w.z * a; pe[4 * c + 3] += w.w * a;
        }
    }
#pragma unroll
    for (int c = 0; c < 32; ++c) u[c] += pe[c];

    // logits(own half) = A2 * relu(bn2(A1*u + ab1)) + ab2
    float acc[32];
    {
        const float4* ab24 = (const float4*)(ab2 + co);
#pragma unroll
        for (int c = 0; c < 8; ++c) {
            float4 v = ab24[c];
            acc[4 * c + 0] = v.x; acc[4 * c + 1] = v.y;
            acc[4 * c + 2] = v.z; acc[4 * c + 3] = v.w;
        }
    }
#pragma unroll 1
    for (int hh = 0; hh < AH; ++hh) {
        const float4* w4 = (const float4*)(A1 + hh * CC + co);
        float s0 = 0.f, s1 = 0.f, s2 = 0.f, s3 = 0.f;
#pragma unroll
        for (int c = 0; c < 8; ++c) {
            float4 w = w4[c];
            s0 += w.x * u[4 * c + 0];
            s1 += w.y * u[4 * c + 1];
            s2 += w.z * u[4 * c + 2];
            s3 += w.w * u[4 * c + 3];
        }
        float sv = (s0 + s1) + (s2 + s3);
        sv += __shfl_xor(sv, 16);       // merge the two halves' partial dots
        sv += ab1[hh];
        float hv = fmaxf(sv * bn2s[hh] + bn2c[hh], 0.f);
        const float4* w24 = (const float4*)(A2T + hh * CC + co);
#pragma unroll
        for (int c = 0; c < 8; ++c) {
            float4 w = w24[c];
            acc[4 * c + 0] += w.x * hv; acc[4 * c + 1] += w.y * hv;
            acc[4 * c + 2] += w.z * hv; acc[4 * c + 3] += w.w * hv;
        }
    }

    // softmax over the 16 k-lanes per channel, then weighted aggregation.
    // agg stored into u[] (dead).
    {
        const float4* v4 = (const float4*)(y1_t + bn * CC + co);
#pragma unroll
        for (int c4 = 0; c4 < 8; ++c4) {
            float4 vv = v4[c4];
            float vvv[4] = {vv.x, vv.y, vv.z, vv.w};
#pragma unroll
            for (int e = 0; e < 4; ++e) {
                int c = 4 * c4 + e;
                float v = acc[c];
                float m = v;
                m = fmaxf(m, __shfl_xor(m, 1));
                m = fmaxf(m, __shfl_xor(m, 2));
                m = fmaxf(m, __shfl_xor(m, 4));
                m = fmaxf(m, __shfl_xor(m, 8));
                float ee = __expf(v - m);
                float ssum = ee;
                ssum += __shfl_xor(ssum, 1);
                ssum += __shfl_xor(ssum, 2);
                ssum += __shfl_xor(ssum, 4);
                ssum += __shfl_xor(ssum, 8);
                float w = ee / ssum;
                float contrib = w * (vvv[e] + pe[c]);
                contrib += __shfl_xor(contrib, 1);
                contrib += __shfl_xor(contrib, 2);
                contrib += __shfl_xor(contrib, 4);
                contrib += __shfl_xor(contrib, 8);
                u[c] = contrib;
            }
        }
    }

    // final: pair kk handles outputs 4kk..4kk+3; each thread partial over its
    // 32 channels, merged across halves via shfl_xor(16).
    float po[4];
#pragma unroll
    for (int i = 0; i < 4; ++i) {
        const float4* w4 = (const float4*)(Wend + (4 * kk + i) * CC + co);
        float s0 = 0.f, s1 = 0.f, s2 = 0.f, s3 = 0.f;
#pragma unroll
        for (int c = 0; c < 8; ++c) {
            float4 w = w4[c];
            s0 += w.x * u[4 * c + 0];
            s1 += w.y * u[4 * c + 1];
            s2 += w.z * u[4 * c + 2];
            s3 += w.w * u[4 * c + 3];
        }
        po[i] = (s0 + s1) + (s2 + s3);
    }
#pragma unroll
    for (int i = 0; i < 4; ++i) po[i] += __shfl_xor(po[i], 16);
#pragma unroll
    for (int i2 = 0; i2 < 2; ++i2) {
        int o = 4 * kk + 2 * h + i2;
        size_t oi = ((size_t)(b * CC + o)) * NN + n;
        out[oi] = po[2 * h + i2] + bend[o] + y[oi];
    }
}

// ---------------------------------------------------------------------------
extern "C" void kernel_launch(void* const* d_in, const int* in_sizes, int n_in,
                              void* d_out, int out_size, void* d_ws, size_t ws_size,
                              hipStream_t stream) {
    const float* x    = (const float*)d_in[0];
    const float* y    = (const float*)d_in[1];
    const float* Ws   = (const float*)d_in[2];
    const float* bs   = (const float*)d_in[3];
    const float* Wk   = (const float*)d_in[4];
    const float* bk   = (const float*)d_in[5];
    const float* Wq   = (const float*)d_in[6];
    const float* bq   = (const float*)d_in[7];
    const float* P1   = (const float*)d_in[8];
    const float* pb1  = (const float*)d_in[9];
    const float* g1   = (const float*)d_in[10];
    const float* b1   = (const float*)d_in[11];
    const float* m1   = (const float*)d_in[12];
    const float* v1   = (const float*)d_in[13];
    const float* P2   = (const float*)d_in[14];
    const float* pb2  = (const float*)d_in[15];
    const float* A1   = (const float*)d_in[16];
    const float* ab1  = (const float*)d_in[17];
    const float* g2   = (const float*)d_in[18];
    const float* b2   = (const float*)d_in[19];
    const float* m2   = (const float*)d_in[20];
    const float* v2   = (const float*)d_in[21];
    const float* A2   = (const float*)d_in[22];
    const float* ab2  = (const float*)d_in[23];
    const float* Wend = (const float*)d_in[24];
    const float* bend = (const float*)d_in[25];

    float* ws    = (float*)d_ws;
    float* y1_t  = ws;                    // B*N*C = 1048576 floats
    float* key_t = ws + 1048576;          // 1048576
    float* qry_t = ws + 2097152;          // 1048576
    int*   idx   = (int*)(ws + 3145728);  // B*N*16 = 262144 ints
    float* P2T   = ws + 3407872;          // 4096
    float* A2T   = P2T + 4096;            // 16384
    float* bn1s  = A2T + 16384;
    float* bn1c  = bn1s + 64;
    float* bn2s  = bn1c + 64;
    float* bn2c  = bn2s + 256;
    float* out   = (float*)d_out;

    hipLaunchKernelGGL(prep_params, dim3(1), dim3(256), 0, stream,
                       P2, A2, g1, b1, m1, v1, g2, b2, m2, v2,
                       P2T, A2T, bn1s, bn1c, bn2s, bn2c);
    hipLaunchKernelGGL(prep_features, dim3(64), dim3(256), 0, stream,
                       x, y, Ws, bs, Wk, bk, Wq, bq, y1_t, key_t, qry_t);
    hipLaunchKernelGGL(knn_kernel, dim3(1024), dim3(256), 0, stream, x, idx);
    hipLaunchKernelGGL(attn_kernel, dim3(2048), dim3(256), 0, stream,
                       x, y, y1_t, key_t, qry_t, idx,
                       P1, pb1, bn1s, bn1c, P2T, pb2,
                       A1, ab1, bn2s, bn2c, A2T, ab2,
                       Wend, bend, out);
}

// Round 3
// 923.531 us; speedup vs baseline: 1.9808x; 1.9808x over previous
//
#include <hip/hip_runtime.h>
#include <hip/hip_bf16.h>

#define BB 4
#define CC 64
#define NN 4096
#define HH 64
#define AH 256
#define KNN 16
#define EPSV 1e-5f

typedef __attribute__((ext_vector_type(8))) short short8;
typedef __attribute__((ext_vector_type(4))) short short4v;
typedef __attribute__((ext_vector_type(4))) float floatx4;

__device__ __forceinline__ unsigned short f2bf(float f) {
    unsigned u = __float_as_uint(f);
    u += 0x7FFFu + ((u >> 16) & 1u);   // round-to-nearest-even
    return (unsigned short)(u >> 16);
}

// ---------------------------------------------------------------------------
// Kernel 1: fold BN params; emit bf16 weight copies in MFMA-friendly layouts.
//  A1bf (AH,C) row-major  : B-frag rows for GEMM1 (lane n = h-col reads row h)
//  A2bf (C,AH) row-major  : B-frag rows for GEMM2
//  P2bf (C,H)  row-major  : B-frag rows for GEMM-P2
//  P1p  float4[h] = (P1*bn1s, pb1 folded)   ab1f = folded bias for bn2
// ---------------------------------------------------------------------------
__global__ void prep_params(const float* __restrict__ P1, const float* __restrict__ pb1,
                            const float* __restrict__ P2, const float* __restrict__ A1,
                            const float* __restrict__ ab1, const float* __restrict__ A2,
                            const float* __restrict__ g1, const float* __restrict__ b1,
                            const float* __restrict__ m1, const float* __restrict__ v1,
                            const float* __restrict__ g2, const float* __restrict__ b2,
                            const float* __restrict__ m2, const float* __restrict__ v2,
                            unsigned short* __restrict__ A1bf, unsigned short* __restrict__ A2bf,
                            unsigned short* __restrict__ P2bf, float* __restrict__ P1p,
                            float* __restrict__ ab1f, float* __restrict__ bn2s_c) {
    int t = threadIdx.x;
    if (t < HH) {
        float s = g1[t] * rsqrtf(v1[t] + EPSV);
        float c = b1[t] - m1[t] * s;
        P1p[4 * t + 0] = P1[3 * t + 0] * s;
        P1p[4 * t + 1] = P1[3 * t + 1] * s;
        P1p[4 * t + 2] = P1[3 * t + 2] * s;
        P1p[4 * t + 3] = pb1[t] * s + c;
    }
    if (t < AH) {
        float s = g2[t] * rsqrtf(v2[t] + EPSV);
        bn2s_c[t] = s;
        ab1f[t] = ab1[t] * s + (b2[t] - m2[t] * s);
    }
    for (int i = t; i < AH * CC; i += 256) A1bf[i] = f2bf(A1[i]);
    for (int i = t; i < CC * AH; i += 256) A2bf[i] = f2bf(A2[i]);
    for (int i = t; i < CC * HH; i += 256) P2bf[i] = f2bf(P2[i]);
}

// ---------------------------------------------------------------------------
// Kernel 2: y1 = Ws*y+bs, key = Wk*y1+bk, query = Wq*x+bq  (point-major out)
// ---------------------------------------------------------------------------
__global__ void prep_features(const float* __restrict__ x, const float* __restrict__ y,
                              const float* __restrict__ Ws, const float* __restrict__ bs,
                              const float* __restrict__ Wk, const float* __restrict__ bk,
                              const float* __restrict__ Wq, const float* __restrict__ bq,
                              float* __restrict__ y1_t, float* __restrict__ key_t,
                              float* __restrict__ qry_t) {
    int gid = blockIdx.x * blockDim.x + threadIdx.x;  // 0..B*N-1
    int b = gid >> 12;
    int n = gid & (NN - 1);

    float yv[CC];
#pragma unroll
    for (int c = 0; c < CC; ++c) yv[c] = y[((size_t)(b * CC + c)) * NN + n];

    float y1v[CC];
#pragma unroll 4
    for (int o = 0; o < CC; ++o) {
        const float* wr = Ws + o * CC;
        float s0 = 0.f, s1 = 0.f, s2 = 0.f, s3 = 0.f;
#pragma unroll
        for (int d = 0; d < 16; ++d) {
            s0 += wr[4 * d + 0] * yv[4 * d + 0];
            s1 += wr[4 * d + 1] * yv[4 * d + 1];
            s2 += wr[4 * d + 2] * yv[4 * d + 2];
            s3 += wr[4 * d + 3] * yv[4 * d + 3];
        }
        y1v[o] = (s0 + s1) + (s2 + s3) + bs[o];
    }

    float* y1o = y1_t + (size_t)gid * CC;
#pragma unroll
    for (int o = 0; o < CC; ++o) y1o[o] = y1v[o];

    float* ko = key_t + (size_t)gid * CC;
#pragma unroll 4
    for (int o = 0; o < CC; ++o) {
        const float* wr = Wk + o * CC;
        float s0 = 0.f, s1 = 0.f, s2 = 0.f, s3 = 0.f;
#pragma unroll
        for (int d = 0; d < 16; ++d) {
            s0 += wr[4 * d + 0] * y1v[4 * d + 0];
            s1 += wr[4 * d + 1] * y1v[4 * d + 1];
            s2 += wr[4 * d + 2] * y1v[4 * d + 2];
            s3 += wr[4 * d + 3] * y1v[4 * d + 3];
        }
        ko[o] = (s0 + s1) + (s2 + s3) + bk[o];
    }

    float x0 = x[(size_t)(b * 3 + 0) * NN + n];
    float x1 = x[(size_t)(b * 3 + 1) * NN + n];
    float x2 = x[(size_t)(b * 3 + 2) * NN + n];
    float* qo = qry_t + (size_t)gid * CC;
#pragma unroll
    for (int o = 0; o < CC; ++o)
        qo[o] = Wq[o * 3 + 0] * x0 + Wq[o * 3 + 1] * x1 + Wq[o * 3 + 2] * x2 + bq[o];
}

// ---------------------------------------------------------------------------
// Kernel 3: exact KNN (unchanged from round 2 — verified correct).
// ---------------------------------------------------------------------------
__global__ __launch_bounds__(256) void knn_kernel(const float* __restrict__ x,
                                                  int* __restrict__ idx_out) {
    __shared__ __align__(16) float4 pts[NN];
    int b = blockIdx.x >> 8;
    int n0 = (blockIdx.x & 255) << 4;
    const float* xb = x + (size_t)b * 3 * NN;
    for (int i = threadIdx.x; i < NN; i += 256)
        pts[i] = make_float4(xb[i], xb[NN + i], xb[2 * NN + i], 0.f);
    __syncthreads();

    int ql = threadIdx.x >> 4;
    int s  = threadIdx.x & 15;
    int n = n0 + ql;
    float4 q = pts[n];

    unsigned long long key[16];
#pragma unroll
    for (int i = 0; i < 16; ++i) key[i] = 0xFFFFFFFFFFFFFFFFULL;
    unsigned long long kmax = 0xFFFFFFFFFFFFFFFFULL;
    int maxslot = 0;

    for (int m = 0; m < 256; ++m) {
        int j = (m << 4) + s;
        float4 c = pts[j];
        float ax = q.x - c.x, ay = q.y - c.y, az = q.z - c.z;
        float d = ax * ax + ay * ay + az * az;
        unsigned long long kk = ((unsigned long long)__float_as_uint(d) << 32) | (unsigned)j;
        if (kk < kmax) {
#pragma unroll
            for (int t2 = 0; t2 < 16; ++t2)
                if (t2 == maxslot) key[t2] = kk;
            kmax = key[0]; maxslot = 0;
#pragma unroll
            for (int t2 = 1; t2 < 16; ++t2)
                if (key[t2] > kmax) { kmax = key[t2]; maxslot = t2; }
        }
    }

#pragma unroll
    for (int kk2 = 2; kk2 <= 16; kk2 <<= 1) {
#pragma unroll
        for (int j2 = kk2 >> 1; j2 > 0; j2 >>= 1) {
#pragma unroll
            for (int i = 0; i < 16; ++i) {
                int l = i ^ j2;
                if (l > i) {
                    bool up = ((i & kk2) == 0);
                    unsigned long long A = key[i], Bv = key[l];
                    bool sw = up ? (A > Bv) : (A < Bv);
                    unsigned long long lo = sw ? Bv : A;
                    unsigned long long hi = sw ? A : Bv;
                    key[i] = lo; key[l] = hi;
                }
            }
        }
    }

    int mywin = 0;
#pragma unroll
    for (int r = 0; r < 16; ++r) {
        unsigned long long h = key[0];
        unsigned long long o1;
        o1 = __shfl_xor(h, 1); h = (o1 < h) ? o1 : h;
        o1 = __shfl_xor(h, 2); h = (o1 < h) ? o1 : h;
        o1 = __shfl_xor(h, 4); h = (o1 < h) ? o1 : h;
        o1 = __shfl_xor(h, 8); h = (o1 < h) ? o1 : h;
        bool win = (key[0] == h);
#pragma unroll
        for (int i2 = 0; i2 < 15; ++i2) key[i2] = win ? key[i2 + 1] : key[i2];
        key[15] = win ? 0xFFFFFFFFFFFFFFFFULL : key[15];
        mywin = (r == s) ? (int)(unsigned)(h & 0xFFFFFFFFu) : mywin;
    }
    idx_out[((size_t)b * NN + n) * KNN + s] = mywin;
}

// ---------------------------------------------------------------------------
// Kernel 4: fused MFMA attention. Block = 4 points x 16 neighbors = 64 rows,
// 4 waves; wave w owns point w's 16-row M-tile end-to-end (P2-GEMM, GEMM1,
// GEMM2, softmax, aggregation, final 64x64 dot). Single barrier for the
// coalesced output transpose.
// MFMA 16x16x32 bf16 layouts: A[m=lane&15][k=quad*8+j], B[n=lane&15][k=...],
// C/D col=lane&15, row=quad*4+reg.
// ---------------------------------------------------------------------------
#define UPITCH 68    // ushorts per u row (136B: 8B-aligned, bank-staggered)
#define HPITCH 260   // ushorts per hidden row (520B)

__device__ __forceinline__ short8 lds_frag(const unsigned short* p) {
    short4v lo = *(const short4v*)p;
    short4v hi = *(const short4v*)(p + 4);
    short8 v;
    v[0] = lo[0]; v[1] = lo[1]; v[2] = lo[2]; v[3] = lo[3];
    v[4] = hi[0]; v[5] = hi[1]; v[6] = hi[2]; v[7] = hi[3];
    return v;
}

__global__ __launch_bounds__(256, 3) void attn_mfma(
    const float* __restrict__ x, const float* __restrict__ y,
    const float* __restrict__ y1_t, const float* __restrict__ key_t,
    const float* __restrict__ qry_t, const int* __restrict__ idx,
    const float* __restrict__ P1p, const unsigned short* __restrict__ P2bf,
    const float* __restrict__ pb2, const unsigned short* __restrict__ A1bf,
    const float* __restrict__ ab1f, const float* __restrict__ bn2s_c,
    const unsigned short* __restrict__ A2bf,
    const float* __restrict__ Wend, const float* __restrict__ bend,
    float* __restrict__ out) {
    __shared__ unsigned short u_lds[64 * UPITCH];
    __shared__ unsigned short hid_lds[64 * HPITCH];
    __shared__ float agg_lds[4 * 64];
    __shared__ float outstage[64 * 4];

    int blk = blockIdx.x;
    int b = blk >> 10;
    int n0 = (blk & 1023) << 2;
    int w = threadIdx.x >> 6;
    int lane = threadIdx.x & 63;
    int m = lane & 15, quad = lane >> 4;
    int pt = n0 + w;
    size_t bpt = (size_t)b * NN + pt;

    // ---- hidden1 A-frags in registers: rows = neighbor slots, k = h1 ----
    int jm = idx[bpt * KNN + m];
    float dx = x[(size_t)(b * 3 + 0) * NN + pt] - x[(size_t)(b * 3 + 0) * NN + jm];
    float dy = x[(size_t)(b * 3 + 1) * NN + pt] - x[(size_t)(b * 3 + 1) * NN + jm];
    float dz = x[(size_t)(b * 3 + 2) * NN + pt] - x[(size_t)(b * 3 + 2) * NN + jm];
    short8 h1A[2];
#pragma unroll
    for (int ks = 0; ks < 2; ++ks) {
#pragma unroll
        for (int j = 0; j < 8; ++j) {
            int h1 = ks * 32 + quad * 8 + j;
            const float4 p = *(const float4*)(P1p + 4 * h1);
            float a = fmaxf(p.x * dx + p.y * dy + p.z * dz + p.w, 0.f);
            h1A[ks][j] = (short)f2bf(a);
        }
    }

    // ---- GEMM-P2: pe (C-layout regs), + pb2 ----
    floatx4 pacc[4];
#pragma unroll
    for (int nt = 0; nt < 4; ++nt) pacc[nt] = (floatx4){0.f, 0.f, 0.f, 0.f};
#pragma unroll
    for (int ks = 0; ks < 2; ++ks) {
#pragma unroll
        for (int nt = 0; nt < 4; ++nt) {
            short8 bb = *(const short8*)(P2bf + (nt * 16 + m) * HH + ks * 32 + quad * 8);
            pacc[nt] = __builtin_amdgcn_mfma_f32_16x16x32_bf16(h1A[ks], bb, pacc[nt], 0, 0, 0);
        }
    }
#pragma unroll
    for (int nt = 0; nt < 4; ++nt) {
        float pb = pb2[nt * 16 + m];
#pragma unroll
        for (int r = 0; r < 4; ++r) pacc[nt][r] += pb;
    }

    // ---- u = query - key + pe -> bf16 LDS (C-layout write) ----
    int j4[4];
#pragma unroll
    for (int r = 0; r < 4; ++r) j4[r] = idx[bpt * KNN + 4 * quad + r];
#pragma unroll
    for (int nt = 0; nt < 4; ++nt) {
        float qv = qry_t[bpt * CC + nt * 16 + m];
#pragma unroll
        for (int r = 0; r < 4; ++r) {
            float kv = key_t[((size_t)b * NN + j4[r]) * CC + nt * 16 + m];
            float uu = qv - kv + pacc[nt][r];
            u_lds[(w * 16 + 4 * quad + r) * UPITCH + nt * 16 + m] = f2bf(uu);
        }
    }

    // ---- u A-frags ----
    short8 uA[2];
#pragma unroll
    for (int ks = 0; ks < 2; ++ks)
        uA[ks] = lds_frag(&u_lds[(w * 16 + m) * UPITCH + ks * 32 + quad * 8]);

    // ---- GEMM1: hidden = relu(bn2(u*A1^T)) -> bf16 LDS ----
#pragma unroll 1
    for (int nt = 0; nt < 16; ++nt) {
        const unsigned short* brow = A1bf + (nt * 16 + m) * CC;
        short8 b0 = *(const short8*)(brow + quad * 8);
        short8 b1 = *(const short8*)(brow + 32 + quad * 8);
        floatx4 acc = (floatx4){0.f, 0.f, 0.f, 0.f};
        acc = __builtin_amdgcn_mfma_f32_16x16x32_bf16(uA[0], b0, acc, 0, 0, 0);
        acc = __builtin_amdgcn_mfma_f32_16x16x32_bf16(uA[1], b1, acc, 0, 0, 0);
        int h = nt * 16 + m;
        float s = bn2s_c[h], t0 = ab1f[h];
#pragma unroll
        for (int r = 0; r < 4; ++r) {
            float hv = fmaxf(acc[r] * s + t0, 0.f);
            hid_lds[(w * 16 + 4 * quad + r) * HPITCH + h] = f2bf(hv);
        }
    }

    // ---- GEMM2: logits = hidden * A2^T  (ab2 dropped: softmax-invariant) ----
    floatx4 acc2[4];
#pragma unroll
    for (int nt = 0; nt < 4; ++nt) acc2[nt] = (floatx4){0.f, 0.f, 0.f, 0.f};
#pragma unroll 1
    for (int ks = 0; ks < 8; ++ks) {
        short8 hA = lds_frag(&hid_lds[(w * 16 + m) * HPITCH + ks * 32 + quad * 8]);
#pragma unroll
        for (int nt = 0; nt < 4; ++nt) {
            short8 bb = *(const short8*)(A2bf + (nt * 16 + m) * AH + ks * 32 + quad * 8);
            acc2[nt] = __builtin_amdgcn_mfma_f32_16x16x32_bf16(hA, bb, acc2[nt], 0, 0, 0);
        }
    }

    // ---- softmax over 16 neighbors (4 regs x 4 quads) + aggregation ----
#pragma unroll
    for (int nt = 0; nt < 4; ++nt) {
        float l0 = acc2[nt][0], l1 = acc2[nt][1], l2 = acc2[nt][2], l3 = acc2[nt][3];
        float mx = fmaxf(fmaxf(l0, l1), fmaxf(l2, l3));
        mx = fmaxf(mx, __shfl_xor(mx, 16));
        mx = fmaxf(mx, __shfl_xor(mx, 32));
        float e0 = __expf(l0 - mx), e1 = __expf(l1 - mx);
        float e2 = __expf(l2 - mx), e3 = __expf(l3 - mx);
        float sum = (e0 + e1) + (e2 + e3);
        sum += __shfl_xor(sum, 16);
        sum += __shfl_xor(sum, 32);
        float y1v = y1_t[bpt * CC + nt * 16 + m];
        float contrib = e0 * (y1v + pacc[nt][0]) + e1 * (y1v + pacc[nt][1]) +
                        e2 * (y1v + pacc[nt][2]) + e3 * (y1v + pacc[nt][3]);
        contrib += __shfl_xor(contrib, 16);
        contrib += __shfl_xor(contrib, 32);
        float agg = contrib / sum;
        if (quad == 0) agg_lds[w * 64 + nt * 16 + m] = agg;
    }

    // ---- final: out[o=lane] = Wend[o]·agg + bend[o]  (wave-local) ----
    float acco = 0.f;
#pragma unroll
    for (int c4 = 0; c4 < 16; ++c4) {
        float4 wv = *(const float4*)(Wend + lane * CC + c4 * 4);
        float4 av = *(const float4*)(agg_lds + w * 64 + c4 * 4);
        acco += wv.x * av.x + wv.y * av.y + wv.z * av.z + wv.w * av.w;
    }
    acco += bend[lane];
    outstage[lane * 4 + w] = acco;
    __syncthreads();

    int t = threadIdx.x;
    int o = t >> 2, p = t & 3;
    size_t oi = ((size_t)(b * CC + o)) * NN + n0 + p;
    out[oi] = outstage[t] + y[oi];
}

// ---------------------------------------------------------------------------
extern "C" void kernel_launch(void* const* d_in, const int* in_sizes, int n_in,
                              void* d_out, int out_size, void* d_ws, size_t ws_size,
                              hipStream_t stream) {
    const float* x    = (const float*)d_in[0];
    const float* y    = (const float*)d_in[1];
    const float* Ws   = (const float*)d_in[2];
    const float* bs   = (const float*)d_in[3];
    const float* Wk   = (const float*)d_in[4];
    const float* bk   = (const float*)d_in[5];
    const float* Wq   = (const float*)d_in[6];
    const float* bq   = (const float*)d_in[7];
    const float* P1   = (const float*)d_in[8];
    const float* pb1  = (const float*)d_in[9];
    const float* g1   = (const float*)d_in[10];
    const float* b1   = (const float*)d_in[11];
    const float* m1   = (const float*)d_in[12];
    const float* v1   = (const float*)d_in[13];
    const float* P2   = (const float*)d_in[14];
    const float* pb2  = (const float*)d_in[15];
    const float* A1   = (const float*)d_in[16];
    const float* ab1  = (const float*)d_in[17];
    const float* g2   = (const float*)d_in[18];
    const float* b2   = (const float*)d_in[19];
    const float* m2   = (const float*)d_in[20];
    const float* v2   = (const float*)d_in[21];
    const float* A2   = (const float*)d_in[22];
    const float* ab2  = (const float*)d_in[23];  // dropped (softmax-invariant)
    const float* Wend = (const float*)d_in[24];
    const float* bend = (const float*)d_in[25];
    (void)ab2;

    float* ws    = (float*)d_ws;
    float* y1_t  = ws;                           // 1,048,576 f
    float* key_t = ws + 1048576;                 // 1,048,576 f
    float* qry_t = ws + 2097152;                 // 1,048,576 f
    int*   idx   = (int*)(ws + 3145728);         // 262,144 i
    unsigned short* A1bf = (unsigned short*)(ws + 3407872);  // 16384 bf16
    unsigned short* A2bf = (unsigned short*)(ws + 3416064);  // 16384 bf16
    unsigned short* P2bf = (unsigned short*)(ws + 3424256);  // 4096 bf16
    float* P1p   = ws + 3426304;                 // 256 f (float4 per h)
    float* ab1f  = ws + 3426560;                 // 256 f
    float* bn2sc = ws + 3426816;                 // 256 f
    float* out   = (float*)d_out;

    hipLaunchKernelGGL(prep_params, dim3(1), dim3(256), 0, stream,
                       P1, pb1, P2, A1, ab1, A2, g1, b1, m1, v1, g2, b2, m2, v2,
                       A1bf, A2bf, P2bf, P1p, ab1f, bn2sc);
    hipLaunchKernelGGL(prep_features, dim3(128), dim3(128), 0, stream,
                       x, y, Ws, bs, Wk, bk, Wq, bq, y1_t, key_t, qry_t);
    hipLaunchKernelGGL(knn_kernel, dim3(1024), dim3(256), 0, stream, x, idx);
    hipLaunchKernelGGL(attn_mfma, dim3(4096), dim3(256), 0, stream,
                       x, y, y1_t, key_t, qry_t, idx,
                       P1p, P2bf, pb2, A1bf, ab1f, bn2sc, A2bf,
                       Wend, bend, out);
}

// Round 5
// 572.423 us; speedup vs baseline: 3.1957x; 1.6134x over previous
//
#include <hip/hip_runtime.h>
#include <hip/hip_bf16.h>

#define BB 4
#define CC 64
#define NN 4096
#define HH 64
#define AH 256
#define KNN 16
#define EPSV 1e-5f

typedef __attribute__((ext_vector_type(8))) short short8;
typedef __attribute__((ext_vector_type(4))) short short4v;
typedef __attribute__((ext_vector_type(4))) float floatx4;

__device__ __forceinline__ unsigned short f2bf(float f) {
    unsigned u = __float_as_uint(f);
    u += 0x7FFFu + ((u >> 16) & 1u);   // round-to-nearest-even
    return (unsigned short)(u >> 16);
}

__device__ __forceinline__ unsigned long long umin64(unsigned long long a, unsigned long long b) {
    return a < b ? a : b;
}
__device__ __forceinline__ unsigned long long umax64(unsigned long long a, unsigned long long b) {
    return a > b ? a : b;
}
__device__ __forceinline__ unsigned long long shfl_xor_u64(unsigned long long v, int m) {
    int lo = __shfl_xor((int)(unsigned)(v & 0xFFFFFFFFull), m);
    int hi = __shfl_xor((int)(unsigned)(v >> 32), m);
    return ((unsigned long long)(unsigned)hi << 32) | (unsigned)lo;
}

// ---------------------------------------------------------------------------
// Kernel 1: fold BN params; emit bf16 weight copies in MFMA-friendly layouts.
// ---------------------------------------------------------------------------
__global__ void prep_params(const float* __restrict__ P1, const float* __restrict__ pb1,
                            const float* __restrict__ P2, const float* __restrict__ A1,
                            const float* __restrict__ ab1, const float* __restrict__ A2,
                            const float* __restrict__ g1, const float* __restrict__ b1,
                            const float* __restrict__ m1, const float* __restrict__ v1,
                            const float* __restrict__ g2, const float* __restrict__ b2,
                            const float* __restrict__ m2, const float* __restrict__ v2,
                            unsigned short* __restrict__ A1bf, unsigned short* __restrict__ A2bf,
                            unsigned short* __restrict__ P2bf, float* __restrict__ P1p,
                            float* __restrict__ ab1f, float* __restrict__ bn2s_c) {
    int t = threadIdx.x;
    if (t < HH) {
        float s = g1[t] * rsqrtf(v1[t] + EPSV);
        float c = b1[t] - m1[t] * s;
        P1p[4 * t + 0] = P1[3 * t + 0] * s;
        P1p[4 * t + 1] = P1[3 * t + 1] * s;
        P1p[4 * t + 2] = P1[3 * t + 2] * s;
        P1p[4 * t + 3] = pb1[t] * s + c;
    }
    if (t < AH) {
        float s = g2[t] * rsqrtf(v2[t] + EPSV);
        bn2s_c[t] = s;
        ab1f[t] = ab1[t] * s + (b2[t] - m2[t] * s);
    }
    for (int i = t; i < AH * CC; i += 256) A1bf[i] = f2bf(A1[i]);
    for (int i = t; i < CC * AH; i += 256) A2bf[i] = f2bf(A2[i]);
    for (int i = t; i < CC * HH; i += 256) P2bf[i] = f2bf(P2[i]);
}

// ---------------------------------------------------------------------------
// Kernel 2: y1 = Ws*y+bs, key = Wk*y1+bk, query = Wq*x+bq  (point-major out)
// ---------------------------------------------------------------------------
__global__ void prep_features(const float* __restrict__ x, const float* __restrict__ y,
                              const float* __restrict__ Ws, const float* __restrict__ bs,
                              const float* __restrict__ Wk, const float* __restrict__ bk,
                              const float* __restrict__ Wq, const float* __restrict__ bq,
                              float* __restrict__ y1_t, float* __restrict__ key_t,
                              float* __restrict__ qry_t) {
    int gid = blockIdx.x * blockDim.x + threadIdx.x;  // 0..B*N-1
    int b = gid >> 12;
    int n = gid & (NN - 1);

    float yv[CC];
#pragma unroll
    for (int c = 0; c < CC; ++c) yv[c] = y[((size_t)(b * CC + c)) * NN + n];

    float y1v[CC];
#pragma unroll 4
    for (int o = 0; o < CC; ++o) {
        const float* wr = Ws + o * CC;
        float s0 = 0.f, s1 = 0.f, s2 = 0.f, s3 = 0.f;
#pragma unroll
        for (int d = 0; d < 16; ++d) {
            s0 += wr[4 * d + 0] * yv[4 * d + 0];
            s1 += wr[4 * d + 1] * yv[4 * d + 1];
            s2 += wr[4 * d + 2] * yv[4 * d + 2];
            s3 += wr[4 * d + 3] * yv[4 * d + 3];
        }
        y1v[o] = (s0 + s1) + (s2 + s3) + bs[o];
    }

    float* y1o = y1_t + (size_t)gid * CC;
#pragma unroll
    for (int o = 0; o < CC; ++o) y1o[o] = y1v[o];

    float* ko = key_t + (size_t)gid * CC;
#pragma unroll 4
    for (int o = 0; o < CC; ++o) {
        const float* wr = Wk + o * CC;
        float s0 = 0.f, s1 = 0.f, s2 = 0.f, s3 = 0.f;
#pragma unroll
        for (int d = 0; d < 16; ++d) {
            s0 += wr[4 * d + 0] * y1v[4 * d + 0];
            s1 += wr[4 * d + 1] * y1v[4 * d + 1];
            s2 += wr[4 * d + 2] * y1v[4 * d + 2];
            s3 += wr[4 * d + 3] * y1v[4 * d + 3];
        }
        ko[o] = (s0 + s1) + (s2 + s3) + bk[o];
    }

    float x0 = x[(size_t)(b * 3 + 0) * NN + n];
    float x1 = x[(size_t)(b * 3 + 1) * NN + n];
    float x2 = x[(size_t)(b * 3 + 2) * NN + n];
    float* qo = qry_t + (size_t)gid * CC;
#pragma unroll
    for (int o = 0; o < CC; ++o)
        qo[o] = Wq[o * 3 + 0] * x0 + Wq[o * 3 + 1] * x1 + Wq[o * 3 + 2] * x2 + bq[o];
}

// ---------------------------------------------------------------------------
// Kernel 3: exact KNN, branch-coherent 3-phase. 1 query/wave, 4 waves/block.
// LDS = single 64 KiB block: float4 pts[4096]; survivor buffer ALIASES the
// first 4 KiB (pts is dead after phase 1 — distances cached in registers;
// a barrier separates the last pts read from the first surv write).
// Phase 1: per-lane min over 64-candidate slice (dists -> dreg[64] regs),
//          sort64 lane-mins -> T = 16th smallest (exact bound: d16 <= T).
// Phase 2: register re-test, ballot-compact (d <= T) into surv (cap 128).
// Phase 3: cross-lane bitonic-128 on u64 (dist,idx) == top_k tie-break.
// ---------------------------------------------------------------------------
__global__ __launch_bounds__(256) void knn_kernel(const float* __restrict__ x,
                                                  int* __restrict__ idx_out) {
    __shared__ __align__(16) char smem[65536];            // exactly 64 KiB
    float4* pts = (float4*)smem;                          // [NN] = 64 KiB
    unsigned long long* surv = (unsigned long long*)smem; // [4*128] = 4 KiB alias

    int b = blockIdx.x >> 10;
    int grp = blockIdx.x & 1023;
    int w = threadIdx.x >> 6;
    int lane = threadIdx.x & 63;
    int n = (grp << 2) + w;

    const float* xb = x + (size_t)b * 3 * NN;
    for (int i = threadIdx.x; i < NN; i += 256)
        pts[i] = make_float4(xb[i], xb[NN + i], xb[2 * NN + i], 0.f);
    __syncthreads();

    float4 q = pts[n];

    // ---- phase 1: distances into registers, running min ----
    float dreg[64];
    float vmin = 3.4e38f;
#pragma unroll
    for (int r = 0; r < 64; ++r) {
        float4 c = pts[(r << 6) + lane];
        float ax = q.x - c.x, ay = q.y - c.y, az = q.z - c.z;
        float d = ax * ax + ay * ay + az * az;
        dreg[r] = d;
        vmin = fminf(vmin, d);
    }
    // bitonic sort 64 lane-mins ascending
#pragma unroll
    for (int k = 2; k <= 64; k <<= 1) {
#pragma unroll
        for (int j = k >> 1; j > 0; j >>= 1) {
            float o = __shfl_xor(vmin, j);
            bool lower = (lane & j) == 0;
            bool up = (lane & k) == 0;   // k==64: always true (final ascending)
            float mn = fminf(vmin, o), mx = fmaxf(vmin, o);
            vmin = (lower == up) ? mn : mx;
        }
    }
    float T = __shfl(vmin, 15);   // 16th smallest lane-min >= d16

    __syncthreads();   // all waves done reading pts; safe to overwrite w/ surv

    // ---- phase 2: ballot-compact survivors (d <= T) from registers ----
    unsigned long long* buf = surv + (w << 7);
    unsigned cnt = 0;
#pragma unroll
    for (int r = 0; r < 64; ++r) {
        float d = dreg[r];
        bool hit = d <= T;
        unsigned long long mask = __ballot(hit);
        if (hit) {
            unsigned off = cnt + (unsigned)__popcll(mask & ((1ull << lane) - 1ull));
            if (off < 128) {
                int j = (r << 6) + lane;
                buf[off] = ((unsigned long long)__float_as_uint(d) << 32) | (unsigned)j;
            }
        }
        cnt += (unsigned)__popcll(mask);
    }
    if (cnt > 128) cnt = 128;

    // ---- phase 3: bitonic sort up to 128 survivor keys, take 16 smallest ----
    unsigned long long v0 = (lane < (int)cnt) ? buf[lane] : 0xFFFFFFFFFFFFFFFFull;
    unsigned long long v1 = (lane + 64 < (int)cnt) ? buf[lane + 64] : 0xFFFFFFFFFFFFFFFFull;
#pragma unroll
    for (int k = 2; k <= 128; k <<= 1) {
#pragma unroll
        for (int j = k >> 1; j > 0; j >>= 1) {
            if (j >= 64) {
                unsigned long long lo = umin64(v0, v1), hi = umax64(v0, v1);
                v0 = lo; v1 = hi;
            } else {
                bool lower = (lane & j) == 0;
                unsigned long long o0 = shfl_xor_u64(v0, j);
                bool up0 = ((lane & k) == 0);                 // element e0 = lane
                v0 = (lower == up0) ? umin64(v0, o0) : umax64(v0, o0);
                unsigned long long o1 = shfl_xor_u64(v1, j);
                bool up1 = (((64 + lane) & k) == 0);          // element e1 = 64+lane
                v1 = (lower == up1) ? umin64(v1, o1) : umax64(v1, o1);
            }
        }
    }
    if (lane < KNN)
        idx_out[((size_t)b * NN + n) * KNN + lane] = (int)(unsigned)(v0 & 0xFFFFFFFFull);
}

// ---------------------------------------------------------------------------
// Kernel 4: fused MFMA attention (unchanged from round 3 — verified).
// ---------------------------------------------------------------------------
#define UPITCH 68
#define HPITCH 260

__device__ __forceinline__ short8 lds_frag(const unsigned short* p) {
    short4v lo = *(const short4v*)p;
    short4v hi = *(const short4v*)(p + 4);
    short8 v;
    v[0] = lo[0]; v[1] = lo[1]; v[2] = lo[2]; v[3] = lo[3];
    v[4] = hi[0]; v[5] = hi[1]; v[6] = hi[2]; v[7] = hi[3];
    return v;
}

__global__ __launch_bounds__(256, 3) void attn_mfma(
    const float* __restrict__ x, const float* __restrict__ y,
    const float* __restrict__ y1_t, const float* __restrict__ key_t,
    const float* __restrict__ qry_t, const int* __restrict__ idx,
    const float* __restrict__ P1p, const unsigned short* __restrict__ P2bf,
    const float* __restrict__ pb2, const unsigned short* __restrict__ A1bf,
    const float* __restrict__ ab1f, const float* __restrict__ bn2s_c,
    const unsigned short* __restrict__ A2bf,
    const float* __restrict__ Wend, const float* __restrict__ bend,
    float* __restrict__ out) {
    __shared__ unsigned short u_lds[64 * UPITCH];
    __shared__ unsigned short hid_lds[64 * HPITCH];
    __shared__ float agg_lds[4 * 64];
    __shared__ float outstage[64 * 4];

    int blk = blockIdx.x;
    int b = blk >> 10;
    int n0 = (blk & 1023) << 2;
    int w = threadIdx.x >> 6;
    int lane = threadIdx.x & 63;
    int m = lane & 15, quad = lane >> 4;
    int pt = n0 + w;
    size_t bpt = (size_t)b * NN + pt;

    int jm = idx[bpt * KNN + m];
    float dx = x[(size_t)(b * 3 + 0) * NN + pt] - x[(size_t)(b * 3 + 0) * NN + jm];
    float dy = x[(size_t)(b * 3 + 1) * NN + pt] - x[(size_t)(b * 3 + 1) * NN + jm];
    float dz = x[(size_t)(b * 3 + 2) * NN + pt] - x[(size_t)(b * 3 + 2) * NN + jm];
    short8 h1A[2];
#pragma unroll
    for (int ks = 0; ks < 2; ++ks) {
#pragma unroll
        for (int j = 0; j < 8; ++j) {
            int h1 = ks * 32 + quad * 8 + j;
            const float4 p = *(const float4*)(P1p + 4 * h1);
            float a = fmaxf(p.x * dx + p.y * dy + p.z * dz + p.w, 0.f);
            h1A[ks][j] = (short)f2bf(a);
        }
    }

    floatx4 pacc[4];
#pragma unroll
    for (int nt = 0; nt < 4; ++nt) pacc[nt] = (floatx4){0.f, 0.f, 0.f, 0.f};
#pragma unroll
    for (int ks = 0; ks < 2; ++ks) {
#pragma unroll
        for (int nt = 0; nt < 4; ++nt) {
            short8 bb = *(const short8*)(P2bf + (nt * 16 + m) * HH + ks * 32 + quad * 8);
            pacc[nt] = __builtin_amdgcn_mfma_f32_16x16x32_bf16(h1A[ks], bb, pacc[nt], 0, 0, 0);
        }
    }
#pragma unroll
    for (int nt = 0; nt < 4; ++nt) {
        float pb = pb2[nt * 16 + m];
#pragma unroll
        for (int r = 0; r < 4; ++r) pacc[nt][r] += pb;
    }

    int j4[4];
#pragma unroll
    for (int r = 0; r < 4; ++r) j4[r] = idx[bpt * KNN + 4 * quad + r];
#pragma unroll
    for (int nt = 0; nt < 4; ++nt) {
        float qv = qry_t[bpt * CC + nt * 16 + m];
#pragma unroll
        for (int r = 0; r < 4; ++r) {
            float kv = key_t[((size_t)b * NN + j4[r]) * CC + nt * 16 + m];
            float uu = qv - kv + pacc[nt][r];
            u_lds[(w * 16 + 4 * quad + r) * UPITCH + nt * 16 + m] = f2bf(uu);
        }
    }

    short8 uA[2];
#pragma unroll
    for (int ks = 0; ks < 2; ++ks)
        uA[ks] = lds_frag(&u_lds[(w * 16 + m) * UPITCH + ks * 32 + quad * 8]);

#pragma unroll 1
    for (int nt = 0; nt < 16; ++nt) {
        const unsigned short* brow = A1bf + (nt * 16 + m) * CC;
        short8 b0 = *(const short8*)(brow + quad * 8);
        short8 b1 = *(const short8*)(brow + 32 + quad * 8);
        floatx4 acc = (floatx4){0.f, 0.f, 0.f, 0.f};
        acc = __builtin_amdgcn_mfma_f32_16x16x32_bf16(uA[0], b0, acc, 0, 0, 0);
        acc = __builtin_amdgcn_mfma_f32_16x16x32_bf16(uA[1], b1, acc, 0, 0, 0);
        int h = nt * 16 + m;
        float s = bn2s_c[h], t0 = ab1f[h];
#pragma unroll
        for (int r = 0; r < 4; ++r) {
            float hv = fmaxf(acc[r] * s + t0, 0.f);
            hid_lds[(w * 16 + 4 * quad + r) * HPITCH + h] = f2bf(hv);
        }
    }

    floatx4 acc2[4];
#pragma unroll
    for (int nt = 0; nt < 4; ++nt) acc2[nt] = (floatx4){0.f, 0.f, 0.f, 0.f};
#pragma unroll 1
    for (int ks = 0; ks < 8; ++ks) {
        short8 hA = lds_frag(&hid_lds[(w * 16 + m) * HPITCH + ks * 32 + quad * 8]);
#pragma unroll
        for (int nt = 0; nt < 4; ++nt) {
            short8 bb = *(const short8*)(A2bf + (nt * 16 + m) * AH + ks * 32 + quad * 8);
            acc2[nt] = __builtin_amdgcn_mfma_f32_16x16x32_bf16(hA, bb, acc2[nt], 0, 0, 0);
        }
    }

#pragma unroll
    for (int nt = 0; nt < 4; ++nt) {
        float l0 = acc2[nt][0], l1 = acc2[nt][1], l2 = acc2[nt][2], l3 = acc2[nt][3];
        float mx = fmaxf(fmaxf(l0, l1), fmaxf(l2, l3));
        mx = fmaxf(mx, __shfl_xor(mx, 16));
        mx = fmaxf(mx, __shfl_xor(mx, 32));
        float e0 = __expf(l0 - mx), e1 = __expf(l1 - mx);
        float e2 = __expf(l2 - mx), e3 = __expf(l3 - mx);
        float sum = (e0 + e1) + (e2 + e3);
        sum += __shfl_xor(sum, 16);
        sum += __shfl_xor(sum, 32);
        float y1v = y1_t[bpt * CC + nt * 16 + m];
        float contrib = e0 * (y1v + pacc[nt][0]) + e1 * (y1v + pacc[nt][1]) +
                        e2 * (y1v + pacc[nt][2]) + e3 * (y1v + pacc[nt][3]);
        contrib += __shfl_xor(contrib, 16);
        contrib += __shfl_xor(contrib, 32);
        float agg = contrib / sum;
        if (quad == 0) agg_lds[w * 64 + nt * 16 + m] = agg;
    }

    float acco = 0.f;
#pragma unroll
    for (int c4 = 0; c4 < 16; ++c4) {
        float4 wv = *(const float4*)(Wend + lane * CC + c4 * 4);
        float4 av = *(const float4*)(agg_lds + w * 64 + c4 * 4);
        acco += wv.x * av.x + wv.y * av.y + wv.z * av.z + wv.w * av.w;
    }
    acco += bend[lane];
    outstage[lane * 4 + w] = acco;
    __syncthreads();

    int t = threadIdx.x;
    int o = t >> 2, p = t & 3;
    size_t oi = ((size_t)(b * CC + o)) * NN + n0 + p;
    out[oi] = outstage[t] + y[oi];
}

// ---------------------------------------------------------------------------
extern "C" void kernel_launch(void* const* d_in, const int* in_sizes, int n_in,
                              void* d_out, int out_size, void* d_ws, size_t ws_size,
                              hipStream_t stream) {
    const float* x    = (const float*)d_in[0];
    const float* y    = (const float*)d_in[1];
    const float* Ws   = (const float*)d_in[2];
    const float* bs   = (const float*)d_in[3];
    const float* Wk   = (const float*)d_in[4];
    const float* bk   = (const float*)d_in[5];
    const float* Wq   = (const float*)d_in[6];
    const float* bq   = (const float*)d_in[7];
    const float* P1   = (const float*)d_in[8];
    const float* pb1  = (const float*)d_in[9];
    const float* g1   = (const float*)d_in[10];
    const float* b1   = (const float*)d_in[11];
    const float* m1   = (const float*)d_in[12];
    const float* v1   = (const float*)d_in[13];
    const float* P2   = (const float*)d_in[14];
    const float* pb2  = (const float*)d_in[15];
    const float* A1   = (const float*)d_in[16];
    const float* ab1  = (const float*)d_in[17];
    const float* g2   = (const float*)d_in[18];
    const float* b2   = (const float*)d_in[19];
    const float* m2   = (const float*)d_in[20];
    const float* v2   = (const float*)d_in[21];
    const float* A2   = (const float*)d_in[22];
    const float* ab2  = (const float*)d_in[23];  // dropped (softmax-invariant)
    const float* Wend = (const float*)d_in[24];
    const float* bend = (const float*)d_in[25];
    (void)ab2;

    float* ws    = (float*)d_ws;
    float* y1_t  = ws;                           // 1,048,576 f
    float* key_t = ws + 1048576;                 // 1,048,576 f
    float* qry_t = ws + 2097152;                 // 1,048,576 f
    int*   idx   = (int*)(ws + 3145728);         // 262,144 i
    unsigned short* A1bf = (unsigned short*)(ws + 3407872);  // 16384 bf16
    unsigned short* A2bf = (unsigned short*)(ws + 3416064);  // 16384 bf16
    unsigned short* P2bf = (unsigned short*)(ws + 3424256);  // 4096 bf16
    float* P1p   = ws + 3426304;                 // 256 f
    float* ab1f  = ws + 3426560;                 // 256 f
    float* bn2sc = ws + 3426816;                 // 256 f
    float* out   = (float*)d_out;

    hipLaunchKernelGGL(prep_params, dim3(1), dim3(256), 0, stream,
                       P1, pb1, P2, A1, ab1, A2, g1, b1, m1, v1, g2, b2, m2, v2,
                       A1bf, A2bf, P2bf, P1p, ab1f, bn2sc);
    hipLaunchKernelGGL(prep_features, dim3(128), dim3(128), 0, stream,
                       x, y, Ws, bs, Wk, bk, Wq, bq, y1_t, key_t, qry_t);
    hipLaunchKernelGGL(knn_kernel, dim3(4096), dim3(256), 0, stream, x, idx);
    hipLaunchKernelGGL(attn_mfma, dim3(4096), dim3(256), 0, stream,
                       x, y, y1_t, key_t, qry_t, idx,
                       P1p, P2bf, pb2, A1bf, ab1f, bn2sc, A2bf,
                       Wend, bend, out);
}

// Round 6
// 441.464 us; speedup vs baseline: 4.1438x; 1.2966x over previous
//
#include <hip/hip_runtime.h>
#include <hip/hip_bf16.h>

#define BB 4
#define CC 64
#define NN 4096
#define HH 64
#define AH 256
#define KNN 16
#define EPSV 1e-5f

typedef __attribute__((ext_vector_type(8))) short short8;
typedef __attribute__((ext_vector_type(4))) short short4v;
typedef __attribute__((ext_vector_type(4))) float floatx4;

__device__ __forceinline__ unsigned short f2bf(float f) {
    unsigned u = __float_as_uint(f);
    u += 0x7FFFu + ((u >> 16) & 1u);   // round-to-nearest-even
    return (unsigned short)(u >> 16);
}

__device__ __forceinline__ unsigned long long umin64(unsigned long long a, unsigned long long b) {
    return a < b ? a : b;
}
__device__ __forceinline__ unsigned long long umax64(unsigned long long a, unsigned long long b) {
    return a > b ? a : b;
}
__device__ __forceinline__ unsigned long long shfl_xor_u64(unsigned long long v, int m) {
    int lo = __shfl_xor((int)(unsigned)(v & 0xFFFFFFFFull), m);
    int hi = __shfl_xor((int)(unsigned)(v >> 32), m);
    return ((unsigned long long)(unsigned)hi << 32) | (unsigned)lo;
}

// ---------------------------------------------------------------------------
// Kernel 1: fold BN params; emit bf16 weight copies in MFMA-friendly layouts.
// ---------------------------------------------------------------------------
__global__ void prep_params(const float* __restrict__ P1, const float* __restrict__ pb1,
                            const float* __restrict__ P2, const float* __restrict__ A1,
                            const float* __restrict__ ab1, const float* __restrict__ A2,
                            const float* __restrict__ g1, const float* __restrict__ b1,
                            const float* __restrict__ m1, const float* __restrict__ v1,
                            const float* __restrict__ g2, const float* __restrict__ b2,
                            const float* __restrict__ m2, const float* __restrict__ v2,
                            unsigned short* __restrict__ A1bf, unsigned short* __restrict__ A2bf,
                            unsigned short* __restrict__ P2bf, float* __restrict__ P1p,
                            float* __restrict__ ab1f, float* __restrict__ bn2s_c) {
    int t = threadIdx.x;
    if (t < HH) {
        float s = g1[t] * rsqrtf(v1[t] + EPSV);
        float c = b1[t] - m1[t] * s;
        P1p[4 * t + 0] = P1[3 * t + 0] * s;
        P1p[4 * t + 1] = P1[3 * t + 1] * s;
        P1p[4 * t + 2] = P1[3 * t + 2] * s;
        P1p[4 * t + 3] = pb1[t] * s + c;
    }
    if (t < AH) {
        float s = g2[t] * rsqrtf(v2[t] + EPSV);
        bn2s_c[t] = s;
        ab1f[t] = ab1[t] * s + (b2[t] - m2[t] * s);
    }
    for (int i = t; i < AH * CC; i += 256) A1bf[i] = f2bf(A1[i]);
    for (int i = t; i < CC * AH; i += 256) A2bf[i] = f2bf(A2[i]);
    for (int i = t; i < CC * HH; i += 256) P2bf[i] = f2bf(P2[i]);
}

// ---------------------------------------------------------------------------
// Kernel 2: prep features. 16 points/block, 16 threads/point, 4 channels each.
// y staged in LDS; y1 round-trips through LDS for the key phase. All global
// writes coalesced float4. 1024 blocks x 4 waves = 16 waves/CU.
// ---------------------------------------------------------------------------
__global__ __launch_bounds__(256) void prep_features(
    const float* __restrict__ x, const float* __restrict__ y,
    const float* __restrict__ Ws, const float* __restrict__ bs,
    const float* __restrict__ Wk, const float* __restrict__ bk,
    const float* __restrict__ Wq, const float* __restrict__ bq,
    float* __restrict__ y1_t, float* __restrict__ key_t,
    float* __restrict__ qry_t) {
    __shared__ float y_s[16][68];    // 68-pad: float4-aligned rows (272 B)
    __shared__ float y1_s[16][68];

    int b = blockIdx.x >> 8;           // 256 blocks per batch
    int n0 = (blockIdx.x & 255) << 4;  // 16 points per block
    int tid = threadIdx.x;
    int p = tid >> 4, g = tid & 15;
    int n = n0 + p;
    size_t bpt = (size_t)b * NN + n;

    // stage y: rows c (64), 16 consecutive points each
    for (int i = tid; i < 16 * CC; i += 256) {
        int c = i >> 4, nn = i & 15;
        y_s[nn][c] = y[((size_t)(b * CC + c)) * NN + n0 + nn];
    }
    __syncthreads();

    float yv[CC];
#pragma unroll
    for (int c4 = 0; c4 < 16; ++c4) {
        float4 v = *(const float4*)&y_s[p][c4 * 4];
        yv[4 * c4 + 0] = v.x; yv[4 * c4 + 1] = v.y;
        yv[4 * c4 + 2] = v.z; yv[4 * c4 + 3] = v.w;
    }

    // y1 = Ws*y + bs  (4 outputs per thread)
    float o1[4];
#pragma unroll
    for (int i = 0; i < 4; ++i) {
        int o = g * 4 + i;
        const float4* wr = (const float4*)(Ws + o * CC);
        float s0 = 0.f, s1 = 0.f, s2 = 0.f, s3 = 0.f;
#pragma unroll
        for (int d = 0; d < 16; ++d) {
            float4 w = wr[d];
            s0 += w.x * yv[4 * d + 0];
            s1 += w.y * yv[4 * d + 1];
            s2 += w.z * yv[4 * d + 2];
            s3 += w.w * yv[4 * d + 3];
        }
        o1[i] = (s0 + s1) + (s2 + s3) + bs[o];
        y1_s[p][o] = o1[i];
    }
    *(float4*)(y1_t + bpt * CC + g * 4) = make_float4(o1[0], o1[1], o1[2], o1[3]);
    __syncthreads();

    float y1v[CC];
#pragma unroll
    for (int c4 = 0; c4 < 16; ++c4) {
        float4 v = *(const float4*)&y1_s[p][c4 * 4];
        y1v[4 * c4 + 0] = v.x; y1v[4 * c4 + 1] = v.y;
        y1v[4 * c4 + 2] = v.z; y1v[4 * c4 + 3] = v.w;
    }

    // key = Wk*y1 + bk
    float ok[4];
#pragma unroll
    for (int i = 0; i < 4; ++i) {
        int o = g * 4 + i;
        const float4* wr = (const float4*)(Wk + o * CC);
        float s0 = 0.f, s1 = 0.f, s2 = 0.f, s3 = 0.f;
#pragma unroll
        for (int d = 0; d < 16; ++d) {
            float4 w = wr[d];
            s0 += w.x * y1v[4 * d + 0];
            s1 += w.y * y1v[4 * d + 1];
            s2 += w.z * y1v[4 * d + 2];
            s3 += w.w * y1v[4 * d + 3];
        }
        ok[i] = (s0 + s1) + (s2 + s3) + bk[o];
    }
    *(float4*)(key_t + bpt * CC + g * 4) = make_float4(ok[0], ok[1], ok[2], ok[3]);

    // query = Wq*x + bq
    float x0 = x[(size_t)(b * 3 + 0) * NN + n];
    float x1 = x[(size_t)(b * 3 + 1) * NN + n];
    float x2 = x[(size_t)(b * 3 + 2) * NN + n];
    float oq[4];
#pragma unroll
    for (int i = 0; i < 4; ++i) {
        int o = g * 4 + i;
        oq[i] = Wq[o * 3 + 0] * x0 + Wq[o * 3 + 1] * x1 + Wq[o * 3 + 2] * x2 + bq[o];
    }
    *(float4*)(qry_t + bpt * CC + g * 4) = make_float4(oq[0], oq[1], oq[2], oq[3]);
}

// ---------------------------------------------------------------------------
// Kernel 3: exact KNN, branch-coherent 3-phase (unchanged from round 5).
// ---------------------------------------------------------------------------
__global__ __launch_bounds__(256) void knn_kernel(const float* __restrict__ x,
                                                  int* __restrict__ idx_out) {
    __shared__ __align__(16) char smem[65536];            // exactly 64 KiB
    float4* pts = (float4*)smem;                          // [NN] = 64 KiB
    unsigned long long* surv = (unsigned long long*)smem; // [4*128] = 4 KiB alias

    int b = blockIdx.x >> 10;
    int grp = blockIdx.x & 1023;
    int w = threadIdx.x >> 6;
    int lane = threadIdx.x & 63;
    int n = (grp << 2) + w;

    const float* xb = x + (size_t)b * 3 * NN;
    for (int i = threadIdx.x; i < NN; i += 256)
        pts[i] = make_float4(xb[i], xb[NN + i], xb[2 * NN + i], 0.f);
    __syncthreads();

    float4 q = pts[n];

    float dreg[64];
    float vmin = 3.4e38f;
#pragma unroll
    for (int r = 0; r < 64; ++r) {
        float4 c = pts[(r << 6) + lane];
        float ax = q.x - c.x, ay = q.y - c.y, az = q.z - c.z;
        float d = ax * ax + ay * ay + az * az;
        dreg[r] = d;
        vmin = fminf(vmin, d);
    }
#pragma unroll
    for (int k = 2; k <= 64; k <<= 1) {
#pragma unroll
        for (int j = k >> 1; j > 0; j >>= 1) {
            float o = __shfl_xor(vmin, j);
            bool lower = (lane & j) == 0;
            bool up = (lane & k) == 0;
            float mn = fminf(vmin, o), mx = fmaxf(vmin, o);
            vmin = (lower == up) ? mn : mx;
        }
    }
    float T = __shfl(vmin, 15);

    __syncthreads();

    unsigned long long* buf = surv + (w << 7);
    unsigned cnt = 0;
#pragma unroll
    for (int r = 0; r < 64; ++r) {
        float d = dreg[r];
        bool hit = d <= T;
        unsigned long long mask = __ballot(hit);
        if (hit) {
            unsigned off = cnt + (unsigned)__popcll(mask & ((1ull << lane) - 1ull));
            if (off < 128) {
                int j = (r << 6) + lane;
                buf[off] = ((unsigned long long)__float_as_uint(d) << 32) | (unsigned)j;
            }
        }
        cnt += (unsigned)__popcll(mask);
    }
    if (cnt > 128) cnt = 128;

    unsigned long long v0 = (lane < (int)cnt) ? buf[lane] : 0xFFFFFFFFFFFFFFFFull;
    unsigned long long v1 = (lane + 64 < (int)cnt) ? buf[lane + 64] : 0xFFFFFFFFFFFFFFFFull;
#pragma unroll
    for (int k = 2; k <= 128; k <<= 1) {
#pragma unroll
        for (int j = k >> 1; j > 0; j >>= 1) {
            if (j >= 64) {
                unsigned long long lo = umin64(v0, v1), hi = umax64(v0, v1);
                v0 = lo; v1 = hi;
            } else {
                bool lower = (lane & j) == 0;
                unsigned long long o0 = shfl_xor_u64(v0, j);
                bool up0 = ((lane & k) == 0);
                v0 = (lower == up0) ? umin64(v0, o0) : umax64(v0, o0);
                unsigned long long o1 = shfl_xor_u64(v1, j);
                bool up1 = (((64 + lane) & k) == 0);
                v1 = (lower == up1) ? umin64(v1, o1) : umax64(v1, o1);
            }
        }
    }
    if (lane < KNN)
        idx_out[((size_t)b * NN + n) * KNN + lane] = (int)(unsigned)(v0 & 0xFFFFFFFFull);
}

// ---------------------------------------------------------------------------
// Kernel 4: fused MFMA attention (unchanged — verified).
// ---------------------------------------------------------------------------
#define UPITCH 68
#define HPITCH 260

__device__ __forceinline__ short8 lds_frag(const unsigned short* p) {
    short4v lo = *(const short4v*)p;
    short4v hi = *(const short4v*)(p + 4);
    short8 v;
    v[0] = lo[0]; v[1] = lo[1]; v[2] = lo[2]; v[3] = lo[3];
    v[4] = hi[0]; v[5] = hi[1]; v[6] = hi[2]; v[7] = hi[3];
    return v;
}

__global__ __launch_bounds__(256, 3) void attn_mfma(
    const float* __restrict__ x, const float* __restrict__ y,
    const float* __restrict__ y1_t, const float* __restrict__ key_t,
    const float* __restrict__ qry_t, const int* __restrict__ idx,
    const float* __restrict__ P1p, const unsigned short* __restrict__ P2bf,
    const float* __restrict__ pb2, const unsigned short* __restrict__ A1bf,
    const float* __restrict__ ab1f, const float* __restrict__ bn2s_c,
    const unsigned short* __restrict__ A2bf,
    const float* __restrict__ Wend, const float* __restrict__ bend,
    float* __restrict__ out) {
    __shared__ unsigned short u_lds[64 * UPITCH];
    __shared__ unsigned short hid_lds[64 * HPITCH];
    __shared__ float agg_lds[4 * 64];
    __shared__ float outstage[64 * 4];

    int blk = blockIdx.x;
    int b = blk >> 10;
    int n0 = (blk & 1023) << 2;
    int w = threadIdx.x >> 6;
    int lane = threadIdx.x & 63;
    int m = lane & 15, quad = lane >> 4;
    int pt = n0 + w;
    size_t bpt = (size_t)b * NN + pt;

    int jm = idx[bpt * KNN + m];
    float dx = x[(size_t)(b * 3 + 0) * NN + pt] - x[(size_t)(b * 3 + 0) * NN + jm];
    float dy = x[(size_t)(b * 3 + 1) * NN + pt] - x[(size_t)(b * 3 + 1) * NN + jm];
    float dz = x[(size_t)(b * 3 + 2) * NN + pt] - x[(size_t)(b * 3 + 2) * NN + jm];
    short8 h1A[2];
#pragma unroll
    for (int ks = 0; ks < 2; ++ks) {
#pragma unroll
        for (int j = 0; j < 8; ++j) {
            int h1 = ks * 32 + quad * 8 + j;
            const float4 p = *(const float4*)(P1p + 4 * h1);
            float a = fmaxf(p.x * dx + p.y * dy + p.z * dz + p.w, 0.f);
            h1A[ks][j] = (short)f2bf(a);
        }
    }

    floatx4 pacc[4];
#pragma unroll
    for (int nt = 0; nt < 4; ++nt) pacc[nt] = (floatx4){0.f, 0.f, 0.f, 0.f};
#pragma unroll
    for (int ks = 0; ks < 2; ++ks) {
#pragma unroll
        for (int nt = 0; nt < 4; ++nt) {
            short8 bb = *(const short8*)(P2bf + (nt * 16 + m) * HH + ks * 32 + quad * 8);
            pacc[nt] = __builtin_amdgcn_mfma_f32_16x16x32_bf16(h1A[ks], bb, pacc[nt], 0, 0, 0);
        }
    }
#pragma unroll
    for (int nt = 0; nt < 4; ++nt) {
        float pb = pb2[nt * 16 + m];
#pragma unroll
        for (int r = 0; r < 4; ++r) pacc[nt][r] += pb;
    }

    int j4[4];
#pragma unroll
    for (int r = 0; r < 4; ++r) j4[r] = idx[bpt * KNN + 4 * quad + r];
#pragma unroll
    for (int nt = 0; nt < 4; ++nt) {
        float qv = qry_t[bpt * CC + nt * 16 + m];
#pragma unroll
        for (int r = 0; r < 4; ++r) {
            float kv = key_t[((size_t)b * NN + j4[r]) * CC + nt * 16 + m];
            float uu = qv - kv + pacc[nt][r];
            u_lds[(w * 16 + 4 * quad + r) * UPITCH + nt * 16 + m] = f2bf(uu);
        }
    }

    short8 uA[2];
#pragma unroll
    for (int ks = 0; ks < 2; ++ks)
        uA[ks] = lds_frag(&u_lds[(w * 16 + m) * UPITCH + ks * 32 + quad * 8]);

#pragma unroll 1
    for (int nt = 0; nt < 16; ++nt) {
        const unsigned short* brow = A1bf + (nt * 16 + m) * CC;
        short8 b0 = *(const short8*)(brow + quad * 8);
        short8 b1 = *(const short8*)(brow + 32 + quad * 8);
        floatx4 acc = (floatx4){0.f, 0.f, 0.f, 0.f};
        acc = __builtin_amdgcn_mfma_f32_16x16x32_bf16(uA[0], b0, acc, 0, 0, 0);
        acc = __builtin_amdgcn_mfma_f32_16x16x32_bf16(uA[1], b1, acc, 0, 0, 0);
        int h = nt * 16 + m;
        float s = bn2s_c[h], t0 = ab1f[h];
#pragma unroll
        for (int r = 0; r < 4; ++r) {
            float hv = fmaxf(acc[r] * s + t0, 0.f);
            hid_lds[(w * 16 + 4 * quad + r) * HPITCH + h] = f2bf(hv);
        }
    }

    floatx4 acc2[4];
#pragma unroll
    for (int nt = 0; nt < 4; ++nt) acc2[nt] = (floatx4){0.f, 0.f, 0.f, 0.f};
#pragma unroll 1
    for (int ks = 0; ks < 8; ++ks) {
        short8 hA = lds_frag(&hid_lds[(w * 16 + m) * HPITCH + ks * 32 + quad * 8]);
#pragma unroll
        for (int nt = 0; nt < 4; ++nt) {
            short8 bb = *(const short8*)(A2bf + (nt * 16 + m) * AH + ks * 32 + quad * 8);
            acc2[nt] = __builtin_amdgcn_mfma_f32_16x16x32_bf16(hA, bb, acc2[nt], 0, 0, 0);
        }
    }

#pragma unroll
    for (int nt = 0; nt < 4; ++nt) {
        float l0 = acc2[nt][0], l1 = acc2[nt][1], l2 = acc2[nt][2], l3 = acc2[nt][3];
        float mx = fmaxf(fmaxf(l0, l1), fmaxf(l2, l3));
        mx = fmaxf(mx, __shfl_xor(mx, 16));
        mx = fmaxf(mx, __shfl_xor(mx, 32));
        float e0 = __expf(l0 - mx), e1 = __expf(l1 - mx);
        float e2 = __expf(l2 - mx), e3 = __expf(l3 - mx);
        float sum = (e0 + e1) + (e2 + e3);
        sum += __shfl_xor(sum, 16);
        sum += __shfl_xor(sum, 32);
        float y1v = y1_t[bpt * CC + nt * 16 + m];
        float contrib = e0 * (y1v + pacc[nt][0]) + e1 * (y1v + pacc[nt][1]) +
                        e2 * (y1v + pacc[nt][2]) + e3 * (y1v + pacc[nt][3]);
        contrib += __shfl_xor(contrib, 16);
        contrib += __shfl_xor(contrib, 32);
        float agg = contrib / sum;
        if (quad == 0) agg_lds[w * 64 + nt * 16 + m] = agg;
    }

    float acco = 0.f;
#pragma unroll
    for (int c4 = 0; c4 < 16; ++c4) {
        float4 wv = *(const float4*)(Wend + lane * CC + c4 * 4);
        float4 av = *(const float4*)(agg_lds + w * 64 + c4 * 4);
        acco += wv.x * av.x + wv.y * av.y + wv.z * av.z + wv.w * av.w;
    }
    acco += bend[lane];
    outstage[lane * 4 + w] = acco;
    __syncthreads();

    int t = threadIdx.x;
    int o = t >> 2, p = t & 3;
    size_t oi = ((size_t)(b * CC + o)) * NN + n0 + p;
    out[oi] = outstage[t] + y[oi];
}

// ---------------------------------------------------------------------------
extern "C" void kernel_launch(void* const* d_in, const int* in_sizes, int n_in,
                              void* d_out, int out_size, void* d_ws, size_t ws_size,
                              hipStream_t stream) {
    const float* x    = (const float*)d_in[0];
    const float* y    = (const float*)d_in[1];
    const float* Ws   = (const float*)d_in[2];
    const float* bs   = (const float*)d_in[3];
    const float* Wk   = (const float*)d_in[4];
    const float* bk   = (const float*)d_in[5];
    const float* Wq   = (const float*)d_in[6];
    const float* bq   = (const float*)d_in[7];
    const float* P1   = (const float*)d_in[8];
    const float* pb1  = (const float*)d_in[9];
    const float* g1   = (const float*)d_in[10];
    const float* b1   = (const float*)d_in[11];
    const float* m1   = (const float*)d_in[12];
    const float* v1   = (const float*)d_in[13];
    const float* P2   = (const float*)d_in[14];
    const float* pb2  = (const float*)d_in[15];
    const float* A1   = (const float*)d_in[16];
    const float* ab1  = (const float*)d_in[17];
    const float* g2   = (const float*)d_in[18];
    const float* b2   = (const float*)d_in[19];
    const float* m2   = (const float*)d_in[20];
    const float* v2   = (const float*)d_in[21];
    const float* A2   = (const float*)d_in[22];
    const float* ab2  = (const float*)d_in[23];  // dropped (softmax-invariant)
    const float* Wend = (const float*)d_in[24];
    const float* bend = (const float*)d_in[25];
    (void)ab2;

    float* ws    = (float*)d_ws;
    float* y1_t  = ws;                           // 1,048,576 f
    float* key_t = ws + 1048576;                 // 1,048,576 f
    float* qry_t = ws + 2097152;                 // 1,048,576 f
    int*   idx   = (int*)(ws + 3145728);         // 262,144 i
    unsigned short* A1bf = (unsigned short*)(ws + 3407872);  // 16384 bf16
    unsigned short* A2bf = (unsigned short*)(ws + 3416064);  // 16384 bf16
    unsigned short* P2bf = (unsigned short*)(ws + 3424256);  // 4096 bf16
    float* P1p   = ws + 3426304;                 // 256 f
    float* ab1f  = ws + 3426560;                 // 256 f
    float* bn2sc = ws + 3426816;                 // 256 f
    float* out   = (float*)d_out;

    hipLaunchKernelGGL(prep_params, dim3(1), dim3(256), 0, stream,
                       P1, pb1, P2, A1, ab1, A2, g1, b1, m1, v1, g2, b2, m2, v2,
                       A1bf, A2bf, P2bf, P1p, ab1f, bn2sc);
    hipLaunchKernelGGL(prep_features, dim3(1024), dim3(256), 0, stream,
                       x, y, Ws, bs, Wk, bk, Wq, bq, y1_t, key_t, qry_t);
    hipLaunchKernelGGL(knn_kernel, dim3(4096), dim3(256), 0, stream, x, idx);
    hipLaunchKernelGGL(attn_mfma, dim3(4096), dim3(256), 0, stream,
                       x, y, y1_t, key_t, qry_t, idx,
                       P1p, P2bf, pb2, A1bf, ab1f, bn2sc, A2bf,
                       Wend, bend, out);
}

// Round 7
// 437.385 us; speedup vs baseline: 4.1824x; 1.0093x over previous
//
#include <hip/hip_runtime.h>
#include <hip/hip_bf16.h>

#define BB 4
#define CC 64
#define NN 4096
#define HH 64
#define AH 256
#define KNN 16
#define EPSV 1e-5f

typedef __attribute__((ext_vector_type(8))) short short8;
typedef __attribute__((ext_vector_type(4))) short short4v;
typedef __attribute__((ext_vector_type(4))) unsigned short ushort4v;
typedef __attribute__((ext_vector_type(4))) float floatx4;

__device__ __forceinline__ unsigned short f2bf(float f) {
    unsigned u = __float_as_uint(f);
    u += 0x7FFFu + ((u >> 16) & 1u);   // round-to-nearest-even
    return (unsigned short)(u >> 16);
}
__device__ __forceinline__ float bf2f(unsigned short u) {
    return __uint_as_float(((unsigned)u) << 16);
}

__device__ __forceinline__ unsigned long long umin64(unsigned long long a, unsigned long long b) {
    return a < b ? a : b;
}
__device__ __forceinline__ unsigned long long umax64(unsigned long long a, unsigned long long b) {
    return a > b ? a : b;
}
__device__ __forceinline__ unsigned long long shfl_xor_u64(unsigned long long v, int m) {
    int lo = __shfl_xor((int)(unsigned)(v & 0xFFFFFFFFull), m);
    int hi = __shfl_xor((int)(unsigned)(v >> 32), m);
    return ((unsigned long long)(unsigned)hi << 32) | (unsigned)lo;
}

// ---------------------------------------------------------------------------
// Kernel 1: fold BN params; emit bf16 weight copies in MFMA-friendly layouts.
// ---------------------------------------------------------------------------
__global__ void prep_params(const float* __restrict__ P1, const float* __restrict__ pb1,
                            const float* __restrict__ P2, const float* __restrict__ A1,
                            const float* __restrict__ ab1, const float* __restrict__ A2,
                            const float* __restrict__ g1, const float* __restrict__ b1,
                            const float* __restrict__ m1, const float* __restrict__ v1,
                            const float* __restrict__ g2, const float* __restrict__ b2,
                            const float* __restrict__ m2, const float* __restrict__ v2,
                            unsigned short* __restrict__ A1bf, unsigned short* __restrict__ A2bf,
                            unsigned short* __restrict__ P2bf, float* __restrict__ P1p,
                            float* __restrict__ ab1f, float* __restrict__ bn2s_c) {
    int t = threadIdx.x;
    if (t < HH) {
        float s = g1[t] * rsqrtf(v1[t] + EPSV);
        float c = b1[t] - m1[t] * s;
        P1p[4 * t + 0] = P1[3 * t + 0] * s;
        P1p[4 * t + 1] = P1[3 * t + 1] * s;
        P1p[4 * t + 2] = P1[3 * t + 2] * s;
        P1p[4 * t + 3] = pb1[t] * s + c;
    }
    if (t < AH) {
        float s = g2[t] * rsqrtf(v2[t] + EPSV);
        bn2s_c[t] = s;
        ab1f[t] = ab1[t] * s + (b2[t] - m2[t] * s);
    }
    for (int i = t; i < AH * CC; i += 256) A1bf[i] = f2bf(A1[i]);
    for (int i = t; i < CC * AH; i += 256) A2bf[i] = f2bf(A2[i]);
    for (int i = t; i < CC * HH; i += 256) P2bf[i] = f2bf(P2[i]);
}

// ---------------------------------------------------------------------------
// Kernel 2: prep features -> bf16 outputs. 16 points/block, 16 threads/point.
// ---------------------------------------------------------------------------
__global__ __launch_bounds__(256) void prep_features(
    const float* __restrict__ x, const float* __restrict__ y,
    const float* __restrict__ Ws, const float* __restrict__ bs,
    const float* __restrict__ Wk, const float* __restrict__ bk,
    const float* __restrict__ Wq, const float* __restrict__ bq,
    unsigned short* __restrict__ y1bf, unsigned short* __restrict__ keybf,
    unsigned short* __restrict__ qrybf) {
    __shared__ float y_s[16][68];
    __shared__ float y1_s[16][68];

    int b = blockIdx.x >> 8;
    int n0 = (blockIdx.x & 255) << 4;
    int tid = threadIdx.x;
    int p = tid >> 4, g = tid & 15;
    int n = n0 + p;
    size_t bpt = (size_t)b * NN + n;

    for (int i = tid; i < 16 * CC; i += 256) {
        int c = i >> 4, nn = i & 15;
        y_s[nn][c] = y[((size_t)(b * CC + c)) * NN + n0 + nn];
    }
    __syncthreads();

    float yv[CC];
#pragma unroll
    for (int c4 = 0; c4 < 16; ++c4) {
        float4 v = *(const float4*)&y_s[p][c4 * 4];
        yv[4 * c4 + 0] = v.x; yv[4 * c4 + 1] = v.y;
        yv[4 * c4 + 2] = v.z; yv[4 * c4 + 3] = v.w;
    }

    float o1[4];
#pragma unroll
    for (int i = 0; i < 4; ++i) {
        int o = g * 4 + i;
        const float4* wr = (const float4*)(Ws + o * CC);
        float s0 = 0.f, s1 = 0.f, s2 = 0.f, s3 = 0.f;
#pragma unroll
        for (int d = 0; d < 16; ++d) {
            float4 w = wr[d];
            s0 += w.x * yv[4 * d + 0];
            s1 += w.y * yv[4 * d + 1];
            s2 += w.z * yv[4 * d + 2];
            s3 += w.w * yv[4 * d + 3];
        }
        o1[i] = (s0 + s1) + (s2 + s3) + bs[o];
        y1_s[p][o] = o1[i];
    }
    {
        ushort4v pk;
        pk[0] = f2bf(o1[0]); pk[1] = f2bf(o1[1]);
        pk[2] = f2bf(o1[2]); pk[3] = f2bf(o1[3]);
        *(ushort4v*)(y1bf + bpt * CC + g * 4) = pk;
    }
    __syncthreads();

    float y1v[CC];
#pragma unroll
    for (int c4 = 0; c4 < 16; ++c4) {
        float4 v = *(const float4*)&y1_s[p][c4 * 4];
        y1v[4 * c4 + 0] = v.x; y1v[4 * c4 + 1] = v.y;
        y1v[4 * c4 + 2] = v.z; y1v[4 * c4 + 3] = v.w;
    }

    float ok[4];
#pragma unroll
    for (int i = 0; i < 4; ++i) {
        int o = g * 4 + i;
        const float4* wr = (const float4*)(Wk + o * CC);
        float s0 = 0.f, s1 = 0.f, s2 = 0.f, s3 = 0.f;
#pragma unroll
        for (int d = 0; d < 16; ++d) {
            float4 w = wr[d];
            s0 += w.x * y1v[4 * d + 0];
            s1 += w.y * y1v[4 * d + 1];
            s2 += w.z * y1v[4 * d + 2];
            s3 += w.w * y1v[4 * d + 3];
        }
        ok[i] = (s0 + s1) + (s2 + s3) + bk[o];
    }
    {
        ushort4v pk;
        pk[0] = f2bf(ok[0]); pk[1] = f2bf(ok[1]);
        pk[2] = f2bf(ok[2]); pk[3] = f2bf(ok[3]);
        *(ushort4v*)(keybf + bpt * CC + g * 4) = pk;
    }

    float x0 = x[(size_t)(b * 3 + 0) * NN + n];
    float x1 = x[(size_t)(b * 3 + 1) * NN + n];
    float x2 = x[(size_t)(b * 3 + 2) * NN + n];
    {
        ushort4v pk;
#pragma unroll
        for (int i = 0; i < 4; ++i) {
            int o = g * 4 + i;
            pk[i] = f2bf(Wq[o * 3 + 0] * x0 + Wq[o * 3 + 1] * x1 + Wq[o * 3 + 2] * x2 + bq[o]);
        }
        *(ushort4v*)(qrybf + bpt * CC + g * 4) = pk;
    }
}

// ---------------------------------------------------------------------------
// Kernel 3: exact KNN, branch-coherent 3-phase (unchanged — verified).
// ---------------------------------------------------------------------------
__global__ __launch_bounds__(256) void knn_kernel(const float* __restrict__ x,
                                                  int* __restrict__ idx_out) {
    __shared__ __align__(16) char smem[65536];
    float4* pts = (float4*)smem;
    unsigned long long* surv = (unsigned long long*)smem;

    int b = blockIdx.x >> 10;
    int grp = blockIdx.x & 1023;
    int w = threadIdx.x >> 6;
    int lane = threadIdx.x & 63;
    int n = (grp << 2) + w;

    const float* xb = x + (size_t)b * 3 * NN;
    for (int i = threadIdx.x; i < NN; i += 256)
        pts[i] = make_float4(xb[i], xb[NN + i], xb[2 * NN + i], 0.f);
    __syncthreads();

    float4 q = pts[n];

    float dreg[64];
    float vmin = 3.4e38f;
#pragma unroll
    for (int r = 0; r < 64; ++r) {
        float4 c = pts[(r << 6) + lane];
        float ax = q.x - c.x, ay = q.y - c.y, az = q.z - c.z;
        float d = ax * ax + ay * ay + az * az;
        dreg[r] = d;
        vmin = fminf(vmin, d);
    }
#pragma unroll
    for (int k = 2; k <= 64; k <<= 1) {
#pragma unroll
        for (int j = k >> 1; j > 0; j >>= 1) {
            float o = __shfl_xor(vmin, j);
            bool lower = (lane & j) == 0;
            bool up = (lane & k) == 0;
            float mn = fminf(vmin, o), mx = fmaxf(vmin, o);
            vmin = (lower == up) ? mn : mx;
        }
    }
    float T = __shfl(vmin, 15);

    __syncthreads();

    unsigned long long* buf = surv + (w << 7);
    unsigned cnt = 0;
#pragma unroll
    for (int r = 0; r < 64; ++r) {
        float d = dreg[r];
        bool hit = d <= T;
        unsigned long long mask = __ballot(hit);
        if (hit) {
            unsigned off = cnt + (unsigned)__popcll(mask & ((1ull << lane) - 1ull));
            if (off < 128) {
                int j = (r << 6) + lane;
                buf[off] = ((unsigned long long)__float_as_uint(d) << 32) | (unsigned)j;
            }
        }
        cnt += (unsigned)__popcll(mask);
    }
    if (cnt > 128) cnt = 128;

    unsigned long long v0 = (lane < (int)cnt) ? buf[lane] : 0xFFFFFFFFFFFFFFFFull;
    unsigned long long v1 = (lane + 64 < (int)cnt) ? buf[lane + 64] : 0xFFFFFFFFFFFFFFFFull;
#pragma unroll
    for (int k = 2; k <= 128; k <<= 1) {
#pragma unroll
        for (int j = k >> 1; j > 0; j >>= 1) {
            if (j >= 64) {
                unsigned long long lo = umin64(v0, v1), hi = umax64(v0, v1);
                v0 = lo; v1 = hi;
            } else {
                bool lower = (lane & j) == 0;
                unsigned long long o0 = shfl_xor_u64(v0, j);
                bool up0 = ((lane & k) == 0);
                v0 = (lower == up0) ? umin64(v0, o0) : umax64(v0, o0);
                unsigned long long o1 = shfl_xor_u64(v1, j);
                bool up1 = (((64 + lane) & k) == 0);
                v1 = (lower == up1) ? umin64(v1, o1) : umax64(v1, o1);
            }
        }
    }
    if (lane < KNN)
        idx_out[((size_t)b * NN + n) * KNN + lane] = (int)(unsigned)(v0 & 0xFFFFFFFFull);
}

// ---------------------------------------------------------------------------
// Kernel 4: fused MFMA attention. bf16 feature reads; gathers hoisted early;
// hidden N=256 split into two 128-halves (hid_lds 17 KB, reused; wave-local,
// no barrier); unrolled weight loops for ILP. LDS ~27.5 KB -> 5 blocks/CU;
// __launch_bounds__(256,4) caps VGPR at 128 (4 waves/SIMD).
// XCD swizzle: b = blk & 3 so each XCD's L2 mostly serves one batch.
// ---------------------------------------------------------------------------
#define UPITCH 68
#define HPITCH 136

__device__ __forceinline__ short8 lds_frag(const unsigned short* p) {
    short4v lo = *(const short4v*)p;
    short4v hi = *(const short4v*)(p + 4);
    short8 v;
    v[0] = lo[0]; v[1] = lo[1]; v[2] = lo[2]; v[3] = lo[3];
    v[4] = hi[0]; v[5] = hi[1]; v[6] = hi[2]; v[7] = hi[3];
    return v;
}

__global__ __launch_bounds__(256, 4) void attn_mfma(
    const float* __restrict__ x, const float* __restrict__ y,
    const unsigned short* __restrict__ y1bf, const unsigned short* __restrict__ keybf,
    const unsigned short* __restrict__ qrybf, const int* __restrict__ idx,
    const float* __restrict__ P1p, const unsigned short* __restrict__ P2bf,
    const float* __restrict__ pb2, const unsigned short* __restrict__ A1bf,
    const float* __restrict__ ab1f, const float* __restrict__ bn2s_c,
    const unsigned short* __restrict__ A2bf,
    const float* __restrict__ Wend, const float* __restrict__ bend,
    float* __restrict__ out) {
    __shared__ unsigned short u_lds[64 * UPITCH];
    __shared__ unsigned short hid_lds[64 * HPITCH];
    __shared__ float agg_lds[4 * 64];
    __shared__ float outstage[64 * 4];

    int blk = blockIdx.x;
    int b = blk & 3;                  // XCD-affinity: batch on low bits
    int n0 = (blk >> 2) << 2;
    int w = threadIdx.x >> 6;
    int lane = threadIdx.x & 63;
    int m = lane & 15, quad = lane >> 4;
    int pt = n0 + w;
    size_t bpt = (size_t)b * NN + pt;

    // ---- issue ALL gathers early (overlap with VALU + P2 GEMM) ----
    int jm = idx[bpt * KNN + m];
    int j4[4];
#pragma unroll
    for (int r = 0; r < 4; ++r) j4[r] = idx[bpt * KNN + 4 * quad + r];
    unsigned short kvu[4][4];
    unsigned short qu[4];
#pragma unroll
    for (int nt = 0; nt < 4; ++nt) {
        qu[nt] = qrybf[bpt * CC + nt * 16 + m];
#pragma unroll
        for (int r = 0; r < 4; ++r)
            kvu[nt][r] = keybf[((size_t)b * NN + j4[r]) * CC + nt * 16 + m];
    }

    float dx = x[(size_t)(b * 3 + 0) * NN + pt] - x[(size_t)(b * 3 + 0) * NN + jm];
    float dy = x[(size_t)(b * 3 + 1) * NN + pt] - x[(size_t)(b * 3 + 1) * NN + jm];
    float dz = x[(size_t)(b * 3 + 2) * NN + pt] - x[(size_t)(b * 3 + 2) * NN + jm];
    short8 h1A[2];
#pragma unroll
    for (int ks = 0; ks < 2; ++ks) {
#pragma unroll
        for (int j = 0; j < 8; ++j) {
            int h1 = ks * 32 + quad * 8 + j;
            const float4 p = *(const float4*)(P1p + 4 * h1);
            float a = fmaxf(p.x * dx + p.y * dy + p.z * dz + p.w, 0.f);
            h1A[ks][j] = (short)f2bf(a);
        }
    }

    // ---- GEMM-P2: pe (C-layout regs), + pb2 ----
    floatx4 pacc[4];
#pragma unroll
    for (int nt = 0; nt < 4; ++nt) pacc[nt] = (floatx4){0.f, 0.f, 0.f, 0.f};
#pragma unroll
    for (int ks = 0; ks < 2; ++ks) {
#pragma unroll
        for (int nt = 0; nt < 4; ++nt) {
            short8 bb = *(const short8*)(P2bf + (nt * 16 + m) * HH + ks * 32 + quad * 8);
            pacc[nt] = __builtin_amdgcn_mfma_f32_16x16x32_bf16(h1A[ks], bb, pacc[nt], 0, 0, 0);
        }
    }
#pragma unroll
    for (int nt = 0; nt < 4; ++nt) {
        float pb = pb2[nt * 16 + m];
#pragma unroll
        for (int r = 0; r < 4; ++r) pacc[nt][r] += pb;
    }

    // ---- u = query - key + pe -> bf16 LDS (C-layout write) ----
#pragma unroll
    for (int nt = 0; nt < 4; ++nt) {
        float qv = bf2f(qu[nt]);
#pragma unroll
        for (int r = 0; r < 4; ++r) {
            float uu = qv - bf2f(kvu[nt][r]) + pacc[nt][r];
            u_lds[(w * 16 + 4 * quad + r) * UPITCH + nt * 16 + m] = f2bf(uu);
        }
    }

    short8 uA[2];
#pragma unroll
    for (int ks = 0; ks < 2; ++ks)
        uA[ks] = lds_frag(&u_lds[(w * 16 + m) * UPITCH + ks * 32 + quad * 8]);

    // ---- GEMM1 + GEMM2 in two 128-col halves (wave-local, no barrier) ----
    floatx4 acc2[4];
#pragma unroll
    for (int nt = 0; nt < 4; ++nt) acc2[nt] = (floatx4){0.f, 0.f, 0.f, 0.f};

    for (int hf = 0; hf < 2; ++hf) {
#pragma unroll 4
        for (int nt = 0; nt < 8; ++nt) {
            int h = (hf * 8 + nt) * 16 + m;
            const unsigned short* brow = A1bf + h * CC;
            short8 b0 = *(const short8*)(brow + quad * 8);
            short8 b1 = *(const short8*)(brow + 32 + quad * 8);
            floatx4 acc = (floatx4){0.f, 0.f, 0.f, 0.f};
            acc = __builtin_amdgcn_mfma_f32_16x16x32_bf16(uA[0], b0, acc, 0, 0, 0);
            acc = __builtin_amdgcn_mfma_f32_16x16x32_bf16(uA[1], b1, acc, 0, 0, 0);
            float s = bn2s_c[h], t0 = ab1f[h];
#pragma unroll
            for (int r = 0; r < 4; ++r) {
                float hv = fmaxf(acc[r] * s + t0, 0.f);
                hid_lds[(w * 16 + 4 * quad + r) * HPITCH + nt * 16 + m] = f2bf(hv);
            }
        }
#pragma unroll 2
        for (int ks = 0; ks < 4; ++ks) {
            short8 hA = lds_frag(&hid_lds[(w * 16 + m) * HPITCH + ks * 32 + quad * 8]);
#pragma unroll
            for (int nt = 0; nt < 4; ++nt) {
                short8 bb = *(const short8*)(A2bf + (nt * 16 + m) * AH + hf * 128 + ks * 32 + quad * 8);
                acc2[nt] = __builtin_amdgcn_mfma_f32_16x16x32_bf16(hA, bb, acc2[nt], 0, 0, 0);
            }
        }
    }

    // ---- softmax over 16 neighbors + aggregation ----
#pragma unroll
    for (int nt = 0; nt < 4; ++nt) {
        float l0 = acc2[nt][0], l1 = acc2[nt][1], l2 = acc2[nt][2], l3 = acc2[nt][3];
        float mx = fmaxf(fmaxf(l0, l1), fmaxf(l2, l3));
        mx = fmaxf(mx, __shfl_xor(mx, 16));
        mx = fmaxf(mx, __shfl_xor(mx, 32));
        float e0 = __expf(l0 - mx), e1 = __expf(l1 - mx);
        float e2 = __expf(l2 - mx), e3 = __expf(l3 - mx);
        float sum = (e0 + e1) + (e2 + e3);
        sum += __shfl_xor(sum, 16);
        sum += __shfl_xor(sum, 32);
        float y1v = bf2f(y1bf[bpt * CC + nt * 16 + m]);
        float contrib = e0 * (y1v + pacc[nt][0]) + e1 * (y1v + pacc[nt][1]) +
                        e2 * (y1v + pacc[nt][2]) + e3 * (y1v + pacc[nt][3]);
        contrib += __shfl_xor(contrib, 16);
        contrib += __shfl_xor(contrib, 32);
        float agg = contrib / sum;
        if (quad == 0) agg_lds[w * 64 + nt * 16 + m] = agg;
    }

    // ---- final: out[o=lane] = Wend[o]·agg + bend[o] (wave-local) ----
    float acco = 0.f;
#pragma unroll
    for (int c4 = 0; c4 < 16; ++c4) {
        float4 wv = *(const float4*)(Wend + lane * CC + c4 * 4);
        float4 av = *(const float4*)(agg_lds + w * 64 + c4 * 4);
        acco += wv.x * av.x + wv.y * av.y + wv.z * av.z + wv.w * av.w;
    }
    acco += bend[lane];
    outstage[lane * 4 + w] = acco;
    __syncthreads();

    int t = threadIdx.x;
    int o = t >> 2, p = t & 3;
    size_t oi = ((size_t)(b * CC + o)) * NN + n0 + p;
    out[oi] = outstage[t] + y[oi];
}

// ---------------------------------------------------------------------------
extern "C" void kernel_launch(void* const* d_in, const int* in_sizes, int n_in,
                              void* d_out, int out_size, void* d_ws, size_t ws_size,
                              hipStream_t stream) {
    const float* x    = (const float*)d_in[0];
    const float* y    = (const float*)d_in[1];
    const float* Ws   = (const float*)d_in[2];
    const float* bs   = (const float*)d_in[3];
    const float* Wk   = (const float*)d_in[4];
    const float* bk   = (const float*)d_in[5];
    const float* Wq   = (const float*)d_in[6];
    const float* bq   = (const float*)d_in[7];
    const float* P1   = (const float*)d_in[8];
    const float* pb1  = (const float*)d_in[9];
    const float* g1   = (const float*)d_in[10];
    const float* b1   = (const float*)d_in[11];
    const float* m1   = (const float*)d_in[12];
    const float* v1   = (const float*)d_in[13];
    const float* P2   = (const float*)d_in[14];
    const float* pb2  = (const float*)d_in[15];
    const float* A1   = (const float*)d_in[16];
    const float* ab1  = (const float*)d_in[17];
    const float* g2   = (const float*)d_in[18];
    const float* b2   = (const float*)d_in[19];
    const float* m2   = (const float*)d_in[20];
    const float* v2   = (const float*)d_in[21];
    const float* A2   = (const float*)d_in[22];
    const float* ab2  = (const float*)d_in[23];  // dropped (softmax-invariant)
    const float* Wend = (const float*)d_in[24];
    const float* bend = (const float*)d_in[25];
    (void)ab2;

    unsigned short* usws = (unsigned short*)d_ws;
    unsigned short* y1bf  = usws;                  // 1,048,576 us (2 MB)
    unsigned short* keybf = usws + 1048576;
    unsigned short* qrybf = usws + 2097152;
    int* idx = (int*)(usws + 3145728);             // 262,144 ints
    unsigned short* A1bf = (unsigned short*)(idx + 262144);  // 16384 us
    unsigned short* A2bf = A1bf + 16384;
    unsigned short* P2bf = A2bf + 16384;           // 4096 us
    float* P1p   = (float*)(P2bf + 4096);          // 256 f (16B-aligned)
    float* ab1f  = P1p + 256;
    float* bn2sc = ab1f + 256;
    float* out   = (float*)d_out;

    hipLaunchKernelGGL(prep_params, dim3(1), dim3(256), 0, stream,
                       P1, pb1, P2, A1, ab1, A2, g1, b1, m1, v1, g2, b2, m2, v2,
                       A1bf, A2bf, P2bf, P1p, ab1f, bn2sc);
    hipLaunchKernelGGL(prep_features, dim3(1024), dim3(256), 0, stream,
                       x, y, Ws, bs, Wk, bk, Wq, bq, y1bf, keybf, qrybf);
    hipLaunchKernelGGL(knn_kernel, dim3(4096), dim3(256), 0, stream, x, idx);
    hipLaunchKernelGGL(attn_mfma, dim3(4096), dim3(256), 0, stream,
                       x, y, y1bf, keybf, qrybf, idx,
                       P1p, P2bf, pb2, A1bf, ab1f, bn2sc, A2bf,
                       Wend, bend, out);
}

// Round 8
// 354.168 us; speedup vs baseline: 5.1651x; 1.2350x over previous
//
#include <hip/hip_runtime.h>
#include <hip/hip_bf16.h>

#define BB 4
#define CC 64
#define NN 4096
#define HH 64
#define AH 256
#define KNN 16
#define EPSV 1e-5f

typedef __attribute__((ext_vector_type(8))) short short8;
typedef __attribute__((ext_vector_type(4))) short short4v;
typedef __attribute__((ext_vector_type(4))) unsigned short ushort4v;
typedef __attribute__((ext_vector_type(4))) float floatx4;

__device__ __forceinline__ unsigned short f2bf(float f) {
    unsigned u = __float_as_uint(f);
    u += 0x7FFFu + ((u >> 16) & 1u);   // round-to-nearest-even
    return (unsigned short)(u >> 16);
}
__device__ __forceinline__ float bf2f(unsigned short u) {
    return __uint_as_float(((unsigned)u) << 16);
}

__device__ __forceinline__ unsigned long long umin64(unsigned long long a, unsigned long long b) {
    return a < b ? a : b;
}
__device__ __forceinline__ unsigned long long umax64(unsigned long long a, unsigned long long b) {
    return a > b ? a : b;
}
__device__ __forceinline__ unsigned long long shfl_xor_u64(unsigned long long v, int m) {
    int lo = __shfl_xor((int)(unsigned)(v & 0xFFFFFFFFull), m);
    int hi = __shfl_xor((int)(unsigned)(v >> 32), m);
    return ((unsigned long long)(unsigned)hi << 32) | (unsigned)lo;
}

// ---------------------------------------------------------------------------
// Kernel 1: fold BN params; emit weights in LANE-MAJOR MFMA-tile layouts so
// every weight load in attn is a contiguous 1-KB wave read (4 cache lines per
// 16-lane group instead of 16 -> 4x fewer L1 tag lookups).
//   A1L[((ht*2+ks)*64 + lane)*8 + e]  = bf16(A1[(ht*16+m)*CC  + ks*32+q*8+e])
//   A2L[((nt*8+kk)*64 + lane)*8 + e]  = bf16(A2[(nt*16+m)*AH  + kk*32+q*8+e])
//   P2L[((nt*2+ks)*64 + lane)*8 + e]  = bf16(P2[(nt*16+m)*HH  + ks*32+q*8+e])
//   WendT[c4*256 + lane*4 + e]        = Wend[lane*CC + c4*4 + e]   (floats)
// where lane = q*16+m.
// ---------------------------------------------------------------------------
__global__ void prep_params(const float* __restrict__ P1, const float* __restrict__ pb1,
                            const float* __restrict__ P2, const float* __restrict__ A1,
                            const float* __restrict__ ab1, const float* __restrict__ A2,
                            const float* __restrict__ g1, const float* __restrict__ b1,
                            const float* __restrict__ m1, const float* __restrict__ v1,
                            const float* __restrict__ g2, const float* __restrict__ b2,
                            const float* __restrict__ m2, const float* __restrict__ v2,
                            const float* __restrict__ Wend,
                            unsigned short* __restrict__ A1L, unsigned short* __restrict__ A2L,
                            unsigned short* __restrict__ P2L, float* __restrict__ WendT,
                            float* __restrict__ P1p,
                            float* __restrict__ ab1f, float* __restrict__ bn2s_c) {
    int t = threadIdx.x;
    if (t < HH) {
        float s = g1[t] * rsqrtf(v1[t] + EPSV);
        float c = b1[t] - m1[t] * s;
        P1p[4 * t + 0] = P1[3 * t + 0] * s;
        P1p[4 * t + 1] = P1[3 * t + 1] * s;
        P1p[4 * t + 2] = P1[3 * t + 2] * s;
        P1p[4 * t + 3] = pb1[t] * s + c;
    }
    if (t < AH) {
        float s = g2[t] * rsqrtf(v2[t] + EPSV);
        bn2s_c[t] = s;
        ab1f[t] = ab1[t] * s + (b2[t] - m2[t] * s);
    }
    // A1L: 16 ht x 2 ks x 64 lane x 8 e
    for (int i = t; i < 16384; i += 256) {
        int e = i & 7;
        int lane = (i >> 3) & 63;
        int ks = (i >> 9) & 1;
        int ht = i >> 10;
        int m = lane & 15, q = lane >> 4;
        A1L[i] = f2bf(A1[(ht * 16 + m) * CC + ks * 32 + q * 8 + e]);
    }
    // A2L: 4 nt x 8 kk x 64 lane x 8 e
    for (int i = t; i < 16384; i += 256) {
        int e = i & 7;
        int lane = (i >> 3) & 63;
        int kk = (i >> 9) & 7;
        int nt = i >> 12;
        int m = lane & 15, q = lane >> 4;
        A2L[i] = f2bf(A2[(nt * 16 + m) * AH + kk * 32 + q * 8 + e]);
    }
    // P2L: 4 nt x 2 ks x 64 lane x 8 e
    for (int i = t; i < 4096; i += 256) {
        int e = i & 7;
        int lane = (i >> 3) & 63;
        int ks = (i >> 9) & 1;
        int nt = i >> 10;
        int m = lane & 15, q = lane >> 4;
        P2L[i] = f2bf(P2[(nt * 16 + m) * HH + ks * 32 + q * 8 + e]);
    }
    // WendT: 16 c4 x 64 lane x 4 e  (floats)
    for (int i = t; i < 4096; i += 256) {
        int e = i & 3;
        int lane = (i >> 2) & 63;
        int c4 = i >> 8;
        WendT[i] = Wend[lane * CC + c4 * 4 + e];
    }
}

// ---------------------------------------------------------------------------
// Kernel 2: prep features -> bf16 outputs. 16 points/block, 16 threads/point.
// (unchanged from round 7 — verified)
// ---------------------------------------------------------------------------
__global__ __launch_bounds__(256) void prep_features(
    const float* __restrict__ x, const float* __restrict__ y,
    const float* __restrict__ Ws, const float* __restrict__ bs,
    const float* __restrict__ Wk, const float* __restrict__ bk,
    const float* __restrict__ Wq, const float* __restrict__ bq,
    unsigned short* __restrict__ y1bf, unsigned short* __restrict__ keybf,
    unsigned short* __restrict__ qrybf) {
    __shared__ float y_s[16][68];
    __shared__ float y1_s[16][68];

    int b = blockIdx.x >> 8;
    int n0 = (blockIdx.x & 255) << 4;
    int tid = threadIdx.x;
    int p = tid >> 4, g = tid & 15;
    int n = n0 + p;
    size_t bpt = (size_t)b * NN + n;

    for (int i = tid; i < 16 * CC; i += 256) {
        int c = i >> 4, nn = i & 15;
        y_s[nn][c] = y[((size_t)(b * CC + c)) * NN + n0 + nn];
    }
    __syncthreads();

    float yv[CC];
#pragma unroll
    for (int c4 = 0; c4 < 16; ++c4) {
        float4 v = *(const float4*)&y_s[p][c4 * 4];
        yv[4 * c4 + 0] = v.x; yv[4 * c4 + 1] = v.y;
        yv[4 * c4 + 2] = v.z; yv[4 * c4 + 3] = v.w;
    }

    float o1[4];
#pragma unroll
    for (int i = 0; i < 4; ++i) {
        int o = g * 4 + i;
        const float4* wr = (const float4*)(Ws + o * CC);
        float s0 = 0.f, s1 = 0.f, s2 = 0.f, s3 = 0.f;
#pragma unroll
        for (int d = 0; d < 16; ++d) {
            float4 w = wr[d];
            s0 += w.x * yv[4 * d + 0];
            s1 += w.y * yv[4 * d + 1];
            s2 += w.z * yv[4 * d + 2];
            s3 += w.w * yv[4 * d + 3];
        }
        o1[i] = (s0 + s1) + (s2 + s3) + bs[o];
        y1_s[p][o] = o1[i];
    }
    {
        ushort4v pk;
        pk[0] = f2bf(o1[0]); pk[1] = f2bf(o1[1]);
        pk[2] = f2bf(o1[2]); pk[3] = f2bf(o1[3]);
        *(ushort4v*)(y1bf + bpt * CC + g * 4) = pk;
    }
    __syncthreads();

    float y1v[CC];
#pragma unroll
    for (int c4 = 0; c4 < 16; ++c4) {
        float4 v = *(const float4*)&y1_s[p][c4 * 4];
        y1v[4 * c4 + 0] = v.x; y1v[4 * c4 + 1] = v.y;
        y1v[4 * c4 + 2] = v.z; y1v[4 * c4 + 3] = v.w;
    }

    float ok[4];
#pragma unroll
    for (int i = 0; i < 4; ++i) {
        int o = g * 4 + i;
        const float4* wr = (const float4*)(Wk + o * CC);
        float s0 = 0.f, s1 = 0.f, s2 = 0.f, s3 = 0.f;
#pragma unroll
        for (int d = 0; d < 16; ++d) {
            float4 w = wr[d];
            s0 += w.x * y1v[4 * d + 0];
            s1 += w.y * y1v[4 * d + 1];
            s2 += w.z * y1v[4 * d + 2];
            s3 += w.w * y1v[4 * d + 3];
        }
        ok[i] = (s0 + s1) + (s2 + s3) + bk[o];
    }
    {
        ushort4v pk;
        pk[0] = f2bf(ok[0]); pk[1] = f2bf(ok[1]);
        pk[2] = f2bf(ok[2]); pk[3] = f2bf(ok[3]);
        *(ushort4v*)(keybf + bpt * CC + g * 4) = pk;
    }

    float x0 = x[(size_t)(b * 3 + 0) * NN + n];
    float x1 = x[(size_t)(b * 3 + 1) * NN + n];
    float x2 = x[(size_t)(b * 3 + 2) * NN + n];
    {
        ushort4v pk;
#pragma unroll
        for (int i = 0; i < 4; ++i) {
            int o = g * 4 + i;
            pk[i] = f2bf(Wq[o * 3 + 0] * x0 + Wq[o * 3 + 1] * x1 + Wq[o * 3 + 2] * x2 + bq[o]);
        }
        *(ushort4v*)(qrybf + bpt * CC + g * 4) = pk;
    }
}

// ---------------------------------------------------------------------------
// Kernel 3: exact KNN, branch-coherent 3-phase (unchanged — verified).
// ---------------------------------------------------------------------------
__global__ __launch_bounds__(256) void knn_kernel(const float* __restrict__ x,
                                                  int* __restrict__ idx_out) {
    __shared__ __align__(16) char smem[65536];
    float4* pts = (float4*)smem;
    unsigned long long* surv = (unsigned long long*)smem;

    int b = blockIdx.x >> 10;
    int grp = blockIdx.x & 1023;
    int w = threadIdx.x >> 6;
    int lane = threadIdx.x & 63;
    int n = (grp << 2) + w;

    const float* xb = x + (size_t)b * 3 * NN;
    for (int i = threadIdx.x; i < NN; i += 256)
        pts[i] = make_float4(xb[i], xb[NN + i], xb[2 * NN + i], 0.f);
    __syncthreads();

    float4 q = pts[n];

    float dreg[64];
    float vmin = 3.4e38f;
#pragma unroll
    for (int r = 0; r < 64; ++r) {
        float4 c = pts[(r << 6) + lane];
        float ax = q.x - c.x, ay = q.y - c.y, az = q.z - c.z;
        float d = ax * ax + ay * ay + az * az;
        dreg[r] = d;
        vmin = fminf(vmin, d);
    }
#pragma unroll
    for (int k = 2; k <= 64; k <<= 1) {
#pragma unroll
        for (int j = k >> 1; j > 0; j >>= 1) {
            float o = __shfl_xor(vmin, j);
            bool lower = (lane & j) == 0;
            bool up = (lane & k) == 0;
            float mn = fminf(vmin, o), mx = fmaxf(vmin, o);
            vmin = (lower == up) ? mn : mx;
        }
    }
    float T = __shfl(vmin, 15);

    __syncthreads();

    unsigned long long* buf = surv + (w << 7);
    unsigned cnt = 0;
#pragma unroll
    for (int r = 0; r < 64; ++r) {
        float d = dreg[r];
        bool hit = d <= T;
        unsigned long long mask = __ballot(hit);
        if (hit) {
            unsigned off = cnt + (unsigned)__popcll(mask & ((1ull << lane) - 1ull));
            if (off < 128) {
                int j = (r << 6) + lane;
                buf[off] = ((unsigned long long)__float_as_uint(d) << 32) | (unsigned)j;
            }
        }
        cnt += (unsigned)__popcll(mask);
    }
    if (cnt > 128) cnt = 128;

    unsigned long long v0 = (lane < (int)cnt) ? buf[lane] : 0xFFFFFFFFFFFFFFFFull;
    unsigned long long v1 = (lane + 64 < (int)cnt) ? buf[lane + 64] : 0xFFFFFFFFFFFFFFFFull;
#pragma unroll
    for (int k = 2; k <= 128; k <<= 1) {
#pragma unroll
        for (int j = k >> 1; j > 0; j >>= 1) {
            if (j >= 64) {
                unsigned long long lo = umin64(v0, v1), hi = umax64(v0, v1);
                v0 = lo; v1 = hi;
            } else {
                bool lower = (lane & j) == 0;
                unsigned long long o0 = shfl_xor_u64(v0, j);
                bool up0 = ((lane & k) == 0);
                v0 = (lower == up0) ? umin64(v0, o0) : umax64(v0, o0);
                unsigned long long o1 = shfl_xor_u64(v1, j);
                bool up1 = (((64 + lane) & k) == 0);
                v1 = (lower == up1) ? umin64(v1, o1) : umax64(v1, o1);
            }
        }
    }
    if (lane < KNN)
        idx_out[((size_t)b * NN + n) * KNN + lane] = (int)(unsigned)(v0 & 0xFFFFFFFFull);
}

// ---------------------------------------------------------------------------
// Kernel 4: fused MFMA attention. Weight reads now lane-major contiguous
// (1 KB/wave-instr, 4 lines per 16-lane group); Wend dot served from LDS.
// ---------------------------------------------------------------------------
#define UPITCH 68
#define HPITCH 136

__device__ __forceinline__ short8 lds_frag(const unsigned short* p) {
    short4v lo = *(const short4v*)p;
    short4v hi = *(const short4v*)(p + 4);
    short8 v;
    v[0] = lo[0]; v[1] = lo[1]; v[2] = lo[2]; v[3] = lo[3];
    v[4] = hi[0]; v[5] = hi[1]; v[6] = hi[2]; v[7] = hi[3];
    return v;
}

__global__ __launch_bounds__(256, 4) void attn_mfma(
    const float* __restrict__ x, const float* __restrict__ y,
    const unsigned short* __restrict__ y1bf, const unsigned short* __restrict__ keybf,
    const unsigned short* __restrict__ qrybf, const int* __restrict__ idx,
    const float* __restrict__ P1p, const unsigned short* __restrict__ P2L,
    const float* __restrict__ pb2, const unsigned short* __restrict__ A1L,
    const float* __restrict__ ab1f, const float* __restrict__ bn2s_c,
    const unsigned short* __restrict__ A2L, const float* __restrict__ WendT,
    const float* __restrict__ bend,
    float* __restrict__ out) {
    __shared__ unsigned short u_lds[64 * UPITCH];
    __shared__ unsigned short hid_lds[64 * HPITCH];
    __shared__ float wend_s[4096];     // 16 KB, lane-major: [c4*256 + lane*4]
    __shared__ float agg_lds[4 * 64];
    __shared__ float outstage[64 * 4];

    int blk = blockIdx.x;
    int b = blk & 3;                  // XCD-affinity: batch on low bits
    int n0 = (blk >> 2) << 2;
    int w = threadIdx.x >> 6;
    int lane = threadIdx.x & 63;
    int m = lane & 15, quad = lane >> 4;
    int pt = n0 + w;
    size_t bpt = (size_t)b * NN + pt;

    // ---- stage Wend into LDS (coalesced; used after barrier below) ----
    for (int i = threadIdx.x; i < 1024; i += 256)
        ((float4*)wend_s)[i] = ((const float4*)WendT)[i];

    // ---- issue ALL gathers early (overlap with VALU + P2 GEMM) ----
    int jm = idx[bpt * KNN + m];
    int j4[4];
#pragma unroll
    for (int r = 0; r < 4; ++r) j4[r] = idx[bpt * KNN + 4 * quad + r];
    unsigned short kvu[4][4];
    unsigned short qu[4];
#pragma unroll
    for (int nt = 0; nt < 4; ++nt) {
        qu[nt] = qrybf[bpt * CC + nt * 16 + m];
#pragma unroll
        for (int r = 0; r < 4; ++r)
            kvu[nt][r] = keybf[((size_t)b * NN + j4[r]) * CC + nt * 16 + m];
    }

    float dx = x[(size_t)(b * 3 + 0) * NN + pt] - x[(size_t)(b * 3 + 0) * NN + jm];
    float dy = x[(size_t)(b * 3 + 1) * NN + pt] - x[(size_t)(b * 3 + 1) * NN + jm];
    float dz = x[(size_t)(b * 3 + 2) * NN + pt] - x[(size_t)(b * 3 + 2) * NN + jm];
    short8 h1A[2];
#pragma unroll
    for (int ks = 0; ks < 2; ++ks) {
#pragma unroll
        for (int j = 0; j < 8; ++j) {
            int h1 = ks * 32 + quad * 8 + j;
            const float4 p = *(const float4*)(P1p + 4 * h1);
            float a = fmaxf(p.x * dx + p.y * dy + p.z * dz + p.w, 0.f);
            h1A[ks][j] = (short)f2bf(a);
        }
    }

    // ---- GEMM-P2: pe (C-layout regs), + pb2 ----
    floatx4 pacc[4];
#pragma unroll
    for (int nt = 0; nt < 4; ++nt) pacc[nt] = (floatx4){0.f, 0.f, 0.f, 0.f};
#pragma unroll
    for (int ks = 0; ks < 2; ++ks) {
#pragma unroll
        for (int nt = 0; nt < 4; ++nt) {
            short8 bb = *(const short8*)(P2L + ((nt * 2 + ks) * 64 + lane) * 8);
            pacc[nt] = __builtin_amdgcn_mfma_f32_16x16x32_bf16(h1A[ks], bb, pacc[nt], 0, 0, 0);
        }
    }
#pragma unroll
    for (int nt = 0; nt < 4; ++nt) {
        float pb = pb2[nt * 16 + m];
#pragma unroll
        for (int r = 0; r < 4; ++r) pacc[nt][r] += pb;
    }

    // ---- u = query - key + pe -> bf16 LDS (C-layout write) ----
#pragma unroll
    for (int nt = 0; nt < 4; ++nt) {
        float qv = bf2f(qu[nt]);
#pragma unroll
        for (int r = 0; r < 4; ++r) {
            float uu = qv - bf2f(kvu[nt][r]) + pacc[nt][r];
            u_lds[(w * 16 + 4 * quad + r) * UPITCH + nt * 16 + m] = f2bf(uu);
        }
    }

    short8 uA[2];
#pragma unroll
    for (int ks = 0; ks < 2; ++ks)
        uA[ks] = lds_frag(&u_lds[(w * 16 + m) * UPITCH + ks * 32 + quad * 8]);

    // ---- GEMM1 + GEMM2 in two 128-col halves (wave-local, no barrier) ----
    floatx4 acc2[4];
#pragma unroll
    for (int nt = 0; nt < 4; ++nt) acc2[nt] = (floatx4){0.f, 0.f, 0.f, 0.f};

    for (int hf = 0; hf < 2; ++hf) {
#pragma unroll 4
        for (int nt = 0; nt < 8; ++nt) {
            int ht = hf * 8 + nt;
            const unsigned short* a1t = A1L + ht * 1024 + lane * 8;
            short8 b0 = *(const short8*)(a1t);
            short8 b1 = *(const short8*)(a1t + 512);
            floatx4 acc = (floatx4){0.f, 0.f, 0.f, 0.f};
            acc = __builtin_amdgcn_mfma_f32_16x16x32_bf16(uA[0], b0, acc, 0, 0, 0);
            acc = __builtin_amdgcn_mfma_f32_16x16x32_bf16(uA[1], b1, acc, 0, 0, 0);
            int h = ht * 16 + m;
            float s = bn2s_c[h], t0 = ab1f[h];
#pragma unroll
            for (int r = 0; r < 4; ++r) {
                float hv = fmaxf(acc[r] * s + t0, 0.f);
                hid_lds[(w * 16 + 4 * quad + r) * HPITCH + nt * 16 + m] = f2bf(hv);
            }
        }
#pragma unroll 2
        for (int ks = 0; ks < 4; ++ks) {
            short8 hA = lds_frag(&hid_lds[(w * 16 + m) * HPITCH + ks * 32 + quad * 8]);
#pragma unroll
            for (int nt = 0; nt < 4; ++nt) {
                int kk = hf * 4 + ks;
                short8 bb = *(const short8*)(A2L + ((nt * 8 + kk) * 64 + lane) * 8);
                acc2[nt] = __builtin_amdgcn_mfma_f32_16x16x32_bf16(hA, bb, acc2[nt], 0, 0, 0);
            }
        }
    }

    // ---- softmax over 16 neighbors + aggregation ----
#pragma unroll
    for (int nt = 0; nt < 4; ++nt) {
        float l0 = acc2[nt][0], l1 = acc2[nt][1], l2 = acc2[nt][2], l3 = acc2[nt][3];
        float mx = fmaxf(fmaxf(l0, l1), fmaxf(l2, l3));
        mx = fmaxf(mx, __shfl_xor(mx, 16));
        mx = fmaxf(mx, __shfl_xor(mx, 32));
        float e0 = __expf(l0 - mx), e1 = __expf(l1 - mx);
        float e2 = __expf(l2 - mx), e3 = __expf(l3 - mx);
        float sum = (e0 + e1) + (e2 + e3);
        sum += __shfl_xor(sum, 16);
        sum += __shfl_xor(sum, 32);
        float y1v = bf2f(y1bf[bpt * CC + nt * 16 + m]);
        float contrib = e0 * (y1v + pacc[nt][0]) + e1 * (y1v + pacc[nt][1]) +
                        e2 * (y1v + pacc[nt][2]) + e3 * (y1v + pacc[nt][3]);
        contrib += __shfl_xor(contrib, 16);
        contrib += __shfl_xor(contrib, 32);
        float agg = contrib / sum;
        if (quad == 0) agg_lds[w * 64 + nt * 16 + m] = agg;
    }

    __syncthreads();   // wend_s staged + agg_lds visible (wave-local anyway)

    // ---- final: out[o=lane] = Wend[o]·agg + bend[o], Wend from LDS ----
    float acco = 0.f;
#pragma unroll
    for (int c4 = 0; c4 < 16; ++c4) {
        float4 wv = *(const float4*)&wend_s[c4 * 256 + lane * 4];
        float4 av = *(const float4*)(agg_lds + w * 64 + c4 * 4);
        acco += wv.x * av.x + wv.y * av.y + wv.z * av.z + wv.w * av.w;
    }
    acco += bend[lane];
    outstage[lane * 4 + w] = acco;
    __syncthreads();

    int t = threadIdx.x;
    int o = t >> 2, p = t & 3;
    size_t oi = ((size_t)(b * CC + o)) * NN + n0 + p;
    out[oi] = outstage[t] + y[oi];
}

// ---------------------------------------------------------------------------
extern "C" void kernel_launch(void* const* d_in, const int* in_sizes, int n_in,
                              void* d_out, int out_size, void* d_ws, size_t ws_size,
                              hipStream_t stream) {
    const float* x    = (const float*)d_in[0];
    const float* y    = (const float*)d_in[1];
    const float* Ws   = (const float*)d_in[2];
    const float* bs   = (const float*)d_in[3];
    const float* Wk   = (const float*)d_in[4];
    const float* bk   = (const float*)d_in[5];
    const float* Wq   = (const float*)d_in[6];
    const float* bq   = (const float*)d_in[7];
    const float* P1   = (const float*)d_in[8];
    const float* pb1  = (const float*)d_in[9];
    const float* g1   = (const float*)d_in[10];
    const float* b1   = (const float*)d_in[11];
    const float* m1   = (const float*)d_in[12];
    const float* v1   = (const float*)d_in[13];
    const float* P2   = (const float*)d_in[14];
    const float* pb2  = (const float*)d_in[15];
    const float* A1   = (const float*)d_in[16];
    const float* ab1  = (const float*)d_in[17];
    const float* g2   = (const float*)d_in[18];
    const float* b2   = (const float*)d_in[19];
    const float* m2   = (const float*)d_in[20];
    const float* v2   = (const float*)d_in[21];
    const float* A2   = (const float*)d_in[22];
    const float* ab2  = (const float*)d_in[23];  // dropped (softmax-invariant)
    const float* Wend = (const float*)d_in[24];
    const float* bend = (const float*)d_in[25];
    (void)ab2;

    unsigned short* usws = (unsigned short*)d_ws;
    unsigned short* y1bf  = usws;                  // 1,048,576 us
    unsigned short* keybf = usws + 1048576;        // 1,048,576 us
    unsigned short* qrybf = usws + 2097152;        // 1,048,576 us
    int* idx = (int*)(usws + 3145728);             // 262,144 ints
    unsigned short* A1L = usws + 3670016;          // 16,384 us
    unsigned short* A2L = A1L + 16384;             // 16,384 us
    unsigned short* P2L = A2L + 16384;             // 4,096 us
    float* WendT = (float*)(P2L + 4096);           // 4,096 f (16B-aligned)
    float* P1p   = WendT + 4096;                   // 256 f
    float* ab1f  = P1p + 256;                      // 256 f
    float* bn2sc = ab1f + 256;                     // 256 f
    float* out   = (float*)d_out;

    hipLaunchKernelGGL(prep_params, dim3(1), dim3(256), 0, stream,
                       P1, pb1, P2, A1, ab1, A2, g1, b1, m1, v1, g2, b2, m2, v2,
                       Wend, A1L, A2L, P2L, WendT, P1p, ab1f, bn2sc);
    hipLaunchKernelGGL(prep_features, dim3(1024), dim3(256), 0, stream,
                       x, y, Ws, bs, Wk, bk, Wq, bq, y1bf, keybf, qrybf);
    hipLaunchKernelGGL(knn_kernel, dim3(4096), dim3(256), 0, stream, x, idx);
    hipLaunchKernelGGL(attn_mfma, dim3(4096), dim3(256), 0, stream,
                       x, y, y1bf, keybf, qrybf, idx,
                       P1p, P2L, pb2, A1L, ab1f, bn2sc, A2L, WendT,
                       bend, out);
}

// Round 9
// 273.763 us; speedup vs baseline: 6.6821x; 1.2937x over previous
//
#include <hip/hip_runtime.h>
#include <hip/hip_bf16.h>

#define BB 4
#define CC 64
#define NN 4096
#define HH 64
#define AH 256
#define KNN 16
#define EPSV 1e-5f
#define PREP_NB 32

typedef __attribute__((ext_vector_type(8))) short short8;
typedef __attribute__((ext_vector_type(4))) short short4v;
typedef __attribute__((ext_vector_type(4))) unsigned short ushort4v;
typedef __attribute__((ext_vector_type(4))) float floatx4;

__device__ __forceinline__ unsigned short f2bf(float f) {
    unsigned u = __float_as_uint(f);
    u += 0x7FFFu + ((u >> 16) & 1u);   // round-to-nearest-even
    return (unsigned short)(u >> 16);
}
__device__ __forceinline__ float bf2f(unsigned short u) {
    return __uint_as_float(((unsigned)u) << 16);
}

__device__ __forceinline__ unsigned long long umin64(unsigned long long a, unsigned long long b) {
    return a < b ? a : b;
}
__device__ __forceinline__ unsigned long long umax64(unsigned long long a, unsigned long long b) {
    return a > b ? a : b;
}
__device__ __forceinline__ unsigned long long shfl_xor_u64(unsigned long long v, int m) {
    int lo = __shfl_xor((int)(unsigned)(v & 0xFFFFFFFFull), m);
    int hi = __shfl_xor((int)(unsigned)(v >> 32), m);
    return ((unsigned long long)(unsigned)hi << 32) | (unsigned)lo;
}

// ---------------------------------------------------------------------------
// Kernel 1 (32 blocks): fold BN params; emit ALL weights in lane-major
// MFMA-tile layouts (1-KB contiguous wave reads):
//   XL[((tile*2+ks)*64 + lane)*8 + e] = bf16(X[(tile*16+m)*K + ks*32+q*8+e])
//   WendT[c4*256 + lane*4 + e] = Wend[lane*CC + c4*4 + e]
//   Wq4[4*ch+{0,1,2}] = Wq[ch*3+d], Wq4[4*ch+3] = bq[ch]
// ---------------------------------------------------------------------------
__global__ void prep_params(const float* __restrict__ P1, const float* __restrict__ pb1,
                            const float* __restrict__ P2, const float* __restrict__ A1,
                            const float* __restrict__ ab1, const float* __restrict__ A2,
                            const float* __restrict__ g1, const float* __restrict__ b1,
                            const float* __restrict__ m1, const float* __restrict__ v1,
                            const float* __restrict__ g2, const float* __restrict__ b2,
                            const float* __restrict__ m2, const float* __restrict__ v2,
                            const float* __restrict__ Wend, const float* __restrict__ Ws,
                            const float* __restrict__ Wk, const float* __restrict__ Wq,
                            const float* __restrict__ bq,
                            unsigned short* __restrict__ A1L, unsigned short* __restrict__ A2L,
                            unsigned short* __restrict__ P2L, float* __restrict__ WendT,
                            unsigned short* __restrict__ WsL, unsigned short* __restrict__ WkL,
                            float* __restrict__ Wq4, float* __restrict__ P1p,
                            float* __restrict__ ab1f, float* __restrict__ bn2s_c) {
    int t0 = threadIdx.x;
    int t = blockIdx.x * 256 + t0;
    const int stride = PREP_NB * 256;
    if (blockIdx.x == 0) {
        if (t0 < HH) {
            float s = g1[t0] * rsqrtf(v1[t0] + EPSV);
            float c = b1[t0] - m1[t0] * s;
            P1p[4 * t0 + 0] = P1[3 * t0 + 0] * s;
            P1p[4 * t0 + 1] = P1[3 * t0 + 1] * s;
            P1p[4 * t0 + 2] = P1[3 * t0 + 2] * s;
            P1p[4 * t0 + 3] = pb1[t0] * s + c;
        }
        if (t0 < AH) {
            float s = g2[t0] * rsqrtf(v2[t0] + EPSV);
            bn2s_c[t0] = s;
            ab1f[t0] = ab1[t0] * s + (b2[t0] - m2[t0] * s);
        }
        if (t0 < CC) {
            Wq4[4 * t0 + 0] = Wq[3 * t0 + 0];
            Wq4[4 * t0 + 1] = Wq[3 * t0 + 1];
            Wq4[4 * t0 + 2] = Wq[3 * t0 + 2];
            Wq4[4 * t0 + 3] = bq[t0];
        }
    }
    for (int i = t; i < 16384; i += stride) {   // A1L: 16 ht x 2 ks
        int e = i & 7, lane = (i >> 3) & 63, ks = (i >> 9) & 1, ht = i >> 10;
        int m = lane & 15, q = lane >> 4;
        A1L[i] = f2bf(A1[(ht * 16 + m) * CC + ks * 32 + q * 8 + e]);
    }
    for (int i = t; i < 16384; i += stride) {   // A2L: 4 nt x 8 kk
        int e = i & 7, lane = (i >> 3) & 63, kk = (i >> 9) & 7, nt = i >> 12;
        int m = lane & 15, q = lane >> 4;
        A2L[i] = f2bf(A2[(nt * 16 + m) * AH + kk * 32 + q * 8 + e]);
    }
    for (int i = t; i < 4096; i += stride) {    // P2L: 4 nt x 2 ks
        int e = i & 7, lane = (i >> 3) & 63, ks = (i >> 9) & 1, nt = i >> 10;
        int m = lane & 15, q = lane >> 4;
        P2L[i] = f2bf(P2[(nt * 16 + m) * HH + ks * 32 + q * 8 + e]);
    }
    for (int i = t; i < 4096; i += stride) {    // WendT
        int e = i & 3, lane = (i >> 2) & 63, c4 = i >> 8;
        WendT[i] = Wend[lane * CC + c4 * 4 + e];
    }
    for (int i = t; i < 8192; i += stride) {    // WsL: 4 ot x 2 ks
        int e = i & 7, lane = (i >> 3) & 63, ks = (i >> 9) & 1, ot = i >> 10;
        int m = lane & 15, q = lane >> 4;
        WsL[i] = f2bf(Ws[(ot * 16 + m) * CC + ks * 32 + q * 8 + e]);
    }
    for (int i = t; i < 8192; i += stride) {    // WkL: 4 ot x 2 ks
        int e = i & 7, lane = (i >> 3) & 63, ks = (i >> 9) & 1, ot = i >> 10;
        int m = lane & 15, q = lane >> 4;
        WkL[i] = f2bf(Wk[(ot * 16 + m) * CC + ks * 32 + q * 8 + e]);
    }
}

#define UPITCH 68
#define HPITCH 136

__device__ __forceinline__ short8 lds_frag(const unsigned short* p) {
    short4v lo = *(const short4v*)p;
    short4v hi = *(const short4v*)(p + 4);
    short8 v;
    v[0] = lo[0]; v[1] = lo[1]; v[2] = lo[2]; v[3] = lo[3];
    v[4] = hi[0]; v[5] = hi[1]; v[6] = hi[2]; v[7] = hi[3];
    return v;
}

// ---------------------------------------------------------------------------
// Kernel 2: prep features, MFMA version. 1 wave per block = 16 points.
// y1 = Ws*y+bs and key = Wk*y1+bk as 16x16x32 MFMA chains; y1 C->A transpose
// through a 2.2 KB LDS buffer (attn's u_lds pattern); query via Wq4 VALU.
// All weight reads lane-major contiguous; all global writes coalesced 8B.
// ---------------------------------------------------------------------------
__global__ __launch_bounds__(64) void prep_features(
    const float* __restrict__ x, const float* __restrict__ y,
    const unsigned short* __restrict__ WsL, const float* __restrict__ bs,
    const unsigned short* __restrict__ WkL, const float* __restrict__ bk,
    const float* __restrict__ Wq4,
    unsigned short* __restrict__ y1bf, unsigned short* __restrict__ keybf,
    unsigned short* __restrict__ qrybf) {
    __shared__ unsigned short t_lds[16 * UPITCH];

    int b = blockIdx.x >> 8;
    int n0 = (blockIdx.x & 255) << 4;
    int lane = threadIdx.x;
    int m = lane & 15, quad = lane >> 4;
    size_t ybase = (size_t)b * CC * NN;

    // ---- y A-frags: lane m = point n0+m, k = channel ----
    short8 yA[2];
#pragma unroll
    for (int ks = 0; ks < 2; ++ks)
#pragma unroll
        for (int j = 0; j < 8; ++j)
            yA[ks][j] = (short)f2bf(y[ybase + (size_t)(ks * 32 + quad * 8 + j) * NN + n0 + m]);

    // ---- GEMM y1 = Ws*y + bs -> C-layout -> LDS ----
#pragma unroll
    for (int ot = 0; ot < 4; ++ot) {
        short8 b0 = *(const short8*)(WsL + ((ot * 2 + 0) * 64 + lane) * 8);
        short8 b1 = *(const short8*)(WsL + ((ot * 2 + 1) * 64 + lane) * 8);
        floatx4 acc = (floatx4){0.f, 0.f, 0.f, 0.f};
        acc = __builtin_amdgcn_mfma_f32_16x16x32_bf16(yA[0], b0, acc, 0, 0, 0);
        acc = __builtin_amdgcn_mfma_f32_16x16x32_bf16(yA[1], b1, acc, 0, 0, 0);
        float bsv = bs[ot * 16 + m];
#pragma unroll
        for (int r = 0; r < 4; ++r)
            t_lds[(4 * quad + r) * UPITCH + ot * 16 + m] = f2bf(acc[r] + bsv);
    }
    __syncthreads();

    // ---- y1 A-frags ----
    short8 uA[2];
#pragma unroll
    for (int ks = 0; ks < 2; ++ks)
        uA[ks] = lds_frag(&t_lds[m * UPITCH + ks * 32 + quad * 8]);

    // ---- coalesced y1bf copy-out: lane -> (point p, 16-ch chunk ck) ----
    int p = lane >> 2, ck = lane & 3;
    size_t obase = ((size_t)b * NN + n0 + p) * CC + ck * 16;
#pragma unroll
    for (int s = 0; s < 4; ++s)
        *(ushort4v*)(y1bf + obase + s * 4) =
            *(const ushort4v*)&t_lds[p * UPITCH + ck * 16 + s * 4];
    __syncthreads();

    // ---- GEMM key = Wk*y1 + bk -> LDS (reuse; wave-lockstep safe) ----
#pragma unroll
    for (int ot = 0; ot < 4; ++ot) {
        short8 b0 = *(const short8*)(WkL + ((ot * 2 + 0) * 64 + lane) * 8);
        short8 b1 = *(const short8*)(WkL + ((ot * 2 + 1) * 64 + lane) * 8);
        floatx4 acc = (floatx4){0.f, 0.f, 0.f, 0.f};
        acc = __builtin_amdgcn_mfma_f32_16x16x32_bf16(uA[0], b0, acc, 0, 0, 0);
        acc = __builtin_amdgcn_mfma_f32_16x16x32_bf16(uA[1], b1, acc, 0, 0, 0);
        float bkv = bk[ot * 16 + m];
#pragma unroll
        for (int r = 0; r < 4; ++r)
            t_lds[(4 * quad + r) * UPITCH + ot * 16 + m] = f2bf(acc[r] + bkv);
    }
    __syncthreads();
#pragma unroll
    for (int s = 0; s < 4; ++s)
        *(ushort4v*)(keybf + obase + s * 4) =
            *(const ushort4v*)&t_lds[p * UPITCH + ck * 16 + s * 4];

    // ---- query = Wq*x + bq, computed directly in copy-out layout ----
    float x0 = x[(size_t)(b * 3 + 0) * NN + n0 + p];
    float x1 = x[(size_t)(b * 3 + 1) * NN + n0 + p];
    float x2 = x[(size_t)(b * 3 + 2) * NN + n0 + p];
#pragma unroll
    for (int s = 0; s < 4; ++s) {
        ushort4v pk;
#pragma unroll
        for (int e = 0; e < 4; ++e) {
            int ch = ck * 16 + s * 4 + e;
            const float4 w = *(const float4*)(Wq4 + 4 * ch);
            pk[e] = f2bf(w.x * x0 + w.y * x1 + w.z * x2 + w.w);
        }
        *(ushort4v*)(qrybf + obase + s * 4) = pk;
    }
}

// ---------------------------------------------------------------------------
// Kernel 3: exact KNN, branch-coherent 3-phase (unchanged — verified).
// ---------------------------------------------------------------------------
__global__ __launch_bounds__(256) void knn_kernel(const float* __restrict__ x,
                                                  int* __restrict__ idx_out) {
    __shared__ __align__(16) char smem[65536];
    float4* pts = (float4*)smem;
    unsigned long long* surv = (unsigned long long*)smem;

    int b = blockIdx.x >> 10;
    int grp = blockIdx.x & 1023;
    int w = threadIdx.x >> 6;
    int lane = threadIdx.x & 63;
    int n = (grp << 2) + w;

    const float* xb = x + (size_t)b * 3 * NN;
    for (int i = threadIdx.x; i < NN; i += 256)
        pts[i] = make_float4(xb[i], xb[NN + i], xb[2 * NN + i], 0.f);
    __syncthreads();

    float4 q = pts[n];

    float dreg[64];
    float vmin = 3.4e38f;
#pragma unroll
    for (int r = 0; r < 64; ++r) {
        float4 c = pts[(r << 6) + lane];
        float ax = q.x - c.x, ay = q.y - c.y, az = q.z - c.z;
        float d = ax * ax + ay * ay + az * az;
        dreg[r] = d;
        vmin = fminf(vmin, d);
    }
#pragma unroll
    for (int k = 2; k <= 64; k <<= 1) {
#pragma unroll
        for (int j = k >> 1; j > 0; j >>= 1) {
            float o = __shfl_xor(vmin, j);
            bool lower = (lane & j) == 0;
            bool up = (lane & k) == 0;
            float mn = fminf(vmin, o), mx = fmaxf(vmin, o);
            vmin = (lower == up) ? mn : mx;
        }
    }
    float T = __shfl(vmin, 15);

    __syncthreads();

    unsigned long long* buf = surv + (w << 7);
    unsigned cnt = 0;
#pragma unroll
    for (int r = 0; r < 64; ++r) {
        float d = dreg[r];
        bool hit = d <= T;
        unsigned long long mask = __ballot(hit);
        if (hit) {
            unsigned off = cnt + (unsigned)__popcll(mask & ((1ull << lane) - 1ull));
            if (off < 128) {
                int j = (r << 6) + lane;
                buf[off] = ((unsigned long long)__float_as_uint(d) << 32) | (unsigned)j;
            }
        }
        cnt += (unsigned)__popcll(mask);
    }
    if (cnt > 128) cnt = 128;

    unsigned long long v0 = (lane < (int)cnt) ? buf[lane] : 0xFFFFFFFFFFFFFFFFull;
    unsigned long long v1 = (lane + 64 < (int)cnt) ? buf[lane + 64] : 0xFFFFFFFFFFFFFFFFull;
#pragma unroll
    for (int k = 2; k <= 128; k <<= 1) {
#pragma unroll
        for (int j = k >> 1; j > 0; j >>= 1) {
            if (j >= 64) {
                unsigned long long lo = umin64(v0, v1), hi = umax64(v0, v1);
                v0 = lo; v1 = hi;
            } else {
                bool lower = (lane & j) == 0;
                unsigned long long o0 = shfl_xor_u64(v0, j);
                bool up0 = ((lane & k) == 0);
                v0 = (lower == up0) ? umin64(v0, o0) : umax64(v0, o0);
                unsigned long long o1 = shfl_xor_u64(v1, j);
                bool up1 = (((64 + lane) & k) == 0);
                v1 = (lower == up1) ? umin64(v1, o1) : umax64(v1, o1);
            }
        }
    }
    if (lane < KNN)
        idx_out[((size_t)b * NN + n) * KNN + lane] = (int)(unsigned)(v0 & 0xFFFFFFFFull);
}

// ---------------------------------------------------------------------------
// Kernel 4: fused MFMA attention (unchanged from round 8 — verified 104 µs).
// ---------------------------------------------------------------------------
__global__ __launch_bounds__(256, 4) void attn_mfma(
    const float* __restrict__ x, const float* __restrict__ y,
    const unsigned short* __restrict__ y1bf, const unsigned short* __restrict__ keybf,
    const unsigned short* __restrict__ qrybf, const int* __restrict__ idx,
    const float* __restrict__ P1p, const unsigned short* __restrict__ P2L,
    const float* __restrict__ pb2, const unsigned short* __restrict__ A1L,
    const float* __restrict__ ab1f, const float* __restrict__ bn2s_c,
    const unsigned short* __restrict__ A2L, const float* __restrict__ WendT,
    const float* __restrict__ bend,
    float* __restrict__ out) {
    __shared__ unsigned short u_lds[64 * UPITCH];
    __shared__ unsigned short hid_lds[64 * HPITCH];
    __shared__ float wend_s[4096];
    __shared__ float agg_lds[4 * 64];
    __shared__ float outstage[64 * 4];

    int blk = blockIdx.x;
    int b = blk & 3;
    int n0 = (blk >> 2) << 2;
    int w = threadIdx.x >> 6;
    int lane = threadIdx.x & 63;
    int m = lane & 15, quad = lane >> 4;
    int pt = n0 + w;
    size_t bpt = (size_t)b * NN + pt;

    for (int i = threadIdx.x; i < 1024; i += 256)
        ((float4*)wend_s)[i] = ((const float4*)WendT)[i];

    int jm = idx[bpt * KNN + m];
    int j4[4];
#pragma unroll
    for (int r = 0; r < 4; ++r) j4[r] = idx[bpt * KNN + 4 * quad + r];
    unsigned short kvu[4][4];
    unsigned short qu[4];
#pragma unroll
    for (int nt = 0; nt < 4; ++nt) {
        qu[nt] = qrybf[bpt * CC + nt * 16 + m];
#pragma unroll
        for (int r = 0; r < 4; ++r)
            kvu[nt][r] = keybf[((size_t)b * NN + j4[r]) * CC + nt * 16 + m];
    }

    float dx = x[(size_t)(b * 3 + 0) * NN + pt] - x[(size_t)(b * 3 + 0) * NN + jm];
    float dy = x[(size_t)(b * 3 + 1) * NN + pt] - x[(size_t)(b * 3 + 1) * NN + jm];
    float dz = x[(size_t)(b * 3 + 2) * NN + pt] - x[(size_t)(b * 3 + 2) * NN + jm];
    short8 h1A[2];
#pragma unroll
    for (int ks = 0; ks < 2; ++ks) {
#pragma unroll
        for (int j = 0; j < 8; ++j) {
            int h1 = ks * 32 + quad * 8 + j;
            const float4 p = *(const float4*)(P1p + 4 * h1);
            float a = fmaxf(p.x * dx + p.y * dy + p.z * dz + p.w, 0.f);
            h1A[ks][j] = (short)f2bf(a);
        }
    }

    floatx4 pacc[4];
#pragma unroll
    for (int nt = 0; nt < 4; ++nt) pacc[nt] = (floatx4){0.f, 0.f, 0.f, 0.f};
#pragma unroll
    for (int ks = 0; ks < 2; ++ks) {
#pragma unroll
        for (int nt = 0; nt < 4; ++nt) {
            short8 bb = *(const short8*)(P2L + ((nt * 2 + ks) * 64 + lane) * 8);
            pacc[nt] = __builtin_amdgcn_mfma_f32_16x16x32_bf16(h1A[ks], bb, pacc[nt], 0, 0, 0);
        }
    }
#pragma unroll
    for (int nt = 0; nt < 4; ++nt) {
        float pb = pb2[nt * 16 + m];
#pragma unroll
        for (int r = 0; r < 4; ++r) pacc[nt][r] += pb;
    }

#pragma unroll
    for (int nt = 0; nt < 4; ++nt) {
        float qv = bf2f(qu[nt]);
#pragma unroll
        for (int r = 0; r < 4; ++r) {
            float uu = qv - bf2f(kvu[nt][r]) + pacc[nt][r];
            u_lds[(w * 16 + 4 * quad + r) * UPITCH + nt * 16 + m] = f2bf(uu);
        }
    }

    short8 uA[2];
#pragma unroll
    for (int ks = 0; ks < 2; ++ks)
        uA[ks] = lds_frag(&u_lds[(w * 16 + m) * UPITCH + ks * 32 + quad * 8]);

    floatx4 acc2[4];
#pragma unroll
    for (int nt = 0; nt < 4; ++nt) acc2[nt] = (floatx4){0.f, 0.f, 0.f, 0.f};

    for (int hf = 0; hf < 2; ++hf) {
#pragma unroll 4
        for (int nt = 0; nt < 8; ++nt) {
            int ht = hf * 8 + nt;
            const unsigned short* a1t = A1L + ht * 1024 + lane * 8;
            short8 b0 = *(const short8*)(a1t);
            short8 b1 = *(const short8*)(a1t + 512);
            floatx4 acc = (floatx4){0.f, 0.f, 0.f, 0.f};
            acc = __builtin_amdgcn_mfma_f32_16x16x32_bf16(uA[0], b0, acc, 0, 0, 0);
            acc = __builtin_amdgcn_mfma_f32_16x16x32_bf16(uA[1], b1, acc, 0, 0, 0);
            int h = ht * 16 + m;
            float s = bn2s_c[h], t0 = ab1f[h];
#pragma unroll
            for (int r = 0; r < 4; ++r) {
                float hv = fmaxf(acc[r] * s + t0, 0.f);
                hid_lds[(w * 16 + 4 * quad + r) * HPITCH + nt * 16 + m] = f2bf(hv);
            }
        }
#pragma unroll 2
        for (int ks = 0; ks < 4; ++ks) {
            short8 hA = lds_frag(&hid_lds[(w * 16 + m) * HPITCH + ks * 32 + quad * 8]);
#pragma unroll
            for (int nt = 0; nt < 4; ++nt) {
                int kk = hf * 4 + ks;
                short8 bb = *(const short8*)(A2L + ((nt * 8 + kk) * 64 + lane) * 8);
                acc2[nt] = __builtin_amdgcn_mfma_f32_16x16x32_bf16(hA, bb, acc2[nt], 0, 0, 0);
            }
        }
    }

#pragma unroll
    for (int nt = 0; nt < 4; ++nt) {
        float l0 = acc2[nt][0], l1 = acc2[nt][1], l2 = acc2[nt][2], l3 = acc2[nt][3];
        float mx = fmaxf(fmaxf(l0, l1), fmaxf(l2, l3));
        mx = fmaxf(mx, __shfl_xor(mx, 16));
        mx = fmaxf(mx, __shfl_xor(mx, 32));
        float e0 = __expf(l0 - mx), e1 = __expf(l1 - mx);
        float e2 = __expf(l2 - mx), e3 = __expf(l3 - mx);
        float sum = (e0 + e1) + (e2 + e3);
        sum += __shfl_xor(sum, 16);
        sum += __shfl_xor(sum, 32);
        float y1v = bf2f(y1bf[bpt * CC + nt * 16 + m]);
        float contrib = e0 * (y1v + pacc[nt][0]) + e1 * (y1v + pacc[nt][1]) +
                        e2 * (y1v + pacc[nt][2]) + e3 * (y1v + pacc[nt][3]);
        contrib += __shfl_xor(contrib, 16);
        contrib += __shfl_xor(contrib, 32);
        float agg = contrib / sum;
        if (quad == 0) agg_lds[w * 64 + nt * 16 + m] = agg;
    }

    __syncthreads();

    float acco = 0.f;
#pragma unroll
    for (int c4 = 0; c4 < 16; ++c4) {
        float4 wv = *(const float4*)&wend_s[c4 * 256 + lane * 4];
        float4 av = *(const float4*)(agg_lds + w * 64 + c4 * 4);
        acco += wv.x * av.x + wv.y * av.y + wv.z * av.z + wv.w * av.w;
    }
    acco += bend[lane];
    outstage[lane * 4 + w] = acco;
    __syncthreads();

    int t = threadIdx.x;
    int o = t >> 2, p = t & 3;
    size_t oi = ((size_t)(b * CC + o)) * NN + n0 + p;
    out[oi] = outstage[t] + y[oi];
}

// ---------------------------------------------------------------------------
extern "C" void kernel_launch(void* const* d_in, const int* in_sizes, int n_in,
                              void* d_out, int out_size, void* d_ws, size_t ws_size,
                              hipStream_t stream) {
    const float* x    = (const float*)d_in[0];
    const float* y    = (const float*)d_in[1];
    const float* Ws   = (const float*)d_in[2];
    const float* bs   = (const float*)d_in[3];
    const float* Wk   = (const float*)d_in[4];
    const float* bk   = (const float*)d_in[5];
    const float* Wq   = (const float*)d_in[6];
    const float* bq   = (const float*)d_in[7];
    const float* P1   = (const float*)d_in[8];
    const float* pb1  = (const float*)d_in[9];
    const float* g1   = (const float*)d_in[10];
    const float* b1   = (const float*)d_in[11];
    const float* m1   = (const float*)d_in[12];
    const float* v1   = (const float*)d_in[13];
    const float* P2   = (const float*)d_in[14];
    const float* pb2  = (const float*)d_in[15];
    const float* A1   = (const float*)d_in[16];
    const float* ab1  = (const float*)d_in[17];
    const float* g2   = (const float*)d_in[18];
    const float* b2   = (const float*)d_in[19];
    const float* m2   = (const float*)d_in[20];
    const float* v2   = (const float*)d_in[21];
    const float* A2   = (const float*)d_in[22];
    const float* ab2  = (const float*)d_in[23];  // dropped (softmax-invariant)
    const float* Wend = (const float*)d_in[24];
    const float* bend = (const float*)d_in[25];
    (void)ab2;

    unsigned short* usws = (unsigned short*)d_ws;
    unsigned short* y1bf  = usws;                  // 1,048,576 us
    unsigned short* keybf = usws + 1048576;        // 1,048,576 us
    unsigned short* qrybf = usws + 2097152;        // 1,048,576 us
    int* idx = (int*)(usws + 3145728);             // 262,144 ints
    unsigned short* A1L = usws + 3670016;          // 16,384 us
    unsigned short* A2L = A1L + 16384;             // 16,384 us
    unsigned short* P2L = A2L + 16384;             // 4,096 us
    unsigned short* WsL = P2L + 4096;              // 8,192 us
    unsigned short* WkL = WsL + 8192;              // 8,192 us
    float* WendT = (float*)(WkL + 8192);           // 4,096 f (16B-aligned)
    float* Wq4   = WendT + 4096;                   // 256 f
    float* P1p   = Wq4 + 256;                      // 256 f
    float* ab1f  = P1p + 256;                      // 256 f
    float* bn2sc = ab1f + 256;                     // 256 f
    float* out   = (float*)d_out;

    hipLaunchKernelGGL(prep_params, dim3(PREP_NB), dim3(256), 0, stream,
                       P1, pb1, P2, A1, ab1, A2, g1, b1, m1, v1, g2, b2, m2, v2,
                       Wend, Ws, Wk, Wq, bq,
                       A1L, A2L, P2L, WendT, WsL, WkL, Wq4, P1p, ab1f, bn2sc);
    hipLaunchKernelGGL(prep_features, dim3(1024), dim3(64), 0, stream,
                       x, y, WsL, bs, WkL, bk, Wq4, y1bf, keybf, qrybf);
    hipLaunchKernelGGL(knn_kernel, dim3(4096), dim3(256), 0, stream, x, idx);
    hipLaunchKernelGGL(attn_mfma, dim3(4096), dim3(256), 0, stream,
                       x, y, y1bf, keybf, qrybf, idx,
                       P1p, P2L, pb2, A1L, ab1f, bn2sc, A2L, WendT,
                       bend, out);
}

// Round 10
// 241.965 us; speedup vs baseline: 7.5603x; 1.1314x over previous
//
#include <hip/hip_runtime.h>
#include <hip/hip_bf16.h>

#define BB 4
#define CC 64
#define NN 4096
#define HH 64
#define AH 256
#define KNN 16
#define EPSV 1e-5f
#define PREP_NB 32

typedef __attribute__((ext_vector_type(8))) short short8;
typedef __attribute__((ext_vector_type(4))) short short4v;
typedef __attribute__((ext_vector_type(4))) unsigned short ushort4v;
typedef __attribute__((ext_vector_type(4))) float floatx4;

__device__ __forceinline__ unsigned short f2bf(float f) {
    unsigned u = __float_as_uint(f);
    u += 0x7FFFu + ((u >> 16) & 1u);   // round-to-nearest-even
    return (unsigned short)(u >> 16);
}
__device__ __forceinline__ float bf2f(unsigned short u) {
    return __uint_as_float(((unsigned)u) << 16);
}

__device__ __forceinline__ unsigned long long umin64(unsigned long long a, unsigned long long b) {
    return a < b ? a : b;
}
__device__ __forceinline__ unsigned long long umax64(unsigned long long a, unsigned long long b) {
    return a > b ? a : b;
}
__device__ __forceinline__ unsigned long long shfl_xor_u64(unsigned long long v, int m) {
    int lo = __shfl_xor((int)(unsigned)(v & 0xFFFFFFFFull), m);
    int hi = __shfl_xor((int)(unsigned)(v >> 32), m);
    return ((unsigned long long)(unsigned)hi << 32) | (unsigned)lo;
}

// ---------------------------------------------------------------------------
// Kernel 1 (32 blocks): fold BN params; emit ALL weights in lane-major
// MFMA-tile layouts (1-KB contiguous wave reads).
//   WendL[((wv*2+ks)*64+lane)*8+e] = bf16(Wend[(wv*16+m)*CC + ks*32+q*8+e])
// ---------------------------------------------------------------------------
__global__ void prep_params(const float* __restrict__ P1, const float* __restrict__ pb1,
                            const float* __restrict__ P2, const float* __restrict__ A1,
                            const float* __restrict__ ab1, const float* __restrict__ A2,
                            const float* __restrict__ g1, const float* __restrict__ b1,
                            const float* __restrict__ m1, const float* __restrict__ v1,
                            const float* __restrict__ g2, const float* __restrict__ b2,
                            const float* __restrict__ m2, const float* __restrict__ v2,
                            const float* __restrict__ Wend, const float* __restrict__ Ws,
                            const float* __restrict__ Wk, const float* __restrict__ Wq,
                            const float* __restrict__ bq,
                            unsigned short* __restrict__ A1L, unsigned short* __restrict__ A2L,
                            unsigned short* __restrict__ P2L, unsigned short* __restrict__ WendL,
                            unsigned short* __restrict__ WsL, unsigned short* __restrict__ WkL,
                            float* __restrict__ Wq4, float* __restrict__ P1p,
                            float* __restrict__ ab1f, float* __restrict__ bn2s_c) {
    int t0 = threadIdx.x;
    int t = blockIdx.x * 256 + t0;
    const int stride = PREP_NB * 256;
    if (blockIdx.x == 0) {
        if (t0 < HH) {
            float s = g1[t0] * rsqrtf(v1[t0] + EPSV);
            float c = b1[t0] - m1[t0] * s;
            P1p[4 * t0 + 0] = P1[3 * t0 + 0] * s;
            P1p[4 * t0 + 1] = P1[3 * t0 + 1] * s;
            P1p[4 * t0 + 2] = P1[3 * t0 + 2] * s;
            P1p[4 * t0 + 3] = pb1[t0] * s + c;
        }
        if (t0 < AH) {
            float s = g2[t0] * rsqrtf(v2[t0] + EPSV);
            bn2s_c[t0] = s;
            ab1f[t0] = ab1[t0] * s + (b2[t0] - m2[t0] * s);
        }
        if (t0 < CC) {
            Wq4[4 * t0 + 0] = Wq[3 * t0 + 0];
            Wq4[4 * t0 + 1] = Wq[3 * t0 + 1];
            Wq4[4 * t0 + 2] = Wq[3 * t0 + 2];
            Wq4[4 * t0 + 3] = bq[t0];
        }
    }
    for (int i = t; i < 16384; i += stride) {   // A1L: 16 ht x 2 ks
        int e = i & 7, lane = (i >> 3) & 63, ks = (i >> 9) & 1, ht = i >> 10;
        int m = lane & 15, q = lane >> 4;
        A1L[i] = f2bf(A1[(ht * 16 + m) * CC + ks * 32 + q * 8 + e]);
    }
    for (int i = t; i < 16384; i += stride) {   // A2L: 4 nt x 8 kk
        int e = i & 7, lane = (i >> 3) & 63, kk = (i >> 9) & 7, nt = i >> 12;
        int m = lane & 15, q = lane >> 4;
        A2L[i] = f2bf(A2[(nt * 16 + m) * AH + kk * 32 + q * 8 + e]);
    }
    for (int i = t; i < 4096; i += stride) {    // P2L: 4 nt x 2 ks
        int e = i & 7, lane = (i >> 3) & 63, ks = (i >> 9) & 1, nt = i >> 10;
        int m = lane & 15, q = lane >> 4;
        P2L[i] = f2bf(P2[(nt * 16 + m) * HH + ks * 32 + q * 8 + e]);
    }
    for (int i = t; i < 4096; i += stride) {    // WendL: 4 wv x 2 ks
        int e = i & 7, lane = (i >> 3) & 63, ks = (i >> 9) & 1, wv = i >> 10;
        int m = lane & 15, q = lane >> 4;
        WendL[i] = f2bf(Wend[(wv * 16 + m) * CC + ks * 32 + q * 8 + e]);
    }
    for (int i = t; i < 8192; i += stride) {    // WsL: 4 ot x 2 ks
        int e = i & 7, lane = (i >> 3) & 63, ks = (i >> 9) & 1, ot = i >> 10;
        int m = lane & 15, q = lane >> 4;
        WsL[i] = f2bf(Ws[(ot * 16 + m) * CC + ks * 32 + q * 8 + e]);
    }
    for (int i = t; i < 8192; i += stride) {    // WkL: 4 ot x 2 ks
        int e = i & 7, lane = (i >> 3) & 63, ks = (i >> 9) & 1, ot = i >> 10;
        int m = lane & 15, q = lane >> 4;
        WkL[i] = f2bf(Wk[(ot * 16 + m) * CC + ks * 32 + q * 8 + e]);
    }
}

#define UPITCH 68
#define HPITCH 68

__device__ __forceinline__ short8 lds_frag(const unsigned short* p) {
    short4v lo = *(const short4v*)p;
    short4v hi = *(const short4v*)(p + 4);
    short8 v;
    v[0] = lo[0]; v[1] = lo[1]; v[2] = lo[2]; v[3] = lo[3];
    v[4] = hi[0]; v[5] = hi[1]; v[6] = hi[2]; v[7] = hi[3];
    return v;
}

// ---------------------------------------------------------------------------
// Kernel 2: prep features, MFMA version (unchanged from round 9 — verified).
// ---------------------------------------------------------------------------
__global__ __launch_bounds__(64) void prep_features(
    const float* __restrict__ x, const float* __restrict__ y,
    const unsigned short* __restrict__ WsL, const float* __restrict__ bs,
    const unsigned short* __restrict__ WkL, const float* __restrict__ bk,
    const float* __restrict__ Wq4,
    unsigned short* __restrict__ y1bf, unsigned short* __restrict__ keybf,
    unsigned short* __restrict__ qrybf) {
    __shared__ unsigned short t_lds[16 * UPITCH];

    int b = blockIdx.x >> 8;
    int n0 = (blockIdx.x & 255) << 4;
    int lane = threadIdx.x;
    int m = lane & 15, quad = lane >> 4;
    size_t ybase = (size_t)b * CC * NN;

    short8 yA[2];
#pragma unroll
    for (int ks = 0; ks < 2; ++ks)
#pragma unroll
        for (int j = 0; j < 8; ++j)
            yA[ks][j] = (short)f2bf(y[ybase + (size_t)(ks * 32 + quad * 8 + j) * NN + n0 + m]);

#pragma unroll
    for (int ot = 0; ot < 4; ++ot) {
        short8 b0 = *(const short8*)(WsL + ((ot * 2 + 0) * 64 + lane) * 8);
        short8 b1 = *(const short8*)(WsL + ((ot * 2 + 1) * 64 + lane) * 8);
        floatx4 acc = (floatx4){0.f, 0.f, 0.f, 0.f};
        acc = __builtin_amdgcn_mfma_f32_16x16x32_bf16(yA[0], b0, acc, 0, 0, 0);
        acc = __builtin_amdgcn_mfma_f32_16x16x32_bf16(yA[1], b1, acc, 0, 0, 0);
        float bsv = bs[ot * 16 + m];
#pragma unroll
        for (int r = 0; r < 4; ++r)
            t_lds[(4 * quad + r) * UPITCH + ot * 16 + m] = f2bf(acc[r] + bsv);
    }
    __syncthreads();

    short8 uA[2];
#pragma unroll
    for (int ks = 0; ks < 2; ++ks)
        uA[ks] = lds_frag(&t_lds[m * UPITCH + ks * 32 + quad * 8]);

    int p = lane >> 2, ck = lane & 3;
    size_t obase = ((size_t)b * NN + n0 + p) * CC + ck * 16;
#pragma unroll
    for (int s = 0; s < 4; ++s)
        *(ushort4v*)(y1bf + obase + s * 4) =
            *(const ushort4v*)&t_lds[p * UPITCH + ck * 16 + s * 4];
    __syncthreads();

#pragma unroll
    for (int ot = 0; ot < 4; ++ot) {
        short8 b0 = *(const short8*)(WkL + ((ot * 2 + 0) * 64 + lane) * 8);
        short8 b1 = *(const short8*)(WkL + ((ot * 2 + 1) * 64 + lane) * 8);
        floatx4 acc = (floatx4){0.f, 0.f, 0.f, 0.f};
        acc = __builtin_amdgcn_mfma_f32_16x16x32_bf16(uA[0], b0, acc, 0, 0, 0);
        acc = __builtin_amdgcn_mfma_f32_16x16x32_bf16(uA[1], b1, acc, 0, 0, 0);
        float bkv = bk[ot * 16 + m];
#pragma unroll
        for (int r = 0; r < 4; ++r)
            t_lds[(4 * quad + r) * UPITCH + ot * 16 + m] = f2bf(acc[r] + bkv);
    }
    __syncthreads();
#pragma unroll
    for (int s = 0; s < 4; ++s)
        *(ushort4v*)(keybf + obase + s * 4) =
            *(const ushort4v*)&t_lds[p * UPITCH + ck * 16 + s * 4];

    float x0 = x[(size_t)(b * 3 + 0) * NN + n0 + p];
    float x1 = x[(size_t)(b * 3 + 1) * NN + n0 + p];
    float x2 = x[(size_t)(b * 3 + 2) * NN + n0 + p];
#pragma unroll
    for (int s = 0; s < 4; ++s) {
        ushort4v pk;
#pragma unroll
        for (int e = 0; e < 4; ++e) {
            int ch = ck * 16 + s * 4 + e;
            const float4 w = *(const float4*)(Wq4 + 4 * ch);
            pk[e] = f2bf(w.x * x0 + w.y * x1 + w.z * x2 + w.w);
        }
        *(ushort4v*)(qrybf + obase + s * 4) = pk;
    }
}

// ---------------------------------------------------------------------------
// Kernel 3: exact KNN, branch-coherent 3-phase (unchanged — verified).
// ---------------------------------------------------------------------------
__global__ __launch_bounds__(256) void knn_kernel(const float* __restrict__ x,
                                                  int* __restrict__ idx_out) {
    __shared__ __align__(16) char smem[65536];
    float4* pts = (float4*)smem;
    unsigned long long* surv = (unsigned long long*)smem;

    int b = blockIdx.x >> 10;
    int grp = blockIdx.x & 1023;
    int w = threadIdx.x >> 6;
    int lane = threadIdx.x & 63;
    int n = (grp << 2) + w;

    const float* xb = x + (size_t)b * 3 * NN;
    for (int i = threadIdx.x; i < NN; i += 256)
        pts[i] = make_float4(xb[i], xb[NN + i], xb[2 * NN + i], 0.f);
    __syncthreads();

    float4 q = pts[n];

    float dreg[64];
    float vmin = 3.4e38f;
#pragma unroll
    for (int r = 0; r < 64; ++r) {
        float4 c = pts[(r << 6) + lane];
        float ax = q.x - c.x, ay = q.y - c.y, az = q.z - c.z;
        float d = ax * ax + ay * ay + az * az;
        dreg[r] = d;
        vmin = fminf(vmin, d);
    }
#pragma unroll
    for (int k = 2; k <= 64; k <<= 1) {
#pragma unroll
        for (int j = k >> 1; j > 0; j >>= 1) {
            float o = __shfl_xor(vmin, j);
            bool lower = (lane & j) == 0;
            bool up = (lane & k) == 0;
            float mn = fminf(vmin, o), mx = fmaxf(vmin, o);
            vmin = (lower == up) ? mn : mx;
        }
    }
    float T = __shfl(vmin, 15);

    __syncthreads();

    unsigned long long* buf = surv + (w << 7);
    unsigned cnt = 0;
#pragma unroll
    for (int r = 0; r < 64; ++r) {
        float d = dreg[r];
        bool hit = d <= T;
        unsigned long long mask = __ballot(hit);
        if (hit) {
            unsigned off = cnt + (unsigned)__popcll(mask & ((1ull << lane) - 1ull));
            if (off < 128) {
                int j = (r << 6) + lane;
                buf[off] = ((unsigned long long)__float_as_uint(d) << 32) | (unsigned)j;
            }
        }
        cnt += (unsigned)__popcll(mask);
    }
    if (cnt > 128) cnt = 128;

    unsigned long long v0 = (lane < (int)cnt) ? buf[lane] : 0xFFFFFFFFFFFFFFFFull;
    unsigned long long v1 = (lane + 64 < (int)cnt) ? buf[lane + 64] : 0xFFFFFFFFFFFFFFFFull;
#pragma unroll
    for (int k = 2; k <= 128; k <<= 1) {
#pragma unroll
        for (int j = k >> 1; j > 0; j >>= 1) {
            if (j >= 64) {
                unsigned long long lo = umin64(v0, v1), hi = umax64(v0, v1);
                v0 = lo; v1 = hi;
            } else {
                bool lower = (lane & j) == 0;
                unsigned long long o0 = shfl_xor_u64(v0, j);
                bool up0 = ((lane & k) == 0);
                v0 = (lower == up0) ? umin64(v0, o0) : umax64(v0, o0);
                unsigned long long o1 = shfl_xor_u64(v1, j);
                bool up1 = (((64 + lane) & k) == 0);
                v1 = (lower == up1) ? umin64(v1, o1) : umax64(v1, o1);
            }
        }
    }
    if (lane < KNN)
        idx_out[((size_t)b * NN + n) * KNN + lane] = (int)(unsigned)(v0 & 0xFFFFFFFFull);
}

// ---------------------------------------------------------------------------
// Kernel 4: fused MFMA attention v2. 8 points/block, 2 points/wave: every
// weight B-load feeds 2 MFMAs (halved per-point weight traffic + TA work).
// Hidden dim processed in 4 quarters (hid_lds 17.4 KB). Final Wend dot is a
// single MFMA pair over the block's 8 points (no 16 KB wend_s). LDS 39 KB.
// ---------------------------------------------------------------------------
__global__ __launch_bounds__(256, 3) void attn_mfma(
    const float* __restrict__ x, const float* __restrict__ y,
    const unsigned short* __restrict__ y1bf, const unsigned short* __restrict__ keybf,
    const unsigned short* __restrict__ qrybf, const int* __restrict__ idx,
    const float* __restrict__ P1p, const unsigned short* __restrict__ P2L,
    const float* __restrict__ pb2, const unsigned short* __restrict__ A1L,
    const float* __restrict__ ab1f, const float* __restrict__ bn2s_c,
    const unsigned short* __restrict__ A2L, const unsigned short* __restrict__ WendL,
    const float* __restrict__ bend,
    float* __restrict__ out) {
    __shared__ unsigned short u_lds[128 * UPITCH];    // 17.4 KB
    __shared__ unsigned short hid_lds[128 * HPITCH];  // 17.4 KB
    __shared__ float agg_lds[8 * 68];                 // 2.2 KB, [point][ch]
    __shared__ float outstage[512];                   // 2 KB, [o][point]

    int blk = blockIdx.x;
    int b = blk & 3;
    int n0 = (blk >> 2) << 3;          // 8 points per block
    int w = threadIdx.x >> 6;
    int lane = threadIdx.x & 63;
    int m = lane & 15, quad = lane >> 4;

    int pt[2];
    size_t bpt[2];
#pragma unroll
    for (int t = 0; t < 2; ++t) {
        pt[t] = n0 + 2 * w + t;
        bpt[t] = (size_t)b * NN + pt[t];
    }

    // ---- gathers for both points (issued early) ----
    int jm[2], j4[2][4];
    unsigned short qu[2][4], kvu[2][4][4];
#pragma unroll
    for (int t = 0; t < 2; ++t) {
        jm[t] = idx[bpt[t] * KNN + m];
#pragma unroll
        for (int r = 0; r < 4; ++r) j4[t][r] = idx[bpt[t] * KNN + 4 * quad + r];
#pragma unroll
        for (int nt = 0; nt < 4; ++nt) {
            qu[t][nt] = qrybf[bpt[t] * CC + nt * 16 + m];
#pragma unroll
            for (int r = 0; r < 4; ++r)
                kvu[t][nt][r] = keybf[((size_t)b * NN + j4[t][r]) * CC + nt * 16 + m];
        }
    }

    // ---- pos-encoding hidden1 A-frags ----
    short8 h1A[2][2];
#pragma unroll
    for (int t = 0; t < 2; ++t) {
        float dx = x[(size_t)(b * 3 + 0) * NN + pt[t]] - x[(size_t)(b * 3 + 0) * NN + jm[t]];
        float dy = x[(size_t)(b * 3 + 1) * NN + pt[t]] - x[(size_t)(b * 3 + 1) * NN + jm[t]];
        float dz = x[(size_t)(b * 3 + 2) * NN + pt[t]] - x[(size_t)(b * 3 + 2) * NN + jm[t]];
#pragma unroll
        for (int ks = 0; ks < 2; ++ks)
#pragma unroll
            for (int j = 0; j < 8; ++j) {
                int h1 = ks * 32 + quad * 8 + j;
                const float4 p = *(const float4*)(P1p + 4 * h1);
                float a = fmaxf(p.x * dx + p.y * dy + p.z * dz + p.w, 0.f);
                h1A[t][ks][j] = (short)f2bf(a);
            }
    }

    // ---- GEMM-P2 (B shared across both points) ----
    floatx4 pacc[2][4];
#pragma unroll
    for (int t = 0; t < 2; ++t)
#pragma unroll
        for (int nt = 0; nt < 4; ++nt) pacc[t][nt] = (floatx4){0.f, 0.f, 0.f, 0.f};
#pragma unroll
    for (int ks = 0; ks < 2; ++ks)
#pragma unroll
        for (int nt = 0; nt < 4; ++nt) {
            short8 bb = *(const short8*)(P2L + ((nt * 2 + ks) * 64 + lane) * 8);
            pacc[0][nt] = __builtin_amdgcn_mfma_f32_16x16x32_bf16(h1A[0][ks], bb, pacc[0][nt], 0, 0, 0);
            pacc[1][nt] = __builtin_amdgcn_mfma_f32_16x16x32_bf16(h1A[1][ks], bb, pacc[1][nt], 0, 0, 0);
        }
#pragma unroll
    for (int nt = 0; nt < 4; ++nt) {
        float pb = pb2[nt * 16 + m];
#pragma unroll
        for (int t = 0; t < 2; ++t)
#pragma unroll
            for (int r = 0; r < 4; ++r) pacc[t][nt][r] += pb;
    }

    // ---- u = query - key + pe -> bf16 LDS ----
#pragma unroll
    for (int t = 0; t < 2; ++t)
#pragma unroll
        for (int nt = 0; nt < 4; ++nt) {
            float qv = bf2f(qu[t][nt]);
#pragma unroll
            for (int r = 0; r < 4; ++r) {
                float uu = qv - bf2f(kvu[t][nt][r]) + pacc[t][nt][r];
                u_lds[(w * 32 + t * 16 + 4 * quad + r) * UPITCH + nt * 16 + m] = f2bf(uu);
            }
        }

    short8 uA[2][2];
#pragma unroll
    for (int t = 0; t < 2; ++t)
#pragma unroll
        for (int ks = 0; ks < 2; ++ks)
            uA[t][ks] = lds_frag(&u_lds[(w * 32 + t * 16 + m) * UPITCH + ks * 32 + quad * 8]);

    // ---- GEMM1 + GEMM2 over 4 hidden quarters (wave-local) ----
    floatx4 acc2[2][4];
#pragma unroll
    for (int t = 0; t < 2; ++t)
#pragma unroll
        for (int nt = 0; nt < 4; ++nt) acc2[t][nt] = (floatx4){0.f, 0.f, 0.f, 0.f};

    for (int qd = 0; qd < 4; ++qd) {
#pragma unroll
        for (int nt4 = 0; nt4 < 4; ++nt4) {
            int ht = qd * 4 + nt4;
            const unsigned short* a1t = A1L + ht * 1024 + lane * 8;
            short8 b0 = *(const short8*)(a1t);
            short8 b1 = *(const short8*)(a1t + 512);
            int h = ht * 16 + m;
            float s = bn2s_c[h], t0 = ab1f[h];
#pragma unroll
            for (int t = 0; t < 2; ++t) {
                floatx4 acc = (floatx4){0.f, 0.f, 0.f, 0.f};
                acc = __builtin_amdgcn_mfma_f32_16x16x32_bf16(uA[t][0], b0, acc, 0, 0, 0);
                acc = __builtin_amdgcn_mfma_f32_16x16x32_bf16(uA[t][1], b1, acc, 0, 0, 0);
#pragma unroll
                for (int r = 0; r < 4; ++r) {
                    float hv = fmaxf(acc[r] * s + t0, 0.f);
                    hid_lds[(w * 32 + t * 16 + 4 * quad + r) * HPITCH + nt4 * 16 + m] = f2bf(hv);
                }
            }
        }
        short8 hA[2][2];
#pragma unroll
        for (int t = 0; t < 2; ++t)
#pragma unroll
            for (int ks = 0; ks < 2; ++ks)
                hA[t][ks] = lds_frag(&hid_lds[(w * 32 + t * 16 + m) * HPITCH + ks * 32 + quad * 8]);
#pragma unroll
        for (int ks = 0; ks < 2; ++ks)
#pragma unroll
            for (int nt = 0; nt < 4; ++nt) {
                int kk = qd * 2 + ks;
                short8 bb = *(const short8*)(A2L + ((nt * 8 + kk) * 64 + lane) * 8);
                acc2[0][nt] = __builtin_amdgcn_mfma_f32_16x16x32_bf16(hA[0][ks], bb, acc2[0][nt], 0, 0, 0);
                acc2[1][nt] = __builtin_amdgcn_mfma_f32_16x16x32_bf16(hA[1][ks], bb, acc2[1][nt], 0, 0, 0);
            }
    }

    // ---- softmax over 16 neighbors + aggregation, per point ----
#pragma unroll
    for (int t = 0; t < 2; ++t)
#pragma unroll
        for (int nt = 0; nt < 4; ++nt) {
            float l0 = acc2[t][nt][0], l1 = acc2[t][nt][1];
            float l2 = acc2[t][nt][2], l3 = acc2[t][nt][3];
            float mx = fmaxf(fmaxf(l0, l1), fmaxf(l2, l3));
            mx = fmaxf(mx, __shfl_xor(mx, 16));
            mx = fmaxf(mx, __shfl_xor(mx, 32));
            float e0 = __expf(l0 - mx), e1 = __expf(l1 - mx);
            float e2 = __expf(l2 - mx), e3 = __expf(l3 - mx);
            float sum = (e0 + e1) + (e2 + e3);
            sum += __shfl_xor(sum, 16);
            sum += __shfl_xor(sum, 32);
            float y1v = bf2f(y1bf[bpt[t] * CC + nt * 16 + m]);
            float contrib = e0 * (y1v + pacc[t][nt][0]) + e1 * (y1v + pacc[t][nt][1]) +
                            e2 * (y1v + pacc[t][nt][2]) + e3 * (y1v + pacc[t][nt][3]);
            contrib += __shfl_xor(contrib, 16);
            contrib += __shfl_xor(contrib, 32);
            float agg = contrib / sum;
            if (quad == 0) agg_lds[(2 * w + t) * 68 + nt * 16 + m] = agg;
        }
    __syncthreads();

    // ---- final: out = Wend*agg + bend via one MFMA pair per wave.
    // A[row=point (rows 8-15 duplicates, unused)][k=ch]; B = WendL tile w.
    short8 aggA[2];
#pragma unroll
    for (int ks = 0; ks < 2; ++ks)
#pragma unroll
        for (int j = 0; j < 8; ++j)
            aggA[ks][j] = (short)f2bf(agg_lds[(m & 7) * 68 + ks * 32 + quad * 8 + j]);
    short8 wb0 = *(const short8*)(WendL + ((w * 2 + 0) * 64 + lane) * 8);
    short8 wb1 = *(const short8*)(WendL + ((w * 2 + 1) * 64 + lane) * 8);
    floatx4 facc = (floatx4){0.f, 0.f, 0.f, 0.f};
    facc = __builtin_amdgcn_mfma_f32_16x16x32_bf16(aggA[0], wb0, facc, 0, 0, 0);
    facc = __builtin_amdgcn_mfma_f32_16x16x32_bf16(aggA[1], wb1, facc, 0, 0, 0);
    if (quad < 2) {
        float be = bend[w * 16 + m];
#pragma unroll
        for (int r = 0; r < 4; ++r)
            outstage[(w * 16 + m) * 8 + 4 * quad + r] = facc[r] + be;
    }
    __syncthreads();

    // ---- coalesced output write (+identity) ----
    int t2 = threadIdx.x;
    int o = t2 >> 2, pp = (t2 & 3) * 2;
#pragma unroll
    for (int e = 0; e < 2; ++e) {
        size_t oi = ((size_t)(b * CC + o)) * NN + n0 + pp + e;
        out[oi] = outstage[o * 8 + pp + e] + y[oi];
    }
}

// ---------------------------------------------------------------------------
extern "C" void kernel_launch(void* const* d_in, const int* in_sizes, int n_in,
                              void* d_out, int out_size, void* d_ws, size_t ws_size,
                              hipStream_t stream) {
    const float* x    = (const float*)d_in[0];
    const float* y    = (const float*)d_in[1];
    const float* Ws   = (const float*)d_in[2];
    const float* bs   = (const float*)d_in[3];
    const float* Wk   = (const float*)d_in[4];
    const float* bk   = (const float*)d_in[5];
    const float* Wq   = (const float*)d_in[6];
    const float* bq   = (const float*)d_in[7];
    const float* P1   = (const float*)d_in[8];
    const float* pb1  = (const float*)d_in[9];
    const float* g1   = (const float*)d_in[10];
    const float* b1   = (const float*)d_in[11];
    const float* m1   = (const float*)d_in[12];
    const float* v1   = (const float*)d_in[13];
    const float* P2   = (const float*)d_in[14];
    const float* pb2  = (const float*)d_in[15];
    const float* A1   = (const float*)d_in[16];
    const float* ab1  = (const float*)d_in[17];
    const float* g2   = (const float*)d_in[18];
    const float* b2   = (const float*)d_in[19];
    const float* m2   = (const float*)d_in[20];
    const float* v2   = (const float*)d_in[21];
    const float* A2   = (const float*)d_in[22];
    const float* ab2  = (const float*)d_in[23];  // dropped (softmax-invariant)
    const float* Wend = (const float*)d_in[24];
    const float* bend = (const float*)d_in[25];
    (void)ab2;

    unsigned short* usws = (unsigned short*)d_ws;
    unsigned short* y1bf  = usws;                  // 1,048,576 us
    unsigned short* keybf = usws + 1048576;        // 1,048,576 us
    unsigned short* qrybf = usws + 2097152;        // 1,048,576 us
    int* idx = (int*)(usws + 3145728);             // 262,144 ints
    unsigned short* A1L = usws + 3670016;          // 16,384 us
    unsigned short* A2L = A1L + 16384;             // 16,384 us
    unsigned short* P2L = A2L + 16384;             // 4,096 us
    unsigned short* WsL = P2L + 4096;              // 8,192 us
    unsigned short* WkL = WsL + 8192;              // 8,192 us
    unsigned short* WendL = WkL + 8192;            // 4,096 us
    float* Wq4   = (float*)(WendL + 4096);         // 256 f (16B-aligned)
    float* P1p   = Wq4 + 256;                      // 256 f
    float* ab1f  = P1p + 256;                      // 256 f
    float* bn2sc = ab1f + 256;                     // 256 f
    float* out   = (float*)d_out;

    hipLaunchKernelGGL(prep_params, dim3(PREP_NB), dim3(256), 0, stream,
                       P1, pb1, P2, A1, ab1, A2, g1, b1, m1, v1, g2, b2, m2, v2,
                       Wend, Ws, Wk, Wq, bq,
                       A1L, A2L, P2L, WendL, WsL, WkL, Wq4, P1p, ab1f, bn2sc);
    hipLaunchKernelGGL(prep_features, dim3(1024), dim3(64), 0, stream,
                       x, y, WsL, bs, WkL, bk, Wq4, y1bf, keybf, qrybf);
    hipLaunchKernelGGL(knn_kernel, dim3(4096), dim3(256), 0, stream, x, idx);
    hipLaunchKernelGGL(attn_mfma, dim3(2048), dim3(256), 0, stream,
                       x, y, y1bf, keybf, qrybf, idx,
                       P1p, P2L, pb2, A1L, ab1f, bn2sc, A2L, WendL,
                       bend, out);
}

// Round 11
// 216.747 us; speedup vs baseline: 8.4399x; 1.1163x over previous
//
#include <hip/hip_runtime.h>
#include <hip/hip_bf16.h>

#define BB 4
#define CC 64
#define NN 4096
#define HH 64
#define AH 256
#define KNN 16
#define EPSV 1e-5f

#define KNN_BLKS 2048   // 2 queries/wave, 8/block
#define PF_BLKS 256     // 4 waves x 16 points = 64 points/block
#define PP_BLKS 32

typedef __attribute__((ext_vector_type(8))) short short8;
typedef __attribute__((ext_vector_type(4))) short short4v;
typedef __attribute__((ext_vector_type(4))) unsigned short ushort4v;
typedef __attribute__((ext_vector_type(4))) float floatx4;

__device__ __forceinline__ unsigned short f2bf(float f) {
    unsigned u = __float_as_uint(f);
    u += 0x7FFFu + ((u >> 16) & 1u);   // round-to-nearest-even
    return (unsigned short)(u >> 16);
}
__device__ __forceinline__ float bf2f(unsigned short u) {
    return __uint_as_float(((unsigned)u) << 16);
}
__device__ __forceinline__ unsigned long long umin64(unsigned long long a, unsigned long long b) {
    return a < b ? a : b;
}
__device__ __forceinline__ unsigned long long umax64(unsigned long long a, unsigned long long b) {
    return a > b ? a : b;
}
__device__ __forceinline__ unsigned long long shfl_xor_u64(unsigned long long v, int m) {
    int lo = __shfl_xor((int)(unsigned)(v & 0xFFFFFFFFull), m);
    int hi = __shfl_xor((int)(unsigned)(v >> 32), m);
    return ((unsigned long long)(unsigned)hi << 32) | (unsigned)lo;
}
// monotone signed-float -> unsigned mapping (norm-form distances can be <0)
__device__ __forceinline__ unsigned fmono(float d) {
    unsigned u = __float_as_uint(d);
    return ((int)u < 0) ? ~u : (u | 0x80000000u);
}

#define UPITCH 68
#define HPITCH 68

__device__ __forceinline__ short8 lds_frag(const unsigned short* p) {
    short4v lo = *(const short4v*)p;
    short4v hi = *(const short4v*)(p + 4);
    short8 v;
    v[0] = lo[0]; v[1] = lo[1]; v[2] = lo[2]; v[3] = lo[3];
    v[4] = hi[0]; v[5] = hi[1]; v[6] = hi[2]; v[7] = hi[3];
    return v;
}

// ---------------------------------------------------------------------------
// FUSED kernel: knn (blocks 0..2047) + prep_features (2048..2303) +
// param relayout (2304..2335). All three are independent of each other;
// fusing overlaps prep under knn's shadow and removes 2 launch gaps.
// ---------------------------------------------------------------------------
__global__ __launch_bounds__(256) void fused_prep_knn(
    const float* __restrict__ x, const float* __restrict__ y,
    const float* __restrict__ Ws, const float* __restrict__ bs,
    const float* __restrict__ Wk, const float* __restrict__ bk,
    const float* __restrict__ Wq, const float* __restrict__ bq,
    const float* __restrict__ P1, const float* __restrict__ pb1,
    const float* __restrict__ P2, const float* __restrict__ A1,
    const float* __restrict__ ab1, const float* __restrict__ A2,
    const float* __restrict__ g1, const float* __restrict__ b1v,
    const float* __restrict__ m1, const float* __restrict__ v1,
    const float* __restrict__ g2, const float* __restrict__ b2v,
    const float* __restrict__ m2, const float* __restrict__ v2,
    const float* __restrict__ Wend,
    int* __restrict__ idx_out,
    unsigned short* __restrict__ y1bf, unsigned short* __restrict__ keybf,
    unsigned short* __restrict__ qrybf,
    unsigned short* __restrict__ A1L, unsigned short* __restrict__ A2L,
    unsigned short* __restrict__ P2L, unsigned short* __restrict__ WendL,
    float* __restrict__ P1p, float* __restrict__ ab1f, float* __restrict__ bn2s_c) {
    __shared__ __align__(16) char smem[65536];
    int blk = blockIdx.x;
    int lane = threadIdx.x & 63;
    int w = threadIdx.x >> 6;

    if (blk < KNN_BLKS) {
        // =================== KNN role: 2 queries per wave ===================
        float4* pts = (float4*)smem;                           // 64 KB
        unsigned long long* surv = (unsigned long long*)smem;  // 8 KB alias

        int b = blk >> 9;            // 512 blocks per batch
        int grp = blk & 511;
        const float* xb = x + (size_t)b * 3 * NN;
        for (int i = threadIdx.x; i < NN; i += 256) {
            float cx = xb[i], cy = xb[NN + i], cz = xb[2 * NN + i];
            pts[i] = make_float4(cx, cy, cz, cx * cx + cy * cy + cz * cz);
        }
        __syncthreads();

        int n0 = (grp << 3) + (w << 1);      // queries n0, n0+1
        float4 q0 = pts[n0], q1 = pts[n0 + 1];
        float q0x = -2.f * q0.x, q0y = -2.f * q0.y, q0z = -2.f * q0.z, q0w = q0.w;
        float q1x = -2.f * q1.x, q1y = -2.f * q1.y, q1z = -2.f * q1.z, q1w = q1.w;

        float d0reg[64], d1reg[64];
        float vmin0 = 3.4e38f, vmin1 = 3.4e38f;
#pragma unroll
        for (int r = 0; r < 64; ++r) {
            float4 c = pts[(r << 6) + lane];
            float d0 = fmaf(q0x, c.x, fmaf(q0y, c.y, fmaf(q0z, c.z, c.w + q0w)));
            float d1 = fmaf(q1x, c.x, fmaf(q1y, c.y, fmaf(q1z, c.z, c.w + q1w)));
            d0reg[r] = d0; d1reg[r] = d1;
            vmin0 = fminf(vmin0, d0);
            vmin1 = fminf(vmin1, d1);
        }

        // sort64 lane-mins ascending; T = 16th smallest (>= true d16)
        float T[2];
#pragma unroll
        for (int t = 0; t < 2; ++t) {
            float v = t ? vmin1 : vmin0;
#pragma unroll
            for (int k = 2; k <= 64; k <<= 1) {
#pragma unroll
                for (int j = k >> 1; j > 0; j >>= 1) {
                    float o = __shfl_xor(v, j);
                    bool lower = (lane & j) == 0;
                    bool up = (lane & k) == 0;
                    float mn = fminf(v, o), mx = fmaxf(v, o);
                    v = (lower == up) ? mn : mx;
                }
            }
            T[t] = __shfl(v, 15);
        }
        __syncthreads();   // pts dead; surv alias safe

#pragma unroll
        for (int t = 0; t < 2; ++t) {
            float Tt = T[t];
            unsigned long long* buf = surv + (((w << 1) + t) << 7);
            unsigned cnt = 0;
#pragma unroll
            for (int r = 0; r < 64; ++r) {
                float d = t ? d1reg[r] : d0reg[r];
                bool hit = d <= Tt;
                unsigned long long mask = __ballot(hit);
                if (hit) {
                    unsigned off = cnt + (unsigned)__popcll(mask & ((1ull << lane) - 1ull));
                    if (off < 128) {
                        int j = (r << 6) + lane;
                        buf[off] = ((unsigned long long)fmono(d) << 32) | (unsigned)j;
                    }
                }
                cnt += (unsigned)__popcll(mask);
            }
            if (cnt > 128) cnt = 128;

            unsigned long long v0 = (lane < (int)cnt) ? buf[lane] : 0xFFFFFFFFFFFFFFFFull;
            unsigned long long v1 = (lane + 64 < (int)cnt) ? buf[lane + 64] : 0xFFFFFFFFFFFFFFFFull;
#pragma unroll
            for (int k = 2; k <= 128; k <<= 1) {
#pragma unroll
                for (int j = k >> 1; j > 0; j >>= 1) {
                    if (j >= 64) {
                        unsigned long long lo = umin64(v0, v1), hi = umax64(v0, v1);
                        v0 = lo; v1 = hi;
                    } else {
                        bool lower = (lane & j) == 0;
                        unsigned long long o0 = shfl_xor_u64(v0, j);
                        bool up0 = ((lane & k) == 0);
                        v0 = (lower == up0) ? umin64(v0, o0) : umax64(v0, o0);
                        unsigned long long o1 = shfl_xor_u64(v1, j);
                        bool up1 = (((64 + lane) & k) == 0);
                        v1 = (lower == up1) ? umin64(v1, o1) : umax64(v1, o1);
                    }
                }
            }
            if (lane < KNN)
                idx_out[((size_t)b * NN + n0 + t) * KNN + lane] =
                    (int)(unsigned)(v0 & 0xFFFFFFFFull);
        }
    } else if (blk < KNN_BLKS + PF_BLKS) {
        // ============ prep_features role: 4 waves, 16 points each ===========
        unsigned short* tl = (unsigned short*)smem + w * 16 * UPITCH;
        int g4 = (blk - KNN_BLKS) * 4 + w;   // 0..1023
        int b = g4 >> 8;
        int n0 = (g4 & 255) << 4;
        int m = lane & 15, quad = lane >> 4;
        size_t ybase = (size_t)b * CC * NN;

        // y A-frags: lane m = point n0+m, k = channel
        short8 yA[2];
#pragma unroll
        for (int ks = 0; ks < 2; ++ks)
#pragma unroll
            for (int j = 0; j < 8; ++j)
                yA[ks][j] = (short)f2bf(y[ybase + (size_t)(ks * 32 + quad * 8 + j) * NN + n0 + m]);

        // GEMM y1 = Ws*y + bs  (Ws read directly from global fp32, B-frag rows)
#pragma unroll
        for (int ot = 0; ot < 4; ++ot) {
            short8 bb0, bb1;
#pragma unroll
            for (int ks = 0; ks < 2; ++ks) {
                const float* wr = Ws + (ot * 16 + m) * CC + ks * 32 + quad * 8;
                float4 lo = *(const float4*)wr;
                float4 hi = *(const float4*)(wr + 4);
                short8 bb;
                bb[0] = (short)f2bf(lo.x); bb[1] = (short)f2bf(lo.y);
                bb[2] = (short)f2bf(lo.z); bb[3] = (short)f2bf(lo.w);
                bb[4] = (short)f2bf(hi.x); bb[5] = (short)f2bf(hi.y);
                bb[6] = (short)f2bf(hi.z); bb[7] = (short)f2bf(hi.w);
                if (ks == 0) bb0 = bb; else bb1 = bb;
            }
            floatx4 acc = (floatx4){0.f, 0.f, 0.f, 0.f};
            acc = __builtin_amdgcn_mfma_f32_16x16x32_bf16(yA[0], bb0, acc, 0, 0, 0);
            acc = __builtin_amdgcn_mfma_f32_16x16x32_bf16(yA[1], bb1, acc, 0, 0, 0);
            float bsv = bs[ot * 16 + m];
#pragma unroll
            for (int r = 0; r < 4; ++r)
                tl[(4 * quad + r) * UPITCH + ot * 16 + m] = f2bf(acc[r] + bsv);
        }
        __syncthreads();

        short8 uA[2];
#pragma unroll
        for (int ks = 0; ks < 2; ++ks)
            uA[ks] = lds_frag(&tl[m * UPITCH + ks * 32 + quad * 8]);

        int p = lane >> 2, ck = lane & 3;
        size_t obase = ((size_t)b * NN + n0 + p) * CC + ck * 16;
#pragma unroll
        for (int s = 0; s < 4; ++s)
            *(ushort4v*)(y1bf + obase + s * 4) =
                *(const ushort4v*)&tl[p * UPITCH + ck * 16 + s * 4];
        __syncthreads();

        // GEMM key = Wk*y1 + bk
#pragma unroll
        for (int ot = 0; ot < 4; ++ot) {
            short8 bb0, bb1;
#pragma unroll
            for (int ks = 0; ks < 2; ++ks) {
                const float* wr = Wk + (ot * 16 + m) * CC + ks * 32 + quad * 8;
                float4 lo = *(const float4*)wr;
                float4 hi = *(const float4*)(wr + 4);
                short8 bb;
                bb[0] = (short)f2bf(lo.x); bb[1] = (short)f2bf(lo.y);
                bb[2] = (short)f2bf(lo.z); bb[3] = (short)f2bf(lo.w);
                bb[4] = (short)f2bf(hi.x); bb[5] = (short)f2bf(hi.y);
                bb[6] = (short)f2bf(hi.z); bb[7] = (short)f2bf(hi.w);
                if (ks == 0) bb0 = bb; else bb1 = bb;
            }
            floatx4 acc = (floatx4){0.f, 0.f, 0.f, 0.f};
            acc = __builtin_amdgcn_mfma_f32_16x16x32_bf16(uA[0], bb0, acc, 0, 0, 0);
            acc = __builtin_amdgcn_mfma_f32_16x16x32_bf16(uA[1], bb1, acc, 0, 0, 0);
            float bkv = bk[ot * 16 + m];
#pragma unroll
            for (int r = 0; r < 4; ++r)
                tl[(4 * quad + r) * UPITCH + ot * 16 + m] = f2bf(acc[r] + bkv);
        }
        __syncthreads();
#pragma unroll
        for (int s = 0; s < 4; ++s)
            *(ushort4v*)(keybf + obase + s * 4) =
                *(const ushort4v*)&tl[p * UPITCH + ck * 16 + s * 4];

        // query = Wq*x + bq (direct global reads; tiny, L1-hot)
        float x0 = x[(size_t)(b * 3 + 0) * NN + n0 + p];
        float x1 = x[(size_t)(b * 3 + 1) * NN + n0 + p];
        float x2 = x[(size_t)(b * 3 + 2) * NN + n0 + p];
#pragma unroll
        for (int s = 0; s < 4; ++s) {
            ushort4v pk;
#pragma unroll
            for (int e = 0; e < 4; ++e) {
                int ch = ck * 16 + s * 4 + e;
                pk[e] = f2bf(Wq[3 * ch + 0] * x0 + Wq[3 * ch + 1] * x1 +
                             Wq[3 * ch + 2] * x2 + bq[ch]);
            }
            *(ushort4v*)(qrybf + obase + s * 4) = pk;
        }
    } else {
        // ============ param-relayout role (32 blocks) ============
        int pb = blk - KNN_BLKS - PF_BLKS;
        int t0 = threadIdx.x;
        int t = pb * 256 + t0;
        const int stride = PP_BLKS * 256;
        if (pb == 0) {
            if (t0 < HH) {
                float s = g1[t0] * rsqrtf(v1[t0] + EPSV);
                float c = b1v[t0] - m1[t0] * s;
                P1p[4 * t0 + 0] = P1[3 * t0 + 0] * s;
                P1p[4 * t0 + 1] = P1[3 * t0 + 1] * s;
                P1p[4 * t0 + 2] = P1[3 * t0 + 2] * s;
                P1p[4 * t0 + 3] = pb1[t0] * s + c;
            }
            if (t0 < AH) {
                float s = g2[t0] * rsqrtf(v2[t0] + EPSV);
                bn2s_c[t0] = s;
                ab1f[t0] = ab1[t0] * s + (b2v[t0] - m2[t0] * s);
            }
        }
        for (int i = t; i < 16384; i += stride) {   // A1L
            int e = i & 7, ln = (i >> 3) & 63, ks = (i >> 9) & 1, ht = i >> 10;
            int m = ln & 15, q = ln >> 4;
            A1L[i] = f2bf(A1[(ht * 16 + m) * CC + ks * 32 + q * 8 + e]);
        }
        for (int i = t; i < 16384; i += stride) {   // A2L
            int e = i & 7, ln = (i >> 3) & 63, kk = (i >> 9) & 7, nt = i >> 12;
            int m = ln & 15, q = ln >> 4;
            A2L[i] = f2bf(A2[(nt * 16 + m) * AH + kk * 32 + q * 8 + e]);
        }
        for (int i = t; i < 4096; i += stride) {    // P2L
            int e = i & 7, ln = (i >> 3) & 63, ks = (i >> 9) & 1, nt = i >> 10;
            int m = ln & 15, q = ln >> 4;
            P2L[i] = f2bf(P2[(nt * 16 + m) * HH + ks * 32 + q * 8 + e]);
        }
        for (int i = t; i < 4096; i += stride) {    // WendL
            int e = i & 7, ln = (i >> 3) & 63, ks = (i >> 9) & 1, wv = i >> 10;
            int m = ln & 15, q = ln >> 4;
            WendL[i] = f2bf(Wend[(wv * 16 + m) * CC + ks * 32 + q * 8 + e]);
        }
    }
}

// ---------------------------------------------------------------------------
// Kernel 2: fused MFMA attention v2 (unchanged from round 10 — verified).
// ---------------------------------------------------------------------------
__global__ __launch_bounds__(256, 3) void attn_mfma(
    const float* __restrict__ x, const float* __restrict__ y,
    const unsigned short* __restrict__ y1bf, const unsigned short* __restrict__ keybf,
    const unsigned short* __restrict__ qrybf, const int* __restrict__ idx,
    const float* __restrict__ P1p, const unsigned short* __restrict__ P2L,
    const float* __restrict__ pb2, const unsigned short* __restrict__ A1L,
    const float* __restrict__ ab1f, const float* __restrict__ bn2s_c,
    const unsigned short* __restrict__ A2L, const unsigned short* __restrict__ WendL,
    const float* __restrict__ bend,
    float* __restrict__ out) {
    __shared__ unsigned short u_lds[128 * UPITCH];
    __shared__ unsigned short hid_lds[128 * HPITCH];
    __shared__ float agg_lds[8 * 68];
    __shared__ float outstage[512];

    int blk = blockIdx.x;
    int b = blk & 3;
    int n0 = (blk >> 2) << 3;
    int w = threadIdx.x >> 6;
    int lane = threadIdx.x & 63;
    int m = lane & 15, quad = lane >> 4;

    int pt[2];
    size_t bpt[2];
#pragma unroll
    for (int t = 0; t < 2; ++t) {
        pt[t] = n0 + 2 * w + t;
        bpt[t] = (size_t)b * NN + pt[t];
    }

    int jm[2], j4[2][4];
    unsigned short qu[2][4], kvu[2][4][4];
#pragma unroll
    for (int t = 0; t < 2; ++t) {
        jm[t] = idx[bpt[t] * KNN + m];
#pragma unroll
        for (int r = 0; r < 4; ++r) j4[t][r] = idx[bpt[t] * KNN + 4 * quad + r];
#pragma unroll
        for (int nt = 0; nt < 4; ++nt) {
            qu[t][nt] = qrybf[bpt[t] * CC + nt * 16 + m];
#pragma unroll
            for (int r = 0; r < 4; ++r)
                kvu[t][nt][r] = keybf[((size_t)b * NN + j4[t][r]) * CC + nt * 16 + m];
        }
    }

    short8 h1A[2][2];
#pragma unroll
    for (int t = 0; t < 2; ++t) {
        float dx = x[(size_t)(b * 3 + 0) * NN + pt[t]] - x[(size_t)(b * 3 + 0) * NN + jm[t]];
        float dy = x[(size_t)(b * 3 + 1) * NN + pt[t]] - x[(size_t)(b * 3 + 1) * NN + jm[t]];
        float dz = x[(size_t)(b * 3 + 2) * NN + pt[t]] - x[(size_t)(b * 3 + 2) * NN + jm[t]];
#pragma unroll
        for (int ks = 0; ks < 2; ++ks)
#pragma unroll
            for (int j = 0; j < 8; ++j) {
                int h1 = ks * 32 + quad * 8 + j;
                const float4 p = *(const float4*)(P1p + 4 * h1);
                float a = fmaxf(p.x * dx + p.y * dy + p.z * dz + p.w, 0.f);
                h1A[t][ks][j] = (short)f2bf(a);
            }
    }

    floatx4 pacc[2][4];
#pragma unroll
    for (int t = 0; t < 2; ++t)
#pragma unroll
        for (int nt = 0; nt < 4; ++nt) pacc[t][nt] = (floatx4){0.f, 0.f, 0.f, 0.f};
#pragma unroll
    for (int ks = 0; ks < 2; ++ks)
#pragma unroll
        for (int nt = 0; nt < 4; ++nt) {
            short8 bb = *(const short8*)(P2L + ((nt * 2 + ks) * 64 + lane) * 8);
            pacc[0][nt] = __builtin_amdgcn_mfma_f32_16x16x32_bf16(h1A[0][ks], bb, pacc[0][nt], 0, 0, 0);
            pacc[1][nt] = __builtin_amdgcn_mfma_f32_16x16x32_bf16(h1A[1][ks], bb, pacc[1][nt], 0, 0, 0);
        }
#pragma unroll
    for (int nt = 0; nt < 4; ++nt) {
        float pb = pb2[nt * 16 + m];
#pragma unroll
        for (int t = 0; t < 2; ++t)
#pragma unroll
            for (int r = 0; r < 4; ++r) pacc[t][nt][r] += pb;
    }

#pragma unroll
    for (int t = 0; t < 2; ++t)
#pragma unroll
        for (int nt = 0; nt < 4; ++nt) {
            float qv = bf2f(qu[t][nt]);
#pragma unroll
            for (int r = 0; r < 4; ++r) {
                float uu = qv - bf2f(kvu[t][nt][r]) + pacc[t][nt][r];
                u_lds[(w * 32 + t * 16 + 4 * quad + r) * UPITCH + nt * 16 + m] = f2bf(uu);
            }
        }

    short8 uA[2][2];
#pragma unroll
    for (int t = 0; t < 2; ++t)
#pragma unroll
        for (int ks = 0; ks < 2; ++ks)
            uA[t][ks] = lds_frag(&u_lds[(w * 32 + t * 16 + m) * UPITCH + ks * 32 + quad * 8]);

    floatx4 acc2[2][4];
#pragma unroll
    for (int t = 0; t < 2; ++t)
#pragma unroll
        for (int nt = 0; nt < 4; ++nt) acc2[t][nt] = (floatx4){0.f, 0.f, 0.f, 0.f};

    for (int qd = 0; qd < 4; ++qd) {
#pragma unroll
        for (int nt4 = 0; nt4 < 4; ++nt4) {
            int ht = qd * 4 + nt4;
            const unsigned short* a1t = A1L + ht * 1024 + lane * 8;
            short8 b0 = *(const short8*)(a1t);
            short8 b1 = *(const short8*)(a1t + 512);
            int h = ht * 16 + m;
            float s = bn2s_c[h], t0 = ab1f[h];
#pragma unroll
            for (int t = 0; t < 2; ++t) {
                floatx4 acc = (floatx4){0.f, 0.f, 0.f, 0.f};
                acc = __builtin_amdgcn_mfma_f32_16x16x32_bf16(uA[t][0], b0, acc, 0, 0, 0);
                acc = __builtin_amdgcn_mfma_f32_16x16x32_bf16(uA[t][1], b1, acc, 0, 0, 0);
#pragma unroll
                for (int r = 0; r < 4; ++r) {
                    float hv = fmaxf(acc[r] * s + t0, 0.f);
                    hid_lds[(w * 32 + t * 16 + 4 * quad + r) * HPITCH + nt4 * 16 + m] = f2bf(hv);
                }
            }
        }
        short8 hA[2][2];
#pragma unroll
        for (int t = 0; t < 2; ++t)
#pragma unroll
            for (int ks = 0; ks < 2; ++ks)
                hA[t][ks] = lds_frag(&hid_lds[(w * 32 + t * 16 + m) * HPITCH + ks * 32 + quad * 8]);
#pragma unroll
        for (int ks = 0; ks < 2; ++ks)
#pragma unroll
            for (int nt = 0; nt < 4; ++nt) {
                int kk = qd * 2 + ks;
                short8 bb = *(const short8*)(A2L + ((nt * 8 + kk) * 64 + lane) * 8);
                acc2[0][nt] = __builtin_amdgcn_mfma_f32_16x16x32_bf16(hA[0][ks], bb, acc2[0][nt], 0, 0, 0);
                acc2[1][nt] = __builtin_amdgcn_mfma_f32_16x16x32_bf16(hA[1][ks], bb, acc2[1][nt], 0, 0, 0);
            }
    }

#pragma unroll
    for (int t = 0; t < 2; ++t)
#pragma unroll
        for (int nt = 0; nt < 4; ++nt) {
            float l0 = acc2[t][nt][0], l1 = acc2[t][nt][1];
            float l2 = acc2[t][nt][2], l3 = acc2[t][nt][3];
            float mx = fmaxf(fmaxf(l0, l1), fmaxf(l2, l3));
            mx = fmaxf(mx, __shfl_xor(mx, 16));
            mx = fmaxf(mx, __shfl_xor(mx, 32));
            float e0 = __expf(l0 - mx), e1 = __expf(l1 - mx);
            float e2 = __expf(l2 - mx), e3 = __expf(l3 - mx);
            float sum = (e0 + e1) + (e2 + e3);
            sum += __shfl_xor(sum, 16);
            sum += __shfl_xor(sum, 32);
            float y1v = bf2f(y1bf[bpt[t] * CC + nt * 16 + m]);
            float contrib = e0 * (y1v + pacc[t][nt][0]) + e1 * (y1v + pacc[t][nt][1]) +
                            e2 * (y1v + pacc[t][nt][2]) + e3 * (y1v + pacc[t][nt][3]);
            contrib += __shfl_xor(contrib, 16);
            contrib += __shfl_xor(contrib, 32);
            float agg = contrib / sum;
            if (quad == 0) agg_lds[(2 * w + t) * 68 + nt * 16 + m] = agg;
        }
    __syncthreads();

    short8 aggA[2];
#pragma unroll
    for (int ks = 0; ks < 2; ++ks)
#pragma unroll
        for (int j = 0; j < 8; ++j)
            aggA[ks][j] = (short)f2bf(agg_lds[(m & 7) * 68 + ks * 32 + quad * 8 + j]);
    short8 wb0 = *(const short8*)(WendL + ((w * 2 + 0) * 64 + lane) * 8);
    short8 wb1 = *(const short8*)(WendL + ((w * 2 + 1) * 64 + lane) * 8);
    floatx4 facc = (floatx4){0.f, 0.f, 0.f, 0.f};
    facc = __builtin_amdgcn_mfma_f32_16x16x32_bf16(aggA[0], wb0, facc, 0, 0, 0);
    facc = __builtin_amdgcn_mfma_f32_16x16x32_bf16(aggA[1], wb1, facc, 0, 0, 0);
    if (quad < 2) {
        float be = bend[w * 16 + m];
#pragma unroll
        for (int r = 0; r < 4; ++r)
            outstage[(w * 16 + m) * 8 + 4 * quad + r] = facc[r] + be;
    }
    __syncthreads();

    int t2 = threadIdx.x;
    int o = t2 >> 2, pp = (t2 & 3) * 2;
#pragma unroll
    for (int e = 0; e < 2; ++e) {
        size_t oi = ((size_t)(b * CC + o)) * NN + n0 + pp + e;
        out[oi] = outstage[o * 8 + pp + e] + y[oi];
    }
}

// ---------------------------------------------------------------------------
extern "C" void kernel_launch(void* const* d_in, const int* in_sizes, int n_in,
                              void* d_out, int out_size, void* d_ws, size_t ws_size,
                              hipStream_t stream) {
    const float* x    = (const float*)d_in[0];
    const float* y    = (const float*)d_in[1];
    const float* Ws   = (const float*)d_in[2];
    const float* bs   = (const float*)d_in[3];
    const float* Wk   = (const float*)d_in[4];
    const float* bk   = (const float*)d_in[5];
    const float* Wq   = (const float*)d_in[6];
    const float* bq   = (const float*)d_in[7];
    const float* P1   = (const float*)d_in[8];
    const float* pb1  = (const float*)d_in[9];
    const float* g1   = (const float*)d_in[10];
    const float* b1   = (const float*)d_in[11];
    const float* m1   = (const float*)d_in[12];
    const float* v1   = (const float*)d_in[13];
    const float* P2   = (const float*)d_in[14];
    const float* pb2  = (const float*)d_in[15];
    const float* A1   = (const float*)d_in[16];
    const float* ab1  = (const float*)d_in[17];
    const float* g2   = (const float*)d_in[18];
    const float* b2   = (const float*)d_in[19];
    const float* m2   = (const float*)d_in[20];
    const float* v2   = (const float*)d_in[21];
    const float* A2   = (const float*)d_in[22];
    const float* ab2  = (const float*)d_in[23];  // dropped (softmax-invariant)
    const float* Wend = (const float*)d_in[24];
    const float* bend = (const float*)d_in[25];
    (void)ab2;

    unsigned short* usws = (unsigned short*)d_ws;
    unsigned short* y1bf  = usws;                  // 1,048,576 us
    unsigned short* keybf = usws + 1048576;        // 1,048,576 us
    unsigned short* qrybf = usws + 2097152;        // 1,048,576 us
    int* idx = (int*)(usws + 3145728);             // 262,144 ints
    unsigned short* A1L = usws + 3670016;          // 16,384 us
    unsigned short* A2L = A1L + 16384;             // 16,384 us
    unsigned short* P2L = A2L + 16384;             // 4,096 us
    unsigned short* WendL = P2L + 4096;            // 4,096 us
    float* P1p   = (float*)(WendL + 4096);         // 256 f (16B-aligned)
    float* ab1f  = P1p + 256;                      // 256 f
    float* bn2sc = ab1f + 256;                     // 256 f
    float* out   = (float*)d_out;

    hipLaunchKernelGGL(fused_prep_knn, dim3(KNN_BLKS + PF_BLKS + PP_BLKS), dim3(256), 0, stream,
                       x, y, Ws, bs, Wk, bk, Wq, bq,
                       P1, pb1, P2, A1, ab1, A2,
                       g1, b1, m1, v1, g2, b2, m2, v2, Wend,
                       idx, y1bf, keybf, qrybf,
                       A1L, A2L, P2L, WendL, P1p, ab1f, bn2sc);
    hipLaunchKernelGGL(attn_mfma, dim3(2048), dim3(256), 0, stream,
                       x, y, y1bf, keybf, qrybf, idx,
                       P1p, P2L, pb2, A1L, ab1f, bn2sc, A2L, WendL,
                       bend, out);
}

// Round 12
// 199.332 us; speedup vs baseline: 9.1772x; 1.0874x over previous
//
#include <hip/hip_runtime.h>
#include <hip/hip_bf16.h>

#define BB 4
#define CC 64
#define NN 4096
#define HH 64
#define AH 256
#define KNN 16
#define EPSV 1e-5f

#define KNN_BLKS 2048   // 2 queries/wave, 8/block
#define PF_BLKS 256     // 4 waves x 16 points = 64 points/block
#define PP_BLKS 32

typedef __attribute__((ext_vector_type(8))) short short8;
typedef __attribute__((ext_vector_type(4))) short short4v;
typedef __attribute__((ext_vector_type(4))) unsigned short ushort4v;
typedef __attribute__((ext_vector_type(4))) float floatx4;

__device__ __forceinline__ unsigned short f2bf(float f) {
    unsigned u = __float_as_uint(f);
    u += 0x7FFFu + ((u >> 16) & 1u);   // round-to-nearest-even
    return (unsigned short)(u >> 16);
}
__device__ __forceinline__ float bf2f(unsigned short u) {
    return __uint_as_float(((unsigned)u) << 16);
}
__device__ __forceinline__ unsigned long long umin64(unsigned long long a, unsigned long long b) {
    return a < b ? a : b;
}
__device__ __forceinline__ unsigned long long umax64(unsigned long long a, unsigned long long b) {
    return a > b ? a : b;
}
__device__ __forceinline__ unsigned long long shfl_xor_u64(unsigned long long v, int m) {
    int lo = __shfl_xor((int)(unsigned)(v & 0xFFFFFFFFull), m);
    int hi = __shfl_xor((int)(unsigned)(v >> 32), m);
    return ((unsigned long long)(unsigned)hi << 32) | (unsigned)lo;
}
// monotone signed-float -> unsigned mapping (norm-form distances can be <0)
__device__ __forceinline__ unsigned fmono(float d) {
    unsigned u = __float_as_uint(d);
    return ((int)u < 0) ? ~u : (u | 0x80000000u);
}

#define UPITCH 68
#define HPITCH 68

__device__ __forceinline__ short8 lds_frag(const unsigned short* p) {
    short4v lo = *(const short4v*)p;
    short4v hi = *(const short4v*)(p + 4);
    short8 v;
    v[0] = lo[0]; v[1] = lo[1]; v[2] = lo[2]; v[3] = lo[3];
    v[4] = hi[0]; v[5] = hi[1]; v[6] = hi[2]; v[7] = hi[3];
    return v;
}

// ---------------------------------------------------------------------------
// FUSED kernel: knn (blocks 0..2047) + prep_features (2048..2303) +
// param relayout (2304..2335).
// KNN: coordinate planes px/py/pz (48 KB -> 3 blocks/CU); each lane reads
// 3x b128 = 4 candidates/iter; |c|^2 on the fly (bit-identical to staged w);
// dreg in regs (launch_bounds(256,3) -> no spill); adaptive 64/128 tail sort.
// ---------------------------------------------------------------------------
__global__ __launch_bounds__(256, 3) void fused_prep_knn(
    const float* __restrict__ x, const float* __restrict__ y,
    const float* __restrict__ Ws, const float* __restrict__ bs,
    const float* __restrict__ Wk, const float* __restrict__ bk,
    const float* __restrict__ Wq, const float* __restrict__ bq,
    const float* __restrict__ P1, const float* __restrict__ pb1,
    const float* __restrict__ P2, const float* __restrict__ A1,
    const float* __restrict__ ab1, const float* __restrict__ A2,
    const float* __restrict__ g1, const float* __restrict__ b1v,
    const float* __restrict__ m1, const float* __restrict__ v1,
    const float* __restrict__ g2, const float* __restrict__ b2v,
    const float* __restrict__ m2, const float* __restrict__ v2,
    const float* __restrict__ Wend,
    int* __restrict__ idx_out,
    unsigned short* __restrict__ y1bf, unsigned short* __restrict__ keybf,
    unsigned short* __restrict__ qrybf,
    unsigned short* __restrict__ A1L, unsigned short* __restrict__ A2L,
    unsigned short* __restrict__ P2L, unsigned short* __restrict__ WendL,
    float* __restrict__ P1p, float* __restrict__ ab1f, float* __restrict__ bn2s_c) {
    __shared__ __align__(16) char smem[49152];   // 48 KB
    int blk = blockIdx.x;
    int lane = threadIdx.x & 63;
    int w = threadIdx.x >> 6;

    if (blk < KNN_BLKS) {
        // =================== KNN role: 2 queries per wave ===================
        float* px = (float*)smem;                 // 16 KB
        float* py = px + NN;                      // 16 KB
        float* pz = py + NN;                      // 16 KB
        unsigned long long* surv = (unsigned long long*)smem;  // 8 KB alias

        int b = blk >> 9;            // 512 blocks per batch
        int grp = blk & 511;
        const float* xb = x + (size_t)b * 3 * NN;
        for (int i = threadIdx.x; i < NN; i += 256) {
            px[i] = xb[i];
            py[i] = xb[NN + i];
            pz[i] = xb[2 * NN + i];
        }
        __syncthreads();

        int n0 = (grp << 3) + (w << 1);      // queries n0, n0+1
        float q0x = px[n0], q0y = py[n0], q0z = pz[n0];
        float q1x = px[n0 + 1], q1y = py[n0 + 1], q1z = pz[n0 + 1];
        float q0w = q0x * q0x + q0y * q0y + q0z * q0z;
        float q1w = q1x * q1x + q1y * q1y + q1z * q1z;
        q0x *= -2.f; q0y *= -2.f; q0z *= -2.f;
        q1x *= -2.f; q1y *= -2.f; q1z *= -2.f;

        // lane handles candidates 4*(r*64+lane)+e, e=0..3, r=0..15
        float d0reg[64], d1reg[64];
        float vmin0 = 3.4e38f, vmin1 = 3.4e38f;
#pragma unroll
        for (int r = 0; r < 16; ++r) {
            int c = r * 64 + lane;
            float4 cx = ((const float4*)px)[c];
            float4 cy = ((const float4*)py)[c];
            float4 cz = ((const float4*)pz)[c];
            float exv[4] = {cx.x, cx.y, cx.z, cx.w};
            float eyv[4] = {cy.x, cy.y, cy.z, cy.w};
            float ezv[4] = {cz.x, cz.y, cz.z, cz.w};
#pragma unroll
            for (int e = 0; e < 4; ++e) {
                float nx = exv[e], ny = eyv[e], nz = ezv[e];
                float nc = nx * nx + ny * ny + nz * nz;   // same expr as staged w
                float d0 = fmaf(q0x, nx, fmaf(q0y, ny, fmaf(q0z, nz, nc + q0w)));
                float d1 = fmaf(q1x, nx, fmaf(q1y, ny, fmaf(q1z, nz, nc + q1w)));
                d0reg[r * 4 + e] = d0;
                d1reg[r * 4 + e] = d1;
                vmin0 = fminf(vmin0, d0);
                vmin1 = fminf(vmin1, d1);
            }
        }

        // sort64 lane-mins ascending; T = 16th smallest (>= true d16)
        float T[2];
#pragma unroll
        for (int t = 0; t < 2; ++t) {
            float v = t ? vmin1 : vmin0;
#pragma unroll
            for (int k = 2; k <= 64; k <<= 1) {
#pragma unroll
                for (int j = k >> 1; j > 0; j >>= 1) {
                    float o = __shfl_xor(v, j);
                    bool lower = (lane & j) == 0;
                    bool up = (lane & k) == 0;
                    float mn = fminf(v, o), mx = fmaxf(v, o);
                    v = (lower == up) ? mn : mx;
                }
            }
            T[t] = __shfl(v, 15);
        }
        __syncthreads();   // planes dead; surv alias safe

#pragma unroll
        for (int t = 0; t < 2; ++t) {
            float Tt = T[t];
            unsigned long long* buf = surv + (((w << 1) + t) << 7);
            unsigned cnt = 0;
#pragma unroll
            for (int s = 0; s < 64; ++s) {
                float d = t ? d1reg[s] : d0reg[s];
                bool hit = d <= Tt;
                unsigned long long mask = __ballot(hit);
                if (hit) {
                    unsigned off = cnt + (unsigned)__popcll(mask & ((1ull << lane) - 1ull));
                    if (off < 128) {
                        int j = ((s >> 2) * 64 + lane) * 4 + (s & 3);
                        buf[off] = ((unsigned long long)fmono(d) << 32) | (unsigned)j;
                    }
                }
                cnt += (unsigned)__popcll(mask);
            }
            if (cnt > 128) cnt = 128;

            unsigned long long v0 = (lane < (int)cnt) ? buf[lane] : 0xFFFFFFFFFFFFFFFFull;
            if (cnt <= 64) {
                // common case (E[cnt]~18): 64-element bitonic only
#pragma unroll
                for (int k = 2; k <= 64; k <<= 1) {
#pragma unroll
                    for (int j = k >> 1; j > 0; j >>= 1) {
                        bool lower = (lane & j) == 0;
                        bool up = (lane & k) == 0;
                        unsigned long long o0 = shfl_xor_u64(v0, j);
                        v0 = (lower == up) ? umin64(v0, o0) : umax64(v0, o0);
                    }
                }
            } else {
                unsigned long long v1 = (lane + 64 < (int)cnt) ? buf[lane + 64]
                                                               : 0xFFFFFFFFFFFFFFFFull;
#pragma unroll
                for (int k = 2; k <= 128; k <<= 1) {
#pragma unroll
                    for (int j = k >> 1; j > 0; j >>= 1) {
                        if (j >= 64) {
                            unsigned long long lo = umin64(v0, v1), hi = umax64(v0, v1);
                            v0 = lo; v1 = hi;
                        } else {
                            bool lower = (lane & j) == 0;
                            unsigned long long o0 = shfl_xor_u64(v0, j);
                            bool up0 = ((lane & k) == 0);
                            v0 = (lower == up0) ? umin64(v0, o0) : umax64(v0, o0);
                            unsigned long long o1 = shfl_xor_u64(v1, j);
                            bool up1 = (((64 + lane) & k) == 0);
                            v1 = (lower == up1) ? umin64(v1, o1) : umax64(v1, o1);
                        }
                    }
                }
            }
            if (lane < KNN)
                idx_out[((size_t)b * NN + n0 + t) * KNN + lane] =
                    (int)(unsigned)(v0 & 0xFFFFFFFFull);
        }
    } else if (blk < KNN_BLKS + PF_BLKS) {
        // ============ prep_features role: 4 waves, 16 points each ===========
        unsigned short* tl = (unsigned short*)smem + w * 16 * UPITCH;
        int g4 = (blk - KNN_BLKS) * 4 + w;   // 0..1023
        int b = g4 >> 8;
        int n0 = (g4 & 255) << 4;
        int m = lane & 15, quad = lane >> 4;
        size_t ybase = (size_t)b * CC * NN;

        short8 yA[2];
#pragma unroll
        for (int ks = 0; ks < 2; ++ks)
#pragma unroll
            for (int j = 0; j < 8; ++j)
                yA[ks][j] = (short)f2bf(y[ybase + (size_t)(ks * 32 + quad * 8 + j) * NN + n0 + m]);

#pragma unroll
        for (int ot = 0; ot < 4; ++ot) {
            short8 bb0, bb1;
#pragma unroll
            for (int ks = 0; ks < 2; ++ks) {
                const float* wr = Ws + (ot * 16 + m) * CC + ks * 32 + quad * 8;
                float4 lo = *(const float4*)wr;
                float4 hi = *(const float4*)(wr + 4);
                short8 bb;
                bb[0] = (short)f2bf(lo.x); bb[1] = (short)f2bf(lo.y);
                bb[2] = (short)f2bf(lo.z); bb[3] = (short)f2bf(lo.w);
                bb[4] = (short)f2bf(hi.x); bb[5] = (short)f2bf(hi.y);
                bb[6] = (short)f2bf(hi.z); bb[7] = (short)f2bf(hi.w);
                if (ks == 0) bb0 = bb; else bb1 = bb;
            }
            floatx4 acc = (floatx4){0.f, 0.f, 0.f, 0.f};
            acc = __builtin_amdgcn_mfma_f32_16x16x32_bf16(yA[0], bb0, acc, 0, 0, 0);
            acc = __builtin_amdgcn_mfma_f32_16x16x32_bf16(yA[1], bb1, acc, 0, 0, 0);
            float bsv = bs[ot * 16 + m];
#pragma unroll
            for (int r = 0; r < 4; ++r)
                tl[(4 * quad + r) * UPITCH + ot * 16 + m] = f2bf(acc[r] + bsv);
        }
        __syncthreads();

        short8 uA[2];
#pragma unroll
        for (int ks = 0; ks < 2; ++ks)
            uA[ks] = lds_frag(&tl[m * UPITCH + ks * 32 + quad * 8]);

        int p = lane >> 2, ck = lane & 3;
        size_t obase = ((size_t)b * NN + n0 + p) * CC + ck * 16;
#pragma unroll
        for (int s = 0; s < 4; ++s)
            *(ushort4v*)(y1bf + obase + s * 4) =
                *(const ushort4v*)&tl[p * UPITCH + ck * 16 + s * 4];
        __syncthreads();

#pragma unroll
        for (int ot = 0; ot < 4; ++ot) {
            short8 bb0, bb1;
#pragma unroll
            for (int ks = 0; ks < 2; ++ks) {
                const float* wr = Wk + (ot * 16 + m) * CC + ks * 32 + quad * 8;
                float4 lo = *(const float4*)wr;
                float4 hi = *(const float4*)(wr + 4);
                short8 bb;
                bb[0] = (short)f2bf(lo.x); bb[1] = (short)f2bf(lo.y);
                bb[2] = (short)f2bf(lo.z); bb[3] = (short)f2bf(lo.w);
                bb[4] = (short)f2bf(hi.x); bb[5] = (short)f2bf(hi.y);
                bb[6] = (short)f2bf(hi.z); bb[7] = (short)f2bf(hi.w);
                if (ks == 0) bb0 = bb; else bb1 = bb;
            }
            floatx4 acc = (floatx4){0.f, 0.f, 0.f, 0.f};
            acc = __builtin_amdgcn_mfma_f32_16x16x32_bf16(uA[0], bb0, acc, 0, 0, 0);
            acc = __builtin_amdgcn_mfma_f32_16x16x32_bf16(uA[1], bb1, acc, 0, 0, 0);
            float bkv = bk[ot * 16 + m];
#pragma unroll
            for (int r = 0; r < 4; ++r)
                tl[(4 * quad + r) * UPITCH + ot * 16 + m] = f2bf(acc[r] + bkv);
        }
        __syncthreads();
#pragma unroll
        for (int s = 0; s < 4; ++s)
            *(ushort4v*)(keybf + obase + s * 4) =
                *(const ushort4v*)&tl[p * UPITCH + ck * 16 + s * 4];

        float x0 = x[(size_t)(b * 3 + 0) * NN + n0 + p];
        float x1 = x[(size_t)(b * 3 + 1) * NN + n0 + p];
        float x2 = x[(size_t)(b * 3 + 2) * NN + n0 + p];
#pragma unroll
        for (int s = 0; s < 4; ++s) {
            ushort4v pk;
#pragma unroll
            for (int e = 0; e < 4; ++e) {
                int ch = ck * 16 + s * 4 + e;
                pk[e] = f2bf(Wq[3 * ch + 0] * x0 + Wq[3 * ch + 1] * x1 +
                             Wq[3 * ch + 2] * x2 + bq[ch]);
            }
            *(ushort4v*)(qrybf + obase + s * 4) = pk;
        }
    } else {
        // ============ param-relayout role (32 blocks) ============
        int pb = blk - KNN_BLKS - PF_BLKS;
        int t0 = threadIdx.x;
        int t = pb * 256 + t0;
        const int stride = PP_BLKS * 256;
        if (pb == 0) {
            if (t0 < HH) {
                float s = g1[t0] * rsqrtf(v1[t0] + EPSV);
                float c = b1v[t0] - m1[t0] * s;
                P1p[4 * t0 + 0] = P1[3 * t0 + 0] * s;
                P1p[4 * t0 + 1] = P1[3 * t0 + 1] * s;
                P1p[4 * t0 + 2] = P1[3 * t0 + 2] * s;
                P1p[4 * t0 + 3] = pb1[t0] * s + c;
            }
            if (t0 < AH) {
                float s = g2[t0] * rsqrtf(v2[t0] + EPSV);
                bn2s_c[t0] = s;
                ab1f[t0] = ab1[t0] * s + (b2v[t0] - m2[t0] * s);
            }
        }
        for (int i = t; i < 16384; i += stride) {   // A1L
            int e = i & 7, ln = (i >> 3) & 63, ks = (i >> 9) & 1, ht = i >> 10;
            int m = ln & 15, q = ln >> 4;
            A1L[i] = f2bf(A1[(ht * 16 + m) * CC + ks * 32 + q * 8 + e]);
        }
        for (int i = t; i < 16384; i += stride) {   // A2L
            int e = i & 7, ln = (i >> 3) & 63, kk = (i >> 9) & 7, nt = i >> 12;
            int m = ln & 15, q = ln >> 4;
            A2L[i] = f2bf(A2[(nt * 16 + m) * AH + kk * 32 + q * 8 + e]);
        }
        for (int i = t; i < 4096; i += stride) {    // P2L
            int e = i & 7, ln = (i >> 3) & 63, ks = (i >> 9) & 1, nt = i >> 10;
            int m = ln & 15, q = ln >> 4;
            P2L[i] = f2bf(P2[(nt * 16 + m) * HH + ks * 32 + q * 8 + e]);
        }
        for (int i = t; i < 4096; i += stride) {    // WendL
            int e = i & 7, ln = (i >> 3) & 63, ks = (i >> 9) & 1, wv = i >> 10;
            int m = ln & 15, q = ln >> 4;
            WendL[i] = f2bf(Wend[(wv * 16 + m) * CC + ks * 32 + q * 8 + e]);
        }
    }
}

// ---------------------------------------------------------------------------
// Kernel 2: fused MFMA attention v2 (unchanged from round 10 — verified).
// ---------------------------------------------------------------------------
__global__ __launch_bounds__(256, 3) void attn_mfma(
    const float* __restrict__ x, const float* __restrict__ y,
    const unsigned short* __restrict__ y1bf, const unsigned short* __restrict__ keybf,
    const unsigned short* __restrict__ qrybf, const int* __restrict__ idx,
    const float* __restrict__ P1p, const unsigned short* __restrict__ P2L,
    const float* __restrict__ pb2, const unsigned short* __restrict__ A1L,
    const float* __restrict__ ab1f, const float* __restrict__ bn2s_c,
    const unsigned short* __restrict__ A2L, const unsigned short* __restrict__ WendL,
    const float* __restrict__ bend,
    float* __restrict__ out) {
    __shared__ unsigned short u_lds[128 * UPITCH];
    __shared__ unsigned short hid_lds[128 * HPITCH];
    __shared__ float agg_lds[8 * 68];
    __shared__ float outstage[512];

    int blk = blockIdx.x;
    int b = blk & 3;
    int n0 = (blk >> 2) << 3;
    int w = threadIdx.x >> 6;
    int lane = threadIdx.x & 63;
    int m = lane & 15, quad = lane >> 4;

    int pt[2];
    size_t bpt[2];
#pragma unroll
    for (int t = 0; t < 2; ++t) {
        pt[t] = n0 + 2 * w + t;
        bpt[t] = (size_t)b * NN + pt[t];
    }

    int jm[2], j4[2][4];
    unsigned short qu[2][4], kvu[2][4][4];
#pragma unroll
    for (int t = 0; t < 2; ++t) {
        jm[t] = idx[bpt[t] * KNN + m];
#pragma unroll
        for (int r = 0; r < 4; ++r) j4[t][r] = idx[bpt[t] * KNN + 4 * quad + r];
#pragma unroll
        for (int nt = 0; nt < 4; ++nt) {
            qu[t][nt] = qrybf[bpt[t] * CC + nt * 16 + m];
#pragma unroll
            for (int r = 0; r < 4; ++r)
                kvu[t][nt][r] = keybf[((size_t)b * NN + j4[t][r]) * CC + nt * 16 + m];
        }
    }

    short8 h1A[2][2];
#pragma unroll
    for (int t = 0; t < 2; ++t) {
        float dx = x[(size_t)(b * 3 + 0) * NN + pt[t]] - x[(size_t)(b * 3 + 0) * NN + jm[t]];
        float dy = x[(size_t)(b * 3 + 1) * NN + pt[t]] - x[(size_t)(b * 3 + 1) * NN + jm[t]];
        float dz = x[(size_t)(b * 3 + 2) * NN + pt[t]] - x[(size_t)(b * 3 + 2) * NN + jm[t]];
#pragma unroll
        for (int ks = 0; ks < 2; ++ks)
#pragma unroll
            for (int j = 0; j < 8; ++j) {
                int h1 = ks * 32 + quad * 8 + j;
                const float4 p = *(const float4*)(P1p + 4 * h1);
                float a = fmaxf(p.x * dx + p.y * dy + p.z * dz + p.w, 0.f);
                h1A[t][ks][j] = (short)f2bf(a);
            }
    }

    floatx4 pacc[2][4];
#pragma unroll
    for (int t = 0; t < 2; ++t)
#pragma unroll
        for (int nt = 0; nt < 4; ++nt) pacc[t][nt] = (floatx4){0.f, 0.f, 0.f, 0.f};
#pragma unroll
    for (int ks = 0; ks < 2; ++ks)
#pragma unroll
        for (int nt = 0; nt < 4; ++nt) {
            short8 bb = *(const short8*)(P2L + ((nt * 2 + ks) * 64 + lane) * 8);
            pacc[0][nt] = __builtin_amdgcn_mfma_f32_16x16x32_bf16(h1A[0][ks], bb, pacc[0][nt], 0, 0, 0);
            pacc[1][nt] = __builtin_amdgcn_mfma_f32_16x16x32_bf16(h1A[1][ks], bb, pacc[1][nt], 0, 0, 0);
        }
#pragma unroll
    for (int nt = 0; nt < 4; ++nt) {
        float pb = pb2[nt * 16 + m];
#pragma unroll
        for (int t = 0; t < 2; ++t)
#pragma unroll
            for (int r = 0; r < 4; ++r) pacc[t][nt][r] += pb;
    }

#pragma unroll
    for (int t = 0; t < 2; ++t)
#pragma unroll
        for (int nt = 0; nt < 4; ++nt) {
            float qv = bf2f(qu[t][nt]);
#pragma unroll
            for (int r = 0; r < 4; ++r) {
                float uu = qv - bf2f(kvu[t][nt][r]) + pacc[t][nt][r];
                u_lds[(w * 32 + t * 16 + 4 * quad + r) * UPITCH + nt * 16 + m] = f2bf(uu);
            }
        }

    short8 uA[2][2];
#pragma unroll
    for (int t = 0; t < 2; ++t)
#pragma unroll
        for (int ks = 0; ks < 2; ++ks)
            uA[t][ks] = lds_frag(&u_lds[(w * 32 + t * 16 + m) * UPITCH + ks * 32 + quad * 8]);

    floatx4 acc2[2][4];
#pragma unroll
    for (int t = 0; t < 2; ++t)
#pragma unroll
        for (int nt = 0; nt < 4; ++nt) acc2[t][nt] = (floatx4){0.f, 0.f, 0.f, 0.f};

    for (int qd = 0; qd < 4; ++qd) {
#pragma unroll
        for (int nt4 = 0; nt4 < 4; ++nt4) {
            int ht = qd * 4 + nt4;
            const unsigned short* a1t = A1L + ht * 1024 + lane * 8;
            short8 b0 = *(const short8*)(a1t);
            short8 b1 = *(const short8*)(a1t + 512);
            int h = ht * 16 + m;
            float s = bn2s_c[h], t0 = ab1f[h];
#pragma unroll
            for (int t = 0; t < 2; ++t) {
                floatx4 acc = (floatx4){0.f, 0.f, 0.f, 0.f};
                acc = __builtin_amdgcn_mfma_f32_16x16x32_bf16(uA[t][0], b0, acc, 0, 0, 0);
                acc = __builtin_amdgcn_mfma_f32_16x16x32_bf16(uA[t][1], b1, acc, 0, 0, 0);
#pragma unroll
                for (int r = 0; r < 4; ++r) {
                    float hv = fmaxf(acc[r] * s + t0, 0.f);
                    hid_lds[(w * 32 + t * 16 + 4 * quad + r) * HPITCH + nt4 * 16 + m] = f2bf(hv);
                }
            }
        }
        short8 hA[2][2];
#pragma unroll
        for (int t = 0; t < 2; ++t)
#pragma unroll
            for (int ks = 0; ks < 2; ++ks)
                hA[t][ks] = lds_frag(&hid_lds[(w * 32 + t * 16 + m) * HPITCH + ks * 32 + quad * 8]);
#pragma unroll
        for (int ks = 0; ks < 2; ++ks)
#pragma unroll
            for (int nt = 0; nt < 4; ++nt) {
                int kk = qd * 2 + ks;
                short8 bb = *(const short8*)(A2L + ((nt * 8 + kk) * 64 + lane) * 8);
                acc2[0][nt] = __builtin_amdgcn_mfma_f32_16x16x32_bf16(hA[0][ks], bb, acc2[0][nt], 0, 0, 0);
                acc2[1][nt] = __builtin_amdgcn_mfma_f32_16x16x32_bf16(hA[1][ks], bb, acc2[1][nt], 0, 0, 0);
            }
    }

#pragma unroll
    for (int t = 0; t < 2; ++t)
#pragma unroll
        for (int nt = 0; nt < 4; ++nt) {
            float l0 = acc2[t][nt][0], l1 = acc2[t][nt][1];
            float l2 = acc2[t][nt][2], l3 = acc2[t][nt][3];
            float mx = fmaxf(fmaxf(l0, l1), fmaxf(l2, l3));
            mx = fmaxf(mx, __shfl_xor(mx, 16));
            mx = fmaxf(mx, __shfl_xor(mx, 32));
            float e0 = __expf(l0 - mx), e1 = __expf(l1 - mx);
            float e2 = __expf(l2 - mx), e3 = __expf(l3 - mx);
            float sum = (e0 + e1) + (e2 + e3);
            sum += __shfl_xor(sum, 16);
            sum += __shfl_xor(sum, 32);
            float y1v = bf2f(y1bf[bpt[t] * CC + nt * 16 + m]);
            float contrib = e0 * (y1v + pacc[t][nt][0]) + e1 * (y1v + pacc[t][nt][1]) +
                            e2 * (y1v + pacc[t][nt][2]) + e3 * (y1v + pacc[t][nt][3]);
            contrib += __shfl_xor(contrib, 16);
            contrib += __shfl_xor(contrib, 32);
            float agg = contrib / sum;
            if (quad == 0) agg_lds[(2 * w + t) * 68 + nt * 16 + m] = agg;
        }
    __syncthreads();

    short8 aggA[2];
#pragma unroll
    for (int ks = 0; ks < 2; ++ks)
#pragma unroll
        for (int j = 0; j < 8; ++j)
            aggA[ks][j] = (short)f2bf(agg_lds[(m & 7) * 68 + ks * 32 + quad * 8 + j]);
    short8 wb0 = *(const short8*)(WendL + ((w * 2 + 0) * 64 + lane) * 8);
    short8 wb1 = *(const short8*)(WendL + ((w * 2 + 1) * 64 + lane) * 8);
    floatx4 facc = (floatx4){0.f, 0.f, 0.f, 0.f};
    facc = __builtin_amdgcn_mfma_f32_16x16x32_bf16(aggA[0], wb0, facc, 0, 0, 0);
    facc = __builtin_amdgcn_mfma_f32_16x16x32_bf16(aggA[1], wb1, facc, 0, 0, 0);
    if (quad < 2) {
        float be = bend[w * 16 + m];
#pragma unroll
        for (int r = 0; r < 4; ++r)
            outstage[(w * 16 + m) * 8 + 4 * quad + r] = facc[r] + be;
    }
    __syncthreads();

    int t2 = threadIdx.x;
    int o = t2 >> 2, pp = (t2 & 3) * 2;
#pragma unroll
    for (int e = 0; e < 2; ++e) {
        size_t oi = ((size_t)(b * CC + o)) * NN + n0 + pp + e;
        out[oi] = outstage[o * 8 + pp + e] + y[oi];
    }
}

// ---------------------------------------------------------------------------
extern "C" void kernel_launch(void* const* d_in, const int* in_sizes, int n_in,
                              void* d_out, int out_size, void* d_ws, size_t ws_size,
                              hipStream_t stream) {
    const float* x    = (const float*)d_in[0];
    const float* y    = (const float*)d_in[1];
    const float* Ws   = (const float*)d_in[2];
    const float* bs   = (const float*)d_in[3];
    const float* Wk   = (const float*)d_in[4];
    const float* bk   = (const float*)d_in[5];
    const float* Wq   = (const float*)d_in[6];
    const float* bq   = (const float*)d_in[7];
    const float* P1   = (const float*)d_in[8];
    const float* pb1  = (const float*)d_in[9];
    const float* g1   = (const float*)d_in[10];
    const float* b1   = (const float*)d_in[11];
    const float* m1   = (const float*)d_in[12];
    const float* v1   = (const float*)d_in[13];
    const float* P2   = (const float*)d_in[14];
    const float* pb2  = (const float*)d_in[15];
    const float* A1   = (const float*)d_in[16];
    const float* ab1  = (const float*)d_in[17];
    const float* g2   = (const float*)d_in[18];
    const float* b2   = (const float*)d_in[19];
    const float* m2   = (const float*)d_in[20];
    const float* v2   = (const float*)d_in[21];
    const float* A2   = (const float*)d_in[22];
    const float* ab2  = (const float*)d_in[23];  // dropped (softmax-invariant)
    const float* Wend = (const float*)d_in[24];
    const float* bend = (const float*)d_in[25];
    (void)ab2;

    unsigned short* usws = (unsigned short*)d_ws;
    unsigned short* y1bf  = usws;                  // 1,048,576 us
    unsigned short* keybf = usws + 1048576;        // 1,048,576 us
    unsigned short* qrybf = usws + 2097152;        // 1,048,576 us
    int* idx = (int*)(usws + 3145728);             // 262,144 ints
    unsigned short* A1L = usws + 3670016;          // 16,384 us
    unsigned short* A2L = A1L + 16384;             // 16,384 us
    unsigned short* P2L = A2L + 16384;             // 4,096 us
    unsigned short* WendL = P2L + 4096;            // 4,096 us
    float* P1p   = (float*)(WendL + 4096);         // 256 f (16B-aligned)
    float* ab1f  = P1p + 256;                      // 256 f
    float* bn2sc = ab1f + 256;                     // 256 f
    float* out   = (float*)d_out;

    hipLaunchKernelGGL(fused_prep_knn, dim3(KNN_BLKS + PF_BLKS + PP_BLKS), dim3(256), 0, stream,
                       x, y, Ws, bs, Wk, bk, Wq, bq,
                       P1, pb1, P2, A1, ab1, A2,
                       g1, b1, m1, v1, g2, b2, m2, v2, Wend,
                       idx, y1bf, keybf, qrybf,
                       A1L, A2L, P2L, WendL, P1p, ab1f, bn2sc);
    hipLaunchKernelGGL(attn_mfma, dim3(2048), dim3(256), 0, stream,
                       x, y, y1bf, keybf, qrybf, idx,
                       P1p, P2L, pb2, A1L, ab1f, bn2sc, A2L, WendL,
                       bend, out);
}

// Round 13
// 195.392 us; speedup vs baseline: 9.3623x; 1.0202x over previous
//
#include <hip/hip_runtime.h>
#include <hip/hip_bf16.h>

#define BB 4
#define CC 64
#define NN 4096
#define HH 64
#define AH 256
#define KNN 16
#define EPSV 1e-5f

#define KNN_BLKS 2048   // 2 queries/wave, 8/block
#define PF_BLKS 256     // 4 waves x 16 points = 64 points/block
#define PP_BLKS 32

typedef __attribute__((ext_vector_type(8))) short short8;
typedef __attribute__((ext_vector_type(4))) short short4v;
typedef __attribute__((ext_vector_type(4))) unsigned short ushort4v;
typedef __attribute__((ext_vector_type(4))) float floatx4;

__device__ __forceinline__ unsigned short f2bf(float f) {
    unsigned u = __float_as_uint(f);
    u += 0x7FFFu + ((u >> 16) & 1u);   // round-to-nearest-even
    return (unsigned short)(u >> 16);
}
__device__ __forceinline__ float bf2f(unsigned short u) {
    return __uint_as_float(((unsigned)u) << 16);
}
// packed RNE f32x2 -> bf16x2 (v_cvt_pk_bf16_f32 on gfx950)
__device__ __forceinline__ unsigned pkbf(float a, float b) {
    __hip_bfloat162 h = __float22bfloat162_rn(make_float2(a, b));
    return *(reinterpret_cast<unsigned*>(&h));
}
__device__ __forceinline__ unsigned long long umin64(unsigned long long a, unsigned long long b) {
    return a < b ? a : b;
}
__device__ __forceinline__ unsigned long long umax64(unsigned long long a, unsigned long long b) {
    return a > b ? a : b;
}
__device__ __forceinline__ unsigned long long shfl_xor_u64(unsigned long long v, int m) {
    int lo = __shfl_xor((int)(unsigned)(v & 0xFFFFFFFFull), m);
    int hi = __shfl_xor((int)(unsigned)(v >> 32), m);
    return ((unsigned long long)(unsigned)hi << 32) | (unsigned)lo;
}
// monotone signed-float -> unsigned mapping (norm-form distances can be <0)
__device__ __forceinline__ unsigned fmono(float d) {
    unsigned u = __float_as_uint(d);
    return ((int)u < 0) ? ~u : (u | 0x80000000u);
}

#define UPITCH 68
#define HPITCH 68

__device__ __forceinline__ short8 lds_frag(const unsigned short* p) {
    short4v lo = *(const short4v*)p;
    short4v hi = *(const short4v*)(p + 4);
    short8 v;
    v[0] = lo[0]; v[1] = lo[1]; v[2] = lo[2]; v[3] = lo[3];
    v[4] = hi[0]; v[5] = hi[1]; v[6] = hi[2]; v[7] = hi[3];
    return v;
}

// ---------------------------------------------------------------------------
// FUSED kernel: knn (blocks 0..2047) + prep_features (2048..2303) +
// param relayout (2304..2335).  KNN role unchanged from round 12 (verified).
// Param role now folds bn2 scale into A1L.
// ---------------------------------------------------------------------------
__global__ __launch_bounds__(256, 3) void fused_prep_knn(
    const float* __restrict__ x, const float* __restrict__ y,
    const float* __restrict__ Ws, const float* __restrict__ bs,
    const float* __restrict__ Wk, const float* __restrict__ bk,
    const float* __restrict__ Wq, const float* __restrict__ bq,
    const float* __restrict__ P1, const float* __restrict__ pb1,
    const float* __restrict__ P2, const float* __restrict__ A1,
    const float* __restrict__ ab1, const float* __restrict__ A2,
    const float* __restrict__ g1, const float* __restrict__ b1v,
    const float* __restrict__ m1, const float* __restrict__ v1,
    const float* __restrict__ g2, const float* __restrict__ b2v,
    const float* __restrict__ m2, const float* __restrict__ v2,
    const float* __restrict__ Wend,
    int* __restrict__ idx_out,
    unsigned short* __restrict__ y1bf, unsigned short* __restrict__ keybf,
    unsigned short* __restrict__ qrybf,
    unsigned short* __restrict__ A1L, unsigned short* __restrict__ A2L,
    unsigned short* __restrict__ P2L, unsigned short* __restrict__ WendL,
    float* __restrict__ P1p, float* __restrict__ ab1f, float* __restrict__ bn2s_c) {
    __shared__ __align__(16) char smem[49152];   // 48 KB
    int blk = blockIdx.x;
    int lane = threadIdx.x & 63;
    int w = threadIdx.x >> 6;

    if (blk < KNN_BLKS) {
        // =================== KNN role: 2 queries per wave ===================
        float* px = (float*)smem;                 // 16 KB
        float* py = px + NN;                      // 16 KB
        float* pz = py + NN;                      // 16 KB
        unsigned long long* surv = (unsigned long long*)smem;  // 8 KB alias

        int b = blk >> 9;            // 512 blocks per batch
        int grp = blk & 511;
        const float* xb = x + (size_t)b * 3 * NN;
        for (int i = threadIdx.x; i < NN; i += 256) {
            px[i] = xb[i];
            py[i] = xb[NN + i];
            pz[i] = xb[2 * NN + i];
        }
        __syncthreads();

        int n0 = (grp << 3) + (w << 1);      // queries n0, n0+1
        float q0x = px[n0], q0y = py[n0], q0z = pz[n0];
        float q1x = px[n0 + 1], q1y = py[n0 + 1], q1z = pz[n0 + 1];
        float q0w = q0x * q0x + q0y * q0y + q0z * q0z;
        float q1w = q1x * q1x + q1y * q1y + q1z * q1z;
        q0x *= -2.f; q0y *= -2.f; q0z *= -2.f;
        q1x *= -2.f; q1y *= -2.f; q1z *= -2.f;

        float d0reg[64], d1reg[64];
        float vmin0 = 3.4e38f, vmin1 = 3.4e38f;
#pragma unroll
        for (int r = 0; r < 16; ++r) {
            int c = r * 64 + lane;
            float4 cx = ((const float4*)px)[c];
            float4 cy = ((const float4*)py)[c];
            float4 cz = ((const float4*)pz)[c];
            float exv[4] = {cx.x, cx.y, cx.z, cx.w};
            float eyv[4] = {cy.x, cy.y, cy.z, cy.w};
            float ezv[4] = {cz.x, cz.y, cz.z, cz.w};
#pragma unroll
            for (int e = 0; e < 4; ++e) {
                float nx = exv[e], ny = eyv[e], nz = ezv[e];
                float nc = nx * nx + ny * ny + nz * nz;
                float d0 = fmaf(q0x, nx, fmaf(q0y, ny, fmaf(q0z, nz, nc + q0w)));
                float d1 = fmaf(q1x, nx, fmaf(q1y, ny, fmaf(q1z, nz, nc + q1w)));
                d0reg[r * 4 + e] = d0;
                d1reg[r * 4 + e] = d1;
                vmin0 = fminf(vmin0, d0);
                vmin1 = fminf(vmin1, d1);
            }
        }

        float T[2];
#pragma unroll
        for (int t = 0; t < 2; ++t) {
            float v = t ? vmin1 : vmin0;
#pragma unroll
            for (int k = 2; k <= 64; k <<= 1) {
#pragma unroll
                for (int j = k >> 1; j > 0; j >>= 1) {
                    float o = __shfl_xor(v, j);
                    bool lower = (lane & j) == 0;
                    bool up = (lane & k) == 0;
                    float mn = fminf(v, o), mx = fmaxf(v, o);
                    v = (lower == up) ? mn : mx;
                }
            }
            T[t] = __shfl(v, 15);
        }
        __syncthreads();   // planes dead; surv alias safe

#pragma unroll
        for (int t = 0; t < 2; ++t) {
            float Tt = T[t];
            unsigned long long* buf = surv + (((w << 1) + t) << 7);
            unsigned cnt = 0;
#pragma unroll
            for (int s = 0; s < 64; ++s) {
                float d = t ? d1reg[s] : d0reg[s];
                bool hit = d <= Tt;
                unsigned long long mask = __ballot(hit);
                if (hit) {
                    unsigned off = cnt + (unsigned)__popcll(mask & ((1ull << lane) - 1ull));
                    if (off < 128) {
                        int j = ((s >> 2) * 64 + lane) * 4 + (s & 3);
                        buf[off] = ((unsigned long long)fmono(d) << 32) | (unsigned)j;
                    }
                }
                cnt += (unsigned)__popcll(mask);
            }
            if (cnt > 128) cnt = 128;

            unsigned long long v0 = (lane < (int)cnt) ? buf[lane] : 0xFFFFFFFFFFFFFFFFull;
            if (cnt <= 64) {
#pragma unroll
                for (int k = 2; k <= 64; k <<= 1) {
#pragma unroll
                    for (int j = k >> 1; j > 0; j >>= 1) {
                        bool lower = (lane & j) == 0;
                        bool up = (lane & k) == 0;
                        unsigned long long o0 = shfl_xor_u64(v0, j);
                        v0 = (lower == up) ? umin64(v0, o0) : umax64(v0, o0);
                    }
                }
            } else {
                unsigned long long v1 = (lane + 64 < (int)cnt) ? buf[lane + 64]
                                                               : 0xFFFFFFFFFFFFFFFFull;
#pragma unroll
                for (int k = 2; k <= 128; k <<= 1) {
#pragma unroll
                    for (int j = k >> 1; j > 0; j >>= 1) {
                        if (j >= 64) {
                            unsigned long long lo = umin64(v0, v1), hi = umax64(v0, v1);
                            v0 = lo; v1 = hi;
                        } else {
                            bool lower = (lane & j) == 0;
                            unsigned long long o0 = shfl_xor_u64(v0, j);
                            bool up0 = ((lane & k) == 0);
                            v0 = (lower == up0) ? umin64(v0, o0) : umax64(v0, o0);
                            unsigned long long o1 = shfl_xor_u64(v1, j);
                            bool up1 = (((64 + lane) & k) == 0);
                            v1 = (lower == up1) ? umin64(v1, o1) : umax64(v1, o1);
                        }
                    }
                }
            }
            if (lane < KNN)
                idx_out[((size_t)b * NN + n0 + t) * KNN + lane] =
                    (int)(unsigned)(v0 & 0xFFFFFFFFull);
        }
    } else if (blk < KNN_BLKS + PF_BLKS) {
        // ============ prep_features role: 4 waves, 16 points each ===========
        unsigned short* tl = (unsigned short*)smem + w * 16 * UPITCH;
        int g4 = (blk - KNN_BLKS) * 4 + w;   // 0..1023
        int b = g4 >> 8;
        int n0 = (g4 & 255) << 4;
        int m = lane & 15, quad = lane >> 4;
        size_t ybase = (size_t)b * CC * NN;

        short8 yA[2];
#pragma unroll
        for (int ks = 0; ks < 2; ++ks)
#pragma unroll
            for (int j = 0; j < 8; j += 2) {
                float a = y[ybase + (size_t)(ks * 32 + quad * 8 + j) * NN + n0 + m];
                float bq2 = y[ybase + (size_t)(ks * 32 + quad * 8 + j + 1) * NN + n0 + m];
                ((unsigned*)&yA[ks])[j >> 1] = pkbf(a, bq2);
            }

#pragma unroll
        for (int ot = 0; ot < 4; ++ot) {
            short8 bb0, bb1;
#pragma unroll
            for (int ks = 0; ks < 2; ++ks) {
                const float* wr = Ws + (ot * 16 + m) * CC + ks * 32 + quad * 8;
                float4 lo = *(const float4*)wr;
                float4 hi = *(const float4*)(wr + 4);
                short8 bb;
                ((unsigned*)&bb)[0] = pkbf(lo.x, lo.y);
                ((unsigned*)&bb)[1] = pkbf(lo.z, lo.w);
                ((unsigned*)&bb)[2] = pkbf(hi.x, hi.y);
                ((unsigned*)&bb)[3] = pkbf(hi.z, hi.w);
                if (ks == 0) bb0 = bb; else bb1 = bb;
            }
            floatx4 acc = (floatx4){0.f, 0.f, 0.f, 0.f};
            acc = __builtin_amdgcn_mfma_f32_16x16x32_bf16(yA[0], bb0, acc, 0, 0, 0);
            acc = __builtin_amdgcn_mfma_f32_16x16x32_bf16(yA[1], bb1, acc, 0, 0, 0);
            float bsv = bs[ot * 16 + m];
#pragma unroll
            for (int r = 0; r < 4; r += 2) {
                unsigned p2 = pkbf(acc[r] + bsv, acc[r + 1] + bsv);
                tl[(4 * quad + r) * UPITCH + ot * 16 + m] = (unsigned short)p2;
                tl[(4 * quad + r + 1) * UPITCH + ot * 16 + m] = (unsigned short)(p2 >> 16);
            }
        }
        __syncthreads();

        short8 uA[2];
#pragma unroll
        for (int ks = 0; ks < 2; ++ks)
            uA[ks] = lds_frag(&tl[m * UPITCH + ks * 32 + quad * 8]);

        int p = lane >> 2, ck = lane & 3;
        size_t obase = ((size_t)b * NN + n0 + p) * CC + ck * 16;
#pragma unroll
        for (int s = 0; s < 4; ++s)
            *(ushort4v*)(y1bf + obase + s * 4) =
                *(const ushort4v*)&tl[p * UPITCH + ck * 16 + s * 4];
        __syncthreads();

#pragma unroll
        for (int ot = 0; ot < 4; ++ot) {
            short8 bb0, bb1;
#pragma unroll
            for (int ks = 0; ks < 2; ++ks) {
                const float* wr = Wk + (ot * 16 + m) * CC + ks * 32 + quad * 8;
                float4 lo = *(const float4*)wr;
                float4 hi = *(const float4*)(wr + 4);
                short8 bb;
                ((unsigned*)&bb)[0] = pkbf(lo.x, lo.y);
                ((unsigned*)&bb)[1] = pkbf(lo.z, lo.w);
                ((unsigned*)&bb)[2] = pkbf(hi.x, hi.y);
                ((unsigned*)&bb)[3] = pkbf(hi.z, hi.w);
                if (ks == 0) bb0 = bb; else bb1 = bb;
            }
            floatx4 acc = (floatx4){0.f, 0.f, 0.f, 0.f};
            acc = __builtin_amdgcn_mfma_f32_16x16x32_bf16(uA[0], bb0, acc, 0, 0, 0);
            acc = __builtin_amdgcn_mfma_f32_16x16x32_bf16(uA[1], bb1, acc, 0, 0, 0);
            float bkv = bk[ot * 16 + m];
#pragma unroll
            for (int r = 0; r < 4; r += 2) {
                unsigned p2 = pkbf(acc[r] + bkv, acc[r + 1] + bkv);
                tl[(4 * quad + r) * UPITCH + ot * 16 + m] = (unsigned short)p2;
                tl[(4 * quad + r + 1) * UPITCH + ot * 16 + m] = (unsigned short)(p2 >> 16);
            }
        }
        __syncthreads();
#pragma unroll
        for (int s = 0; s < 4; ++s)
            *(ushort4v*)(keybf + obase + s * 4) =
                *(const ushort4v*)&tl[p * UPITCH + ck * 16 + s * 4];

        float x0 = x[(size_t)(b * 3 + 0) * NN + n0 + p];
        float x1 = x[(size_t)(b * 3 + 1) * NN + n0 + p];
        float x2 = x[(size_t)(b * 3 + 2) * NN + n0 + p];
#pragma unroll
        for (int s = 0; s < 4; ++s) {
            ushort4v pk;
#pragma unroll
            for (int e = 0; e < 4; ++e) {
                int ch = ck * 16 + s * 4 + e;
                pk[e] = f2bf(Wq[3 * ch + 0] * x0 + Wq[3 * ch + 1] * x1 +
                             Wq[3 * ch + 2] * x2 + bq[ch]);
            }
            *(ushort4v*)(qrybf + obase + s * 4) = pk;
        }
    } else {
        // ============ param-relayout role (32 blocks) ============
        int pb = blk - KNN_BLKS - PF_BLKS;
        int t0 = threadIdx.x;
        int t = pb * 256 + t0;
        const int stride = PP_BLKS * 256;
        if (pb == 0) {
            if (t0 < HH) {
                float s = g1[t0] * rsqrtf(v1[t0] + EPSV);
                float c = b1v[t0] - m1[t0] * s;
                P1p[4 * t0 + 0] = P1[3 * t0 + 0] * s;
                P1p[4 * t0 + 1] = P1[3 * t0 + 1] * s;
                P1p[4 * t0 + 2] = P1[3 * t0 + 2] * s;
                P1p[4 * t0 + 3] = pb1[t0] * s + c;
            }
            if (t0 < AH) {
                float s = g2[t0] * rsqrtf(v2[t0] + EPSV);
                bn2s_c[t0] = s;
                ab1f[t0] = ab1[t0] * s + (b2v[t0] - m2[t0] * s);
            }
        }
        for (int i = t; i < 16384; i += stride) {   // A1L (bn2 scale folded in)
            int e = i & 7, ln = (i >> 3) & 63, ks = (i >> 9) & 1, ht = i >> 10;
            int m = ln & 15, q = ln >> 4;
            int h = ht * 16 + m;
            float s = g2[h] * rsqrtf(v2[h] + EPSV);
            A1L[i] = f2bf(A1[h * CC + ks * 32 + q * 8 + e] * s);
        }
        for (int i = t; i < 16384; i += stride) {   // A2L
            int e = i & 7, ln = (i >> 3) & 63, kk = (i >> 9) & 7, nt = i >> 12;
            int m = ln & 15, q = ln >> 4;
            A2L[i] = f2bf(A2[(nt * 16 + m) * AH + kk * 32 + q * 8 + e]);
        }
        for (int i = t; i < 4096; i += stride) {    // P2L
            int e = i & 7, ln = (i >> 3) & 63, ks = (i >> 9) & 1, nt = i >> 10;
            int m = ln & 15, q = ln >> 4;
            P2L[i] = f2bf(P2[(nt * 16 + m) * HH + ks * 32 + q * 8 + e]);
        }
        for (int i = t; i < 4096; i += stride) {    // WendL
            int e = i & 7, ln = (i >> 3) & 63, ks = (i >> 9) & 1, wv = i >> 10;
            int m = ln & 15, q = ln >> 4;
            WendL[i] = f2bf(Wend[(wv * 16 + m) * CC + ks * 32 + q * 8 + e]);
        }
    }
}

// ---------------------------------------------------------------------------
// Kernel 2: fused MFMA attention v3. Same structure as round 10/12 (verified);
// VALU cuts: bn2 scale folded into A1L, packed bf16 cvt (v_cvt_pk_bf16_f32),
// y1 loads hoisted into the early gather batch.
// ---------------------------------------------------------------------------
__global__ __launch_bounds__(256, 3) void attn_mfma(
    const float* __restrict__ x, const float* __restrict__ y,
    const unsigned short* __restrict__ y1bf, const unsigned short* __restrict__ keybf,
    const unsigned short* __restrict__ qrybf, const int* __restrict__ idx,
    const float* __restrict__ P1p, const unsigned short* __restrict__ P2L,
    const float* __restrict__ pb2, const unsigned short* __restrict__ A1L,
    const float* __restrict__ ab1f, const float* __restrict__ bn2s_c,
    const unsigned short* __restrict__ A2L, const unsigned short* __restrict__ WendL,
    const float* __restrict__ bend,
    float* __restrict__ out) {
    __shared__ unsigned short u_lds[128 * UPITCH];
    __shared__ unsigned short hid_lds[128 * HPITCH];
    __shared__ float agg_lds[8 * 68];
    __shared__ float outstage[512];

    int blk = blockIdx.x;
    int b = blk & 3;
    int n0 = (blk >> 2) << 3;
    int w = threadIdx.x >> 6;
    int lane = threadIdx.x & 63;
    int m = lane & 15, quad = lane >> 4;

    int pt[2];
    size_t bpt[2];
#pragma unroll
    for (int t = 0; t < 2; ++t) {
        pt[t] = n0 + 2 * w + t;
        bpt[t] = (size_t)b * NN + pt[t];
    }

    // ---- gathers for both points (issued early), incl. y1 ----
    int jm[2], j4[2][4];
    unsigned short qu[2][4], kvu[2][4][4], y1u[2][4];
#pragma unroll
    for (int t = 0; t < 2; ++t) {
        jm[t] = idx[bpt[t] * KNN + m];
#pragma unroll
        for (int r = 0; r < 4; ++r) j4[t][r] = idx[bpt[t] * KNN + 4 * quad + r];
#pragma unroll
        for (int nt = 0; nt < 4; ++nt) {
            qu[t][nt] = qrybf[bpt[t] * CC + nt * 16 + m];
            y1u[t][nt] = y1bf[bpt[t] * CC + nt * 16 + m];
#pragma unroll
            for (int r = 0; r < 4; ++r)
                kvu[t][nt][r] = keybf[((size_t)b * NN + j4[t][r]) * CC + nt * 16 + m];
        }
    }

    short8 h1A[2][2];
#pragma unroll
    for (int t = 0; t < 2; ++t) {
        float dx = x[(size_t)(b * 3 + 0) * NN + pt[t]] - x[(size_t)(b * 3 + 0) * NN + jm[t]];
        float dy = x[(size_t)(b * 3 + 1) * NN + pt[t]] - x[(size_t)(b * 3 + 1) * NN + jm[t]];
        float dz = x[(size_t)(b * 3 + 2) * NN + pt[t]] - x[(size_t)(b * 3 + 2) * NN + jm[t]];
#pragma unroll
        for (int ks = 0; ks < 2; ++ks)
#pragma unroll
            for (int j = 0; j < 8; j += 2) {
                int h1 = ks * 32 + quad * 8 + j;
                const float4 p0 = *(const float4*)(P1p + 4 * h1);
                const float4 p1 = *(const float4*)(P1p + 4 * h1 + 4);
                float a0 = fmaxf(p0.x * dx + p0.y * dy + p0.z * dz + p0.w, 0.f);
                float a1 = fmaxf(p1.x * dx + p1.y * dy + p1.z * dz + p1.w, 0.f);
                ((unsigned*)&h1A[t][ks])[j >> 1] = pkbf(a0, a1);
            }
    }

    floatx4 pacc[2][4];
#pragma unroll
    for (int t = 0; t < 2; ++t)
#pragma unroll
        for (int nt = 0; nt < 4; ++nt) pacc[t][nt] = (floatx4){0.f, 0.f, 0.f, 0.f};
#pragma unroll
    for (int ks = 0; ks < 2; ++ks)
#pragma unroll
        for (int nt = 0; nt < 4; ++nt) {
            short8 bb = *(const short8*)(P2L + ((nt * 2 + ks) * 64 + lane) * 8);
            pacc[0][nt] = __builtin_amdgcn_mfma_f32_16x16x32_bf16(h1A[0][ks], bb, pacc[0][nt], 0, 0, 0);
            pacc[1][nt] = __builtin_amdgcn_mfma_f32_16x16x32_bf16(h1A[1][ks], bb, pacc[1][nt], 0, 0, 0);
        }
#pragma unroll
    for (int nt = 0; nt < 4; ++nt) {
        float pb = pb2[nt * 16 + m];
#pragma unroll
        for (int t = 0; t < 2; ++t)
#pragma unroll
            for (int r = 0; r < 4; ++r) pacc[t][nt][r] += pb;
    }

    // ---- u = query - key + pe -> bf16 LDS (packed cvt) ----
#pragma unroll
    for (int t = 0; t < 2; ++t)
#pragma unroll
        for (int nt = 0; nt < 4; ++nt) {
            float qv = bf2f(qu[t][nt]);
            float u0 = qv - bf2f(kvu[t][nt][0]) + pacc[t][nt][0];
            float u1 = qv - bf2f(kvu[t][nt][1]) + pacc[t][nt][1];
            float u2 = qv - bf2f(kvu[t][nt][2]) + pacc[t][nt][2];
            float u3 = qv - bf2f(kvu[t][nt][3]) + pacc[t][nt][3];
            unsigned p01 = pkbf(u0, u1), p23 = pkbf(u2, u3);
            int base = (w * 32 + t * 16 + 4 * quad) * UPITCH + nt * 16 + m;
            u_lds[base + 0 * UPITCH] = (unsigned short)p01;
            u_lds[base + 1 * UPITCH] = (unsigned short)(p01 >> 16);
            u_lds[base + 2 * UPITCH] = (unsigned short)p23;
            u_lds[base + 3 * UPITCH] = (unsigned short)(p23 >> 16);
        }

    short8 uA[2][2];
#pragma unroll
    for (int t = 0; t < 2; ++t)
#pragma unroll
        for (int ks = 0; ks < 2; ++ks)
            uA[t][ks] = lds_frag(&u_lds[(w * 32 + t * 16 + m) * UPITCH + ks * 32 + quad * 8]);

    floatx4 acc2[2][4];
#pragma unroll
    for (int t = 0; t < 2; ++t)
#pragma unroll
        for (int nt = 0; nt < 4; ++nt) acc2[t][nt] = (floatx4){0.f, 0.f, 0.f, 0.f};

    for (int qd = 0; qd < 4; ++qd) {
#pragma unroll
        for (int nt4 = 0; nt4 < 4; ++nt4) {
            int ht = qd * 4 + nt4;
            const unsigned short* a1t = A1L + ht * 1024 + lane * 8;
            short8 b0 = *(const short8*)(a1t);
            short8 b1 = *(const short8*)(a1t + 512);
            int h = ht * 16 + m;
            float t0 = ab1f[h];          // bn2 scale pre-folded into A1L
#pragma unroll
            for (int t = 0; t < 2; ++t) {
                floatx4 acc = (floatx4){0.f, 0.f, 0.f, 0.f};
                acc = __builtin_amdgcn_mfma_f32_16x16x32_bf16(uA[t][0], b0, acc, 0, 0, 0);
                acc = __builtin_amdgcn_mfma_f32_16x16x32_bf16(uA[t][1], b1, acc, 0, 0, 0);
                float h0 = fmaxf(acc[0] + t0, 0.f);
                float h1 = fmaxf(acc[1] + t0, 0.f);
                float h2 = fmaxf(acc[2] + t0, 0.f);
                float h3 = fmaxf(acc[3] + t0, 0.f);
                unsigned p01 = pkbf(h0, h1), p23 = pkbf(h2, h3);
                int base = (w * 32 + t * 16 + 4 * quad) * HPITCH + nt4 * 16 + m;
                hid_lds[base + 0 * HPITCH] = (unsigned short)p01;
                hid_lds[base + 1 * HPITCH] = (unsigned short)(p01 >> 16);
                hid_lds[base + 2 * HPITCH] = (unsigned short)p23;
                hid_lds[base + 3 * HPITCH] = (unsigned short)(p23 >> 16);
            }
        }
        short8 hA[2][2];
#pragma unroll
        for (int t = 0; t < 2; ++t)
#pragma unroll
            for (int ks = 0; ks < 2; ++ks)
                hA[t][ks] = lds_frag(&hid_lds[(w * 32 + t * 16 + m) * HPITCH + ks * 32 + quad * 8]);
#pragma unroll
        for (int ks = 0; ks < 2; ++ks)
#pragma unroll
            for (int nt = 0; nt < 4; ++nt) {
                int kk = qd * 2 + ks;
                short8 bb = *(const short8*)(A2L + ((nt * 8 + kk) * 64 + lane) * 8);
                acc2[0][nt] = __builtin_amdgcn_mfma_f32_16x16x32_bf16(hA[0][ks], bb, acc2[0][nt], 0, 0, 0);
                acc2[1][nt] = __builtin_amdgcn_mfma_f32_16x16x32_bf16(hA[1][ks], bb, acc2[1][nt], 0, 0, 0);
            }
    }

#pragma unroll
    for (int t = 0; t < 2; ++t)
#pragma unroll
        for (int nt = 0; nt < 4; ++nt) {
            float l0 = acc2[t][nt][0], l1 = acc2[t][nt][1];
            float l2 = acc2[t][nt][2], l3 = acc2[t][nt][3];
            float mx = fmaxf(fmaxf(l0, l1), fmaxf(l2, l3));
            mx = fmaxf(mx, __shfl_xor(mx, 16));
            mx = fmaxf(mx, __shfl_xor(mx, 32));
            float e0 = __expf(l0 - mx), e1 = __expf(l1 - mx);
            float e2 = __expf(l2 - mx), e3 = __expf(l3 - mx);
            float sum = (e0 + e1) + (e2 + e3);
            sum += __shfl_xor(sum, 16);
            sum += __shfl_xor(sum, 32);
            float y1v = bf2f(y1u[t][nt]);
            float contrib = e0 * (y1v + pacc[t][nt][0]) + e1 * (y1v + pacc[t][nt][1]) +
                            e2 * (y1v + pacc[t][nt][2]) + e3 * (y1v + pacc[t][nt][3]);
            contrib += __shfl_xor(contrib, 16);
            contrib += __shfl_xor(contrib, 32);
            float agg = contrib / sum;
            if (quad == 0) agg_lds[(2 * w + t) * 68 + nt * 16 + m] = agg;
        }
    __syncthreads();

    short8 aggA[2];
#pragma unroll
    for (int ks = 0; ks < 2; ++ks)
#pragma unroll
        for (int j = 0; j < 8; j += 2) {
            float a0 = agg_lds[(m & 7) * 68 + ks * 32 + quad * 8 + j];
            float a1 = agg_lds[(m & 7) * 68 + ks * 32 + quad * 8 + j + 1];
            ((unsigned*)&aggA[ks])[j >> 1] = pkbf(a0, a1);
        }
    short8 wb0 = *(const short8*)(WendL + ((w * 2 + 0) * 64 + lane) * 8);
    short8 wb1 = *(const short8*)(WendL + ((w * 2 + 1) * 64 + lane) * 8);
    floatx4 facc = (floatx4){0.f, 0.f, 0.f, 0.f};
    facc = __builtin_amdgcn_mfma_f32_16x16x32_bf16(aggA[0], wb0, facc, 0, 0, 0);
    facc = __builtin_amdgcn_mfma_f32_16x16x32_bf16(aggA[1], wb1, facc, 0, 0, 0);
    if (quad < 2) {
        float be = bend[w * 16 + m];
#pragma unroll
        for (int r = 0; r < 4; ++r)
            outstage[(w * 16 + m) * 8 + 4 * quad + r] = facc[r] + be;
    }
    __syncthreads();

    int t2 = threadIdx.x;
    int o = t2 >> 2, pp = (t2 & 3) * 2;
#pragma unroll
    for (int e = 0; e < 2; ++e) {
        size_t oi = ((size_t)(b * CC + o)) * NN + n0 + pp + e;
        out[oi] = outstage[o * 8 + pp + e] + y[oi];
    }
}

// ---------------------------------------------------------------------------
extern "C" void kernel_launch(void* const* d_in, const int* in_sizes, int n_in,
                              void* d_out, int out_size, void* d_ws, size_t ws_size,
                              hipStream_t stream) {
    const float* x    = (const float*)d_in[0];
    const float* y    = (const float*)d_in[1];
    const float* Ws   = (const float*)d_in[2];
    const float* bs   = (const float*)d_in[3];
    const float* Wk   = (const float*)d_in[4];
    const float* bk   = (const float*)d_in[5];
    const float* Wq   = (const float*)d_in[6];
    const float* bq   = (const float*)d_in[7];
    const float* P1   = (const float*)d_in[8];
    const float* pb1  = (const float*)d_in[9];
    const float* g1   = (const float*)d_in[10];
    const float* b1   = (const float*)d_in[11];
    const float* m1   = (const float*)d_in[12];
    const float* v1   = (const float*)d_in[13];
    const float* P2   = (const float*)d_in[14];
    const float* pb2  = (const float*)d_in[15];
    const float* A1   = (const float*)d_in[16];
    const float* ab1  = (const float*)d_in[17];
    const float* g2   = (const float*)d_in[18];
    const float* b2   = (const float*)d_in[19];
    const float* m2   = (const float*)d_in[20];
    const float* v2   = (const float*)d_in[21];
    const float* A2   = (const float*)d_in[22];
    const float* ab2  = (const float*)d_in[23];  // dropped (softmax-invariant)
    const float* Wend = (const float*)d_in[24];
    const float* bend = (const float*)d_in[25];
    (void)ab2;

    unsigned short* usws = (unsigned short*)d_ws;
    unsigned short* y1bf  = usws;                  // 1,048,576 us
    unsigned short* keybf = usws + 1048576;        // 1,048,576 us
    unsigned short* qrybf = usws + 2097152;        // 1,048,576 us
    int* idx = (int*)(usws + 3145728);             // 262,144 ints
    unsigned short* A1L = usws + 3670016;          // 16,384 us
    unsigned short* A2L = A1L + 16384;             // 16,384 us
    unsigned short* P2L = A2L + 16384;             // 4,096 us
    unsigned short* WendL = P2L + 4096;            // 4,096 us
    float* P1p   = (float*)(WendL + 4096);         // 256 f (16B-aligned)
    float* ab1f  = P1p + 256;                      // 256 f
    float* bn2sc = ab1f + 256;                     // 256 f
    float* out   = (float*)d_out;

    hipLaunchKernelGGL(fused_prep_knn, dim3(KNN_BLKS + PF_BLKS + PP_BLKS), dim3(256), 0, stream,
                       x, y, Ws, bs, Wk, bk, Wq, bq,
                       P1, pb1, P2, A1, ab1, A2,
                       g1, b1, m1, v1, g2, b2, m2, v2, Wend,
                       idx, y1bf, keybf, qrybf,
                       A1L, A2L, P2L, WendL, P1p, ab1f, bn2sc);
    hipLaunchKernelGGL(attn_mfma, dim3(2048), dim3(256), 0, stream,
                       x, y, y1bf, keybf, qrybf, idx,
                       P1p, P2L, pb2, A1L, ab1f, bn2sc, A2L, WendL,
                       bend, out);
}

// Round 15
// 195.254 us; speedup vs baseline: 9.3689x; 1.0007x over previous
//
#include <hip/hip_runtime.h>
#include <hip/hip_bf16.h>

#define BB 4
#define CC 64
#define NN 4096
#define HH 64
#define AH 256
#define KNN 16
#define EPSV 1e-5f
#define LOG2E 1.44269504088896f

#define KNN_BLKS 2048   // 2 queries/wave, 8/block
#define PF_BLKS 256     // 4 waves x 16 points = 64 points/block
#define PP_BLKS 32

typedef __attribute__((ext_vector_type(8))) short short8;
typedef __attribute__((ext_vector_type(4))) short short4v;
typedef __attribute__((ext_vector_type(4))) unsigned short ushort4v;
typedef __attribute__((ext_vector_type(4))) float floatx4;

__device__ __forceinline__ unsigned short f2bf(float f) {
    unsigned u = __float_as_uint(f);
    u += 0x7FFFu + ((u >> 16) & 1u);   // round-to-nearest-even
    return (unsigned short)(u >> 16);
}
__device__ __forceinline__ float bf2f(unsigned short u) {
    return __uint_as_float(((unsigned)u) << 16);
}
// packed RNE f32x2 -> bf16x2 (v_cvt_pk_bf16_f32 on gfx950)
__device__ __forceinline__ unsigned pkbf(float a, float b) {
    __hip_bfloat162 h = __float22bfloat162_rn(make_float2(a, b));
    return *(reinterpret_cast<unsigned*>(&h));
}
__device__ __forceinline__ unsigned long long umin64(unsigned long long a, unsigned long long b) {
    return a < b ? a : b;
}
__device__ __forceinline__ unsigned long long umax64(unsigned long long a, unsigned long long b) {
    return a > b ? a : b;
}
__device__ __forceinline__ unsigned long long shfl_xor_u64(unsigned long long v, int m) {
    int lo = __shfl_xor((int)(unsigned)(v & 0xFFFFFFFFull), m);
    int hi = __shfl_xor((int)(unsigned)(v >> 32), m);
    return ((unsigned long long)(unsigned)hi << 32) | (unsigned)lo;
}
// monotone signed-float -> unsigned mapping (norm-form distances can be <0)
__device__ __forceinline__ unsigned fmono(float d) {
    unsigned u = __float_as_uint(d);
    return ((int)u < 0) ? ~u : (u | 0x80000000u);
}

#define UPITCH 68
#define HPITCH 68

__device__ __forceinline__ short8 lds_frag(const unsigned short* p) {
    short4v lo = *(const short4v*)p;
    short4v hi = *(const short4v*)(p + 4);
    short8 v;
    v[0] = lo[0]; v[1] = lo[1]; v[2] = lo[2]; v[3] = lo[3];
    v[4] = hi[0]; v[5] = hi[1]; v[6] = hi[2]; v[7] = hi[3];
    return v;
}

// ---------------------------------------------------------------------------
// Feature tensors y1bf/keybf/qrybf are stored SWIZZLED: element for original
// column (nt*16 + mcol) lives at [point*64 + mcol*4 + nt]. This makes every
// per-lane gather in attn a contiguous b64 (ushort4 over nt).
// ---------------------------------------------------------------------------

// ---------------------------------------------------------------------------
// FUSED kernel: knn (blocks 0..2047) + prep_features (2048..2303) +
// param relayout (2304..2335). KNN role unchanged (verified). A2L folds
// log2(e) so attn's softmax uses exp2 directly.
// ---------------------------------------------------------------------------
__global__ __launch_bounds__(256, 3) void fused_prep_knn(
    const float* __restrict__ x, const float* __restrict__ y,
    const float* __restrict__ Ws, const float* __restrict__ bs,
    const float* __restrict__ Wk, const float* __restrict__ bk,
    const float* __restrict__ Wq, const float* __restrict__ bq,
    const float* __restrict__ P1, const float* __restrict__ pb1,
    const float* __restrict__ P2, const float* __restrict__ A1,
    const float* __restrict__ ab1, const float* __restrict__ A2,
    const float* __restrict__ g1, const float* __restrict__ b1v,
    const float* __restrict__ m1, const float* __restrict__ v1,
    const float* __restrict__ g2, const float* __restrict__ b2v,
    const float* __restrict__ m2, const float* __restrict__ v2,
    const float* __restrict__ Wend,
    int* __restrict__ idx_out,
    unsigned short* __restrict__ y1bf, unsigned short* __restrict__ keybf,
    unsigned short* __restrict__ qrybf,
    unsigned short* __restrict__ A1L, unsigned short* __restrict__ A2L,
    unsigned short* __restrict__ P2L, unsigned short* __restrict__ WendL,
    float* __restrict__ P1p, float* __restrict__ ab1f, float* __restrict__ bn2s_c) {
    __shared__ __align__(16) char smem[49152];   // 48 KB
    int blk = blockIdx.x;
    int lane = threadIdx.x & 63;
    int w = threadIdx.x >> 6;

    if (blk < KNN_BLKS) {
        // =================== KNN role: 2 queries per wave ===================
        float* px = (float*)smem;
        float* py = px + NN;
        float* pz = py + NN;
        unsigned long long* surv = (unsigned long long*)smem;  // alias

        int b = blk >> 9;
        int grp = blk & 511;
        const float* xb = x + (size_t)b * 3 * NN;
        for (int i = threadIdx.x; i < NN; i += 256) {
            px[i] = xb[i];
            py[i] = xb[NN + i];
            pz[i] = xb[2 * NN + i];
        }
        __syncthreads();

        int n0 = (grp << 3) + (w << 1);
        float q0x = px[n0], q0y = py[n0], q0z = pz[n0];
        float q1x = px[n0 + 1], q1y = py[n0 + 1], q1z = pz[n0 + 1];
        float q0w = q0x * q0x + q0y * q0y + q0z * q0z;
        float q1w = q1x * q1x + q1y * q1y + q1z * q1z;
        q0x *= -2.f; q0y *= -2.f; q0z *= -2.f;
        q1x *= -2.f; q1y *= -2.f; q1z *= -2.f;

        float d0reg[64], d1reg[64];
        float vmin0 = 3.4e38f, vmin1 = 3.4e38f;
#pragma unroll
        for (int r = 0; r < 16; ++r) {
            int c = r * 64 + lane;
            float4 cx = ((const float4*)px)[c];
            float4 cy = ((const float4*)py)[c];
            float4 cz = ((const float4*)pz)[c];
            float exv[4] = {cx.x, cx.y, cx.z, cx.w};
            float eyv[4] = {cy.x, cy.y, cy.z, cy.w};
            float ezv[4] = {cz.x, cz.y, cz.z, cz.w};
#pragma unroll
            for (int e = 0; e < 4; ++e) {
                float nx = exv[e], ny = eyv[e], nz = ezv[e];
                float nc = nx * nx + ny * ny + nz * nz;
                float d0 = fmaf(q0x, nx, fmaf(q0y, ny, fmaf(q0z, nz, nc + q0w)));
                float d1 = fmaf(q1x, nx, fmaf(q1y, ny, fmaf(q1z, nz, nc + q1w)));
                d0reg[r * 4 + e] = d0;
                d1reg[r * 4 + e] = d1;
                vmin0 = fminf(vmin0, d0);
                vmin1 = fminf(vmin1, d1);
            }
        }

        float T[2];
#pragma unroll
        for (int t = 0; t < 2; ++t) {
            float v = t ? vmin1 : vmin0;
#pragma unroll
            for (int k = 2; k <= 64; k <<= 1) {
#pragma unroll
                for (int j = k >> 1; j > 0; j >>= 1) {
                    float o = __shfl_xor(v, j);
                    bool lower = (lane & j) == 0;
                    bool up = (lane & k) == 0;
                    float mn = fminf(v, o), mx = fmaxf(v, o);
                    v = (lower == up) ? mn : mx;
                }
            }
            T[t] = __shfl(v, 15);
        }
        __syncthreads();   // planes dead; surv alias safe

#pragma unroll
        for (int t = 0; t < 2; ++t) {
            float Tt = T[t];
            unsigned long long* buf = surv + (((w << 1) + t) << 7);
            unsigned cnt = 0;
#pragma unroll
            for (int s = 0; s < 64; ++s) {
                float d = t ? d1reg[s] : d0reg[s];
                bool hit = d <= Tt;
                unsigned long long mask = __ballot(hit);
                if (hit) {
                    unsigned off = cnt + (unsigned)__popcll(mask & ((1ull << lane) - 1ull));
                    if (off < 128) {
                        int j = ((s >> 2) * 64 + lane) * 4 + (s & 3);
                        buf[off] = ((unsigned long long)fmono(d) << 32) | (unsigned)j;
                    }
                }
                cnt += (unsigned)__popcll(mask);
            }
            if (cnt > 128) cnt = 128;

            unsigned long long v0 = (lane < (int)cnt) ? buf[lane] : 0xFFFFFFFFFFFFFFFFull;
            if (cnt <= 64) {
#pragma unroll
                for (int k = 2; k <= 64; k <<= 1) {
#pragma unroll
                    for (int j = k >> 1; j > 0; j >>= 1) {
                        bool lower = (lane & j) == 0;
                        bool up = (lane & k) == 0;
                        unsigned long long o0 = shfl_xor_u64(v0, j);
                        v0 = (lower == up) ? umin64(v0, o0) : umax64(v0, o0);
                    }
                }
            } else {
                unsigned long long v1 = (lane + 64 < (int)cnt) ? buf[lane + 64]
                                                               : 0xFFFFFFFFFFFFFFFFull;
#pragma unroll
                for (int k = 2; k <= 128; k <<= 1) {
#pragma unroll
                    for (int j = k >> 1; j > 0; j >>= 1) {
                        if (j >= 64) {
                            unsigned long long lo = umin64(v0, v1), hi = umax64(v0, v1);
                            v0 = lo; v1 = hi;
                        } else {
                            bool lower = (lane & j) == 0;
                            unsigned long long o0 = shfl_xor_u64(v0, j);
                            bool up0 = ((lane & k) == 0);
                            v0 = (lower == up0) ? umin64(v0, o0) : umax64(v0, o0);
                            unsigned long long o1 = shfl_xor_u64(v1, j);
                            bool up1 = (((64 + lane) & k) == 0);
                            v1 = (lower == up1) ? umin64(v1, o1) : umax64(v1, o1);
                        }
                    }
                }
            }
            if (lane < KNN)
                idx_out[((size_t)b * NN + n0 + t) * KNN + lane] =
                    (int)(unsigned)(v0 & 0xFFFFFFFFull);
        }
    } else if (blk < KNN_BLKS + PF_BLKS) {
        // ============ prep_features role: 4 waves, 16 points each ===========
        unsigned short* tl = (unsigned short*)smem + w * 16 * UPITCH;
        int g4 = (blk - KNN_BLKS) * 4 + w;   // 0..1023
        int b = g4 >> 8;
        int n0 = (g4 & 255) << 4;
        int m = lane & 15, quad = lane >> 4;
        size_t ybase = (size_t)b * CC * NN;

        short8 yA[2];
#pragma unroll
        for (int ks = 0; ks < 2; ++ks)
#pragma unroll
            for (int j = 0; j < 8; j += 2) {
                float a = y[ybase + (size_t)(ks * 32 + quad * 8 + j) * NN + n0 + m];
                float bq2 = y[ybase + (size_t)(ks * 32 + quad * 8 + j + 1) * NN + n0 + m];
                ((unsigned*)&yA[ks])[j >> 1] = pkbf(a, bq2);
            }

#pragma unroll
        for (int ot = 0; ot < 4; ++ot) {
            short8 bb0, bb1;
#pragma unroll
            for (int ks = 0; ks < 2; ++ks) {
                const float* wr = Ws + (ot * 16 + m) * CC + ks * 32 + quad * 8;
                float4 lo = *(const float4*)wr;
                float4 hi = *(const float4*)(wr + 4);
                short8 bb;
                ((unsigned*)&bb)[0] = pkbf(lo.x, lo.y);
                ((unsigned*)&bb)[1] = pkbf(lo.z, lo.w);
                ((unsigned*)&bb)[2] = pkbf(hi.x, hi.y);
                ((unsigned*)&bb)[3] = pkbf(hi.z, hi.w);
                if (ks == 0) bb0 = bb; else bb1 = bb;
            }
            floatx4 acc = (floatx4){0.f, 0.f, 0.f, 0.f};
            acc = __builtin_amdgcn_mfma_f32_16x16x32_bf16(yA[0], bb0, acc, 0, 0, 0);
            acc = __builtin_amdgcn_mfma_f32_16x16x32_bf16(yA[1], bb1, acc, 0, 0, 0);
            float bsv = bs[ot * 16 + m];
#pragma unroll
            for (int r = 0; r < 4; r += 2) {
                unsigned p2 = pkbf(acc[r] + bsv, acc[r + 1] + bsv);
                tl[(4 * quad + r) * UPITCH + ot * 16 + m] = (unsigned short)p2;
                tl[(4 * quad + r + 1) * UPITCH + ot * 16 + m] = (unsigned short)(p2 >> 16);
            }
        }
        __syncthreads();

        short8 uA[2];
#pragma unroll
        for (int ks = 0; ks < 2; ++ks)
            uA[ks] = lds_frag(&tl[m * UPITCH + ks * 32 + quad * 8]);

        // ---- swizzled copy-out: [point*64 + mcol*4 + nt] b64 stores ----
        int p = lane >> 2, gb = lane & 3;
        size_t obase = ((size_t)b * NN + n0 + p) * 64;
#pragma unroll
        for (int s = 0; s < 4; ++s) {
            int g = gb * 4 + s;   // mcol
            ushort4v pk;
#pragma unroll
            for (int nt = 0; nt < 4; ++nt)
                pk[nt] = tl[p * UPITCH + nt * 16 + g];
            *(ushort4v*)(y1bf + obase + g * 4) = pk;
        }
        __syncthreads();

#pragma unroll
        for (int ot = 0; ot < 4; ++ot) {
            short8 bb0, bb1;
#pragma unroll
            for (int ks = 0; ks < 2; ++ks) {
                const float* wr = Wk + (ot * 16 + m) * CC + ks * 32 + quad * 8;
                float4 lo = *(const float4*)wr;
                float4 hi = *(const float4*)(wr + 4);
                short8 bb;
                ((unsigned*)&bb)[0] = pkbf(lo.x, lo.y);
                ((unsigned*)&bb)[1] = pkbf(lo.z, lo.w);
                ((unsigned*)&bb)[2] = pkbf(hi.x, hi.y);
                ((unsigned*)&bb)[3] = pkbf(hi.z, hi.w);
                if (ks == 0) bb0 = bb; else bb1 = bb;
            }
            floatx4 acc = (floatx4){0.f, 0.f, 0.f, 0.f};
            acc = __builtin_amdgcn_mfma_f32_16x16x32_bf16(uA[0], bb0, acc, 0, 0, 0);
            acc = __builtin_amdgcn_mfma_f32_16x16x32_bf16(uA[1], bb1, acc, 0, 0, 0);
            float bkv = bk[ot * 16 + m];
#pragma unroll
            for (int r = 0; r < 4; r += 2) {
                unsigned p2 = pkbf(acc[r] + bkv, acc[r + 1] + bkv);
                tl[(4 * quad + r) * UPITCH + ot * 16 + m] = (unsigned short)p2;
                tl[(4 * quad + r + 1) * UPITCH + ot * 16 + m] = (unsigned short)(p2 >> 16);
            }
        }
        __syncthreads();
#pragma unroll
        for (int s = 0; s < 4; ++s) {
            int g = gb * 4 + s;
            ushort4v pk;
#pragma unroll
            for (int nt = 0; nt < 4; ++nt)
                pk[nt] = tl[p * UPITCH + nt * 16 + g];
            *(ushort4v*)(keybf + obase + g * 4) = pk;
        }

        // query = Wq*x + bq, computed directly in swizzled layout
        float x0 = x[(size_t)(b * 3 + 0) * NN + n0 + p];
        float x1 = x[(size_t)(b * 3 + 1) * NN + n0 + p];
        float x2 = x[(size_t)(b * 3 + 2) * NN + n0 + p];
#pragma unroll
        for (int s = 0; s < 4; ++s) {
            int g = gb * 4 + s;
            ushort4v pk;
#pragma unroll
            for (int nt = 0; nt < 4; ++nt) {
                int ch = nt * 16 + g;
                pk[nt] = f2bf(Wq[3 * ch + 0] * x0 + Wq[3 * ch + 1] * x1 +
                              Wq[3 * ch + 2] * x2 + bq[ch]);
            }
            *(ushort4v*)(qrybf + obase + g * 4) = pk;
        }
    } else {
        // ============ param-relayout role (32 blocks) ============
        int pb = blk - KNN_BLKS - PF_BLKS;
        int t0 = threadIdx.x;
        int t = pb * 256 + t0;
        const int stride = PP_BLKS * 256;
        if (pb == 0) {
            if (t0 < HH) {
                float s = g1[t0] * rsqrtf(v1[t0] + EPSV);
                float c = b1v[t0] - m1[t0] * s;
                P1p[4 * t0 + 0] = P1[3 * t0 + 0] * s;
                P1p[4 * t0 + 1] = P1[3 * t0 + 1] * s;
                P1p[4 * t0 + 2] = P1[3 * t0 + 2] * s;
                P1p[4 * t0 + 3] = pb1[t0] * s + c;
            }
            if (t0 < AH) {
                float s = g2[t0] * rsqrtf(v2[t0] + EPSV);
                bn2s_c[t0] = s;
                ab1f[t0] = ab1[t0] * s + (b2v[t0] - m2[t0] * s);
            }
        }
        for (int i = t; i < 16384; i += stride) {   // A1L (bn2 scale folded in)
            int e = i & 7, ln = (i >> 3) & 63, ks = (i >> 9) & 1, ht = i >> 10;
            int m = ln & 15, q = ln >> 4;
            int h = ht * 16 + m;
            float s = g2[h] * rsqrtf(v2[h] + EPSV);
            A1L[i] = f2bf(A1[h * CC + ks * 32 + q * 8 + e] * s);
        }
        for (int i = t; i < 16384; i += stride) {   // A2L (log2e folded in)
            int e = i & 7, ln = (i >> 3) & 63, kk = (i >> 9) & 7, nt = i >> 12;
            int m = ln & 15, q = ln >> 4;
            A2L[i] = f2bf(A2[(nt * 16 + m) * AH + kk * 32 + q * 8 + e] * LOG2E);
        }
        for (int i = t; i < 4096; i += stride) {    // P2L
            int e = i & 7, ln = (i >> 3) & 63, ks = (i >> 9) & 1, nt = i >> 10;
            int m = ln & 15, q = ln >> 4;
            P2L[i] = f2bf(P2[(nt * 16 + m) * HH + ks * 32 + q * 8 + e]);
        }
        for (int i = t; i < 4096; i += stride) {    // WendL
            int e = i & 7, ln = (i >> 3) & 63, ks = (i >> 9) & 1, wv = i >> 10;
            int m = ln & 15, q = ln >> 4;
            WendL[i] = f2bf(Wend[(wv * 16 + m) * CC + ks * 32 + q * 8 + e]);
        }
    }
}

// ---------------------------------------------------------------------------
// Kernel 2: fused MFMA attention v4. Swizzled b64 feature gathers; exp2
// softmax (log2e pre-folded into A2L). Structure otherwise = verified v3.
// ---------------------------------------------------------------------------
__global__ __launch_bounds__(256, 3) void attn_mfma(
    const float* __restrict__ x, const float* __restrict__ y,
    const unsigned short* __restrict__ y1bf, const unsigned short* __restrict__ keybf,
    const unsigned short* __restrict__ qrybf, const int* __restrict__ idx,
    const float* __restrict__ P1p, const unsigned short* __restrict__ P2L,
    const float* __restrict__ pb2, const unsigned short* __restrict__ A1L,
    const float* __restrict__ ab1f, const float* __restrict__ bn2s_c,
    const unsigned short* __restrict__ A2L, const unsigned short* __restrict__ WendL,
    const float* __restrict__ bend,
    float* __restrict__ out) {
    __shared__ unsigned short u_lds[128 * UPITCH];
    __shared__ unsigned short hid_lds[128 * HPITCH];
    __shared__ float agg_lds[8 * 68];
    __shared__ float outstage[512];

    int blk = blockIdx.x;
    int b = blk & 3;
    int n0 = (blk >> 2) << 3;
    int w = threadIdx.x >> 6;
    int lane = threadIdx.x & 63;
    int m = lane & 15, quad = lane >> 4;

    int pt[2];
    size_t bpt[2];
#pragma unroll
    for (int t = 0; t < 2; ++t) {
        pt[t] = n0 + 2 * w + t;
        bpt[t] = (size_t)b * NN + pt[t];
    }

    // ---- gathers (b64 via swizzled layout), issued early ----
    int jm[2], j4[2][4];
    ushort4v qu4[2], y14[2], kv4[2][4];
#pragma unroll
    for (int t = 0; t < 2; ++t) {
        jm[t] = idx[bpt[t] * KNN + m];
#pragma unroll
        for (int r = 0; r < 4; ++r) j4[t][r] = idx[bpt[t] * KNN + 4 * quad + r];
        qu4[t] = *(const ushort4v*)(qrybf + bpt[t] * 64 + m * 4);
        y14[t] = *(const ushort4v*)(y1bf + bpt[t] * 64 + m * 4);
#pragma unroll
        for (int r = 0; r < 4; ++r)
            kv4[t][r] = *(const ushort4v*)(keybf + ((size_t)b * NN + j4[t][r]) * 64 + m * 4);
    }

    short8 h1A[2][2];
#pragma unroll
    for (int t = 0; t < 2; ++t) {
        float dx = x[(size_t)(b * 3 + 0) * NN + pt[t]] - x[(size_t)(b * 3 + 0) * NN + jm[t]];
        float dy = x[(size_t)(b * 3 + 1) * NN + pt[t]] - x[(size_t)(b * 3 + 1) * NN + jm[t]];
        float dz = x[(size_t)(b * 3 + 2) * NN + pt[t]] - x[(size_t)(b * 3 + 2) * NN + jm[t]];
#pragma unroll
        for (int ks = 0; ks < 2; ++ks)
#pragma unroll
            for (int j = 0; j < 8; j += 2) {
                int h1 = ks * 32 + quad * 8 + j;
                const float4 p0 = *(const float4*)(P1p + 4 * h1);
                const float4 p1 = *(const float4*)(P1p + 4 * h1 + 4);
                float a0 = fmaxf(p0.x * dx + p0.y * dy + p0.z * dz + p0.w, 0.f);
                float a1 = fmaxf(p1.x * dx + p1.y * dy + p1.z * dz + p1.w, 0.f);
                ((unsigned*)&h1A[t][ks])[j >> 1] = pkbf(a0, a1);
            }
    }

    floatx4 pacc[2][4];
#pragma unroll
    for (int t = 0; t < 2; ++t)
#pragma unroll
        for (int nt = 0; nt < 4; ++nt) pacc[t][nt] = (floatx4){0.f, 0.f, 0.f, 0.f};
#pragma unroll
    for (int ks = 0; ks < 2; ++ks)
#pragma unroll
        for (int nt = 0; nt < 4; ++nt) {
            short8 bb = *(const short8*)(P2L + ((nt * 2 + ks) * 64 + lane) * 8);
            pacc[0][nt] = __builtin_amdgcn_mfma_f32_16x16x32_bf16(h1A[0][ks], bb, pacc[0][nt], 0, 0, 0);
            pacc[1][nt] = __builtin_amdgcn_mfma_f32_16x16x32_bf16(h1A[1][ks], bb, pacc[1][nt], 0, 0, 0);
        }
#pragma unroll
    for (int nt = 0; nt < 4; ++nt) {
        float pb = pb2[nt * 16 + m];
#pragma unroll
        for (int t = 0; t < 2; ++t)
#pragma unroll
            for (int r = 0; r < 4; ++r) pacc[t][nt][r] += pb;
    }

    // ---- u = query - key + pe -> bf16 LDS (packed cvt) ----
#pragma unroll
    for (int t = 0; t < 2; ++t)
#pragma unroll
        for (int nt = 0; nt < 4; ++nt) {
            float qv = bf2f(qu4[t][nt]);
            float u0 = qv - bf2f(kv4[t][0][nt]) + pacc[t][nt][0];
            float u1 = qv - bf2f(kv4[t][1][nt]) + pacc[t][nt][1];
            float u2 = qv - bf2f(kv4[t][2][nt]) + pacc[t][nt][2];
            float u3 = qv - bf2f(kv4[t][3][nt]) + pacc[t][nt][3];
            unsigned p01 = pkbf(u0, u1), p23 = pkbf(u2, u3);
            int base = (w * 32 + t * 16 + 4 * quad) * UPITCH + nt * 16 + m;
            u_lds[base + 0 * UPITCH] = (unsigned short)p01;
            u_lds[base + 1 * UPITCH] = (unsigned short)(p01 >> 16);
            u_lds[base + 2 * UPITCH] = (unsigned short)p23;
            u_lds[base + 3 * UPITCH] = (unsigned short)(p23 >> 16);
        }

    short8 uA[2][2];
#pragma unroll
    for (int t = 0; t < 2; ++t)
#pragma unroll
        for (int ks = 0; ks < 2; ++ks)
            uA[t][ks] = lds_frag(&u_lds[(w * 32 + t * 16 + m) * UPITCH + ks * 32 + quad * 8]);

    floatx4 acc2[2][4];
#pragma unroll
    for (int t = 0; t < 2; ++t)
#pragma unroll
        for (int nt = 0; nt < 4; ++nt) acc2[t][nt] = (floatx4){0.f, 0.f, 0.f, 0.f};

    for (int qd = 0; qd < 4; ++qd) {
#pragma unroll
        for (int nt4 = 0; nt4 < 4; ++nt4) {
            int ht = qd * 4 + nt4;
            const unsigned short* a1t = A1L + ht * 1024 + lane * 8;
            short8 b0 = *(const short8*)(a1t);
            short8 b1 = *(const short8*)(a1t + 512);
            int h = ht * 16 + m;
            float t0 = ab1f[h];
#pragma unroll
            for (int t = 0; t < 2; ++t) {
                floatx4 acc = (floatx4){0.f, 0.f, 0.f, 0.f};
                acc = __builtin_amdgcn_mfma_f32_16x16x32_bf16(uA[t][0], b0, acc, 0, 0, 0);
                acc = __builtin_amdgcn_mfma_f32_16x16x32_bf16(uA[t][1], b1, acc, 0, 0, 0);
                float h0 = fmaxf(acc[0] + t0, 0.f);
                float h1 = fmaxf(acc[1] + t0, 0.f);
                float h2 = fmaxf(acc[2] + t0, 0.f);
                float h3 = fmaxf(acc[3] + t0, 0.f);
                unsigned p01 = pkbf(h0, h1), p23 = pkbf(h2, h3);
                int base = (w * 32 + t * 16 + 4 * quad) * HPITCH + nt4 * 16 + m;
                hid_lds[base + 0 * HPITCH] = (unsigned short)p01;
                hid_lds[base + 1 * HPITCH] = (unsigned short)(p01 >> 16);
                hid_lds[base + 2 * HPITCH] = (unsigned short)p23;
                hid_lds[base + 3 * HPITCH] = (unsigned short)(p23 >> 16);
            }
        }
        short8 hA[2][2];
#pragma unroll
        for (int t = 0; t < 2; ++t)
#pragma unroll
            for (int ks = 0; ks < 2; ++ks)
                hA[t][ks] = lds_frag(&hid_lds[(w * 32 + t * 16 + m) * HPITCH + ks * 32 + quad * 8]);
#pragma unroll
        for (int ks = 0; ks < 2; ++ks)
#pragma unroll
            for (int nt = 0; nt < 4; ++nt) {
                int kk = qd * 2 + ks;
                short8 bb = *(const short8*)(A2L + ((nt * 8 + kk) * 64 + lane) * 8);
                acc2[0][nt] = __builtin_amdgcn_mfma_f32_16x16x32_bf16(hA[0][ks], bb, acc2[0][nt], 0, 0, 0);
                acc2[1][nt] = __builtin_amdgcn_mfma_f32_16x16x32_bf16(hA[1][ks], bb, acc2[1][nt], 0, 0, 0);
            }
    }

    // ---- softmax over 16 neighbors (logits pre-scaled by log2e -> exp2) ----
#pragma unroll
    for (int t = 0; t < 2; ++t)
#pragma unroll
        for (int nt = 0; nt < 4; ++nt) {
            float l0 = acc2[t][nt][0], l1 = acc2[t][nt][1];
            float l2 = acc2[t][nt][2], l3 = acc2[t][nt][3];
            float mx = fmaxf(fmaxf(l0, l1), fmaxf(l2, l3));
            mx = fmaxf(mx, __shfl_xor(mx, 16));
            mx = fmaxf(mx, __shfl_xor(mx, 32));
            float e0 = exp2f(l0 - mx), e1 = exp2f(l1 - mx);
            float e2 = exp2f(l2 - mx), e3 = exp2f(l3 - mx);
            float sum = (e0 + e1) + (e2 + e3);
            sum += __shfl_xor(sum, 16);
            sum += __shfl_xor(sum, 32);
            float y1v = bf2f(y14[t][nt]);
            float contrib = e0 * (y1v + pacc[t][nt][0]) + e1 * (y1v + pacc[t][nt][1]) +
                            e2 * (y1v + pacc[t][nt][2]) + e3 * (y1v + pacc[t][nt][3]);
            contrib += __shfl_xor(contrib, 16);
            contrib += __shfl_xor(contrib, 32);
            float agg = contrib / sum;
            if (quad == 0) agg_lds[(2 * w + t) * 68 + nt * 16 + m] = agg;
        }
    __syncthreads();

    short8 aggA[2];
#pragma unroll
    for (int ks = 0; ks < 2; ++ks)
#pragma unroll
        for (int j = 0; j < 8; j += 2) {
            float a0 = agg_lds[(m & 7) * 68 + ks * 32 + quad * 8 + j];
            float a1 = agg_lds[(m & 7) * 68 + ks * 32 + quad * 8 + j + 1];
            ((unsigned*)&aggA[ks])[j >> 1] = pkbf(a0, a1);
        }
    short8 wb0 = *(const short8*)(WendL + ((w * 2 + 0) * 64 + lane) * 8);
    short8 wb1 = *(const short8*)(WendL + ((w * 2 + 1) * 64 + lane) * 8);
    floatx4 facc = (floatx4){0.f, 0.f, 0.f, 0.f};
    facc = __builtin_amdgcn_mfma_f32_16x16x32_bf16(aggA[0], wb0, facc, 0, 0, 0);
    facc = __builtin_amdgcn_mfma_f32_16x16x32_bf16(aggA[1], wb1, facc, 0, 0, 0);
    if (quad < 2) {
        float be = bend[w * 16 + m];
#pragma unroll
        for (int r = 0; r < 4; ++r)
            outstage[(w * 16 + m) * 8 + 4 * quad + r] = facc[r] + be;
    }
    __syncthreads();

    int t2 = threadIdx.x;
    int o = t2 >> 2, pp = (t2 & 3) * 2;
#pragma unroll
    for (int e = 0; e < 2; ++e) {
        size_t oi = ((size_t)(b * CC + o)) * NN + n0 + pp + e;
        out[oi] = outstage[o * 8 + pp + e] + y[oi];
    }
}

// ---------------------------------------------------------------------------
extern "C" void kernel_launch(void* const* d_in, const int* in_sizes, int n_in,
                              void* d_out, int out_size, void* d_ws, size_t ws_size,
                              hipStream_t stream) {
    const float* x    = (const float*)d_in[0];
    const float* y    = (const float*)d_in[1];
    const float* Ws   = (const float*)d_in[2];
    const float* bs   = (const float*)d_in[3];
    const float* Wk   = (const float*)d_in[4];
    const float* bk   = (const float*)d_in[5];
    const float* Wq   = (const float*)d_in[6];
    const float* bq   = (const float*)d_in[7];
    const float* P1   = (const float*)d_in[8];
    const float* pb1  = (const float*)d_in[9];
    const float* g1   = (const float*)d_in[10];
    const float* b1   = (const float*)d_in[11];
    const float* m1   = (const float*)d_in[12];
    const float* v1   = (const float*)d_in[13];
    const float* P2   = (const float*)d_in[14];
    const float* pb2  = (const float*)d_in[15];
    const float* A1   = (const float*)d_in[16];
    const float* ab1  = (const float*)d_in[17];
    const float* g2   = (const float*)d_in[18];
    const float* b2   = (const float*)d_in[19];
    const float* m2   = (const float*)d_in[20];
    const float* v2   = (const float*)d_in[21];
    const float* A2   = (const float*)d_in[22];
    const float* ab2  = (const float*)d_in[23];  // dropped (softmax-invariant)
    const float* Wend = (const float*)d_in[24];
    const float* bend = (const float*)d_in[25];
    (void)ab2;

    unsigned short* usws = (unsigned short*)d_ws;
    unsigned short* y1bf  = usws;                  // 1,048,576 us (swizzled)
    unsigned short* keybf = usws + 1048576;        // 1,048,576 us (swizzled)
    unsigned short* qrybf = usws + 2097152;        // 1,048,576 us (swizzled)
    int* idx = (int*)(usws + 3145728);             // 262,144 ints
    unsigned short* A1L = usws + 3670016;          // 16,384 us
    unsigned short* A2L = A1L + 16384;             // 16,384 us
    unsigned short* P2L = A2L + 16384;             // 4,096 us
    unsigned short* WendL = P2L + 4096;            // 4,096 us
    float* P1p   = (float*)(WendL + 4096);         // 256 f (16B-aligned)
    float* ab1f  = P1p + 256;                      // 256 f
    float* bn2sc = ab1f + 256;                     // 256 f
    float* out   = (float*)d_out;

    hipLaunchKernelGGL(fused_prep_knn, dim3(KNN_BLKS + PF_BLKS + PP_BLKS), dim3(256), 0, stream,
                       x, y, Ws, bs, Wk, bk, Wq, bq,
                       P1, pb1, P2, A1, ab1, A2,
                       g1, b1, m1, v1, g2, b2, m2, v2, Wend,
                       idx, y1bf, keybf, qrybf,
                       A1L, A2L, P2L, WendL, P1p, ab1f, bn2sc);
    hipLaunchKernelGGL(attn_mfma, dim3(2048), dim3(256), 0, stream,
                       x, y, y1bf, keybf, qrybf, idx,
                       P1p, P2L, pb2, A1L, ab1f, bn2sc, A2L, WendL,
                       bend, out);
}